// Round 1
// baseline (1888.735 us; speedup 1.0000x reference)
//
#include <hip/hip_runtime.h>
#include <hip/hip_bf16.h>
#include <math.h>

#define B_ 4
#define T_ 1024
#define D_ 1024
#define H_ 16
#define DH_ 64
#define F_ 4096
#define BT_ (B_ * T_)                          // 4096 rows
#define BTD ((size_t)B_ * T_ * D_)             // 4194304
#define ATTN_ELEMS ((size_t)B_ * H_ * T_ * T_) // 16777216

// ---------------- block reductions (256 threads, wave64) ----------------
__device__ __forceinline__ float blk_sum256(float v, float* s4) {
#pragma unroll
  for (int off = 32; off > 0; off >>= 1) v += __shfl_down(v, off);
  if ((threadIdx.x & 63) == 0) s4[threadIdx.x >> 6] = v;
  __syncthreads();
  float t = s4[0] + s4[1] + s4[2] + s4[3];
  __syncthreads();
  return t;
}
__device__ __forceinline__ float blk_max256(float v, float* s4) {
#pragma unroll
  for (int off = 32; off > 0; off >>= 1) v = fmaxf(v, __shfl_down(v, off));
  if ((threadIdx.x & 63) == 0) s4[threadIdx.x >> 6] = v;
  __syncthreads();
  float t = fmaxf(fmaxf(s4[0], s4[1]), fmaxf(s4[2], s4[3]));
  __syncthreads();
  return t;
}

__device__ __forceinline__ float gelu_f(float x) {
  // jax.nn.gelu default: tanh approximation
  float x3 = x * x * x;
  return 0.5f * x * (1.0f + tanhf(0.79788456080286536f * (x + 0.044715f * x3)));
}

// ---------------- LayerNorm over rows of D=1024 (optional second addend) ----
__global__ __launch_bounds__(256) void ln_rows(
    const float* __restrict__ in, const float* __restrict__ in2,
    const float* __restrict__ g, const float* __restrict__ bb,
    float* __restrict__ out) {
  __shared__ float s4[4];
  const size_t base = (size_t)blockIdx.x * D_;
  const int t = threadIdx.x;
  float4 v = ((const float4*)(in + base))[t];
  if (in2) {
    float4 w = ((const float4*)(in2 + base))[t];
    v.x += w.x; v.y += w.y; v.z += w.z; v.w += w.w;
  }
  float mean = blk_sum256(v.x + v.y + v.z + v.w, s4) * (1.0f / D_);
  float dx = v.x - mean, dy = v.y - mean, dz = v.z - mean, dw = v.w - mean;
  float var = blk_sum256(dx * dx + dy * dy + dz * dz + dw * dw, s4) * (1.0f / D_);
  float rstd = rsqrtf(var + 1e-5f);
  float4 gv = ((const float4*)g)[t];
  float4 bv = ((const float4*)bb)[t];
  float4 o;
  o.x = dx * rstd * gv.x + bv.x;
  o.y = dy * rstd * gv.y + bv.y;
  o.z = dz * rstd * gv.z + bv.z;
  o.w = dw * rstd * gv.w + bv.w;
  ((float4*)(out + base))[t] = o;
}

// ---------------- kb += spatial + edge ----------------
__global__ __launch_bounds__(256) void add3_kernel(
    float* __restrict__ a, const float* __restrict__ b,
    const float* __restrict__ c, int n4) {
  int i = blockIdx.x * 256 + threadIdx.x;
  if (i < n4) {
    float4 x = ((float4*)a)[i];
    float4 y = ((const float4*)b)[i];
    float4 z = ((const float4*)c)[i];
    x.x += y.x + z.x; x.y += y.y + z.y; x.z += y.z + z.z; x.w += y.w + z.w;
    ((float4*)a)[i] = x;
  }
}

// ---------------- C[M][N] = A[M][K] @ W[K][N] + bias, epilogue ----------------
// EPI: 0 = bias, 1 = bias+gelu, 2 = bias + residual add (res, same shape as C)
template <int EPI>
__global__ __launch_bounds__(256) void gemm_bias(
    const float* __restrict__ A, const float* __restrict__ W,
    const float* __restrict__ bias, const float* __restrict__ res,
    float* __restrict__ C, int M, int N, int K) {
  __shared__ float As[16][68];
  __shared__ float Bs[16][68];
  const int tid = threadIdx.x;
  const int tx = tid & 15, ty = tid >> 4;
  const int m0 = blockIdx.y * 64, n0 = blockIdx.x * 64;
  float acc[4][4] = {};
  for (int k0 = 0; k0 < K; k0 += 16) {
    {
      const int k = tid & 15, r = tid >> 4;
#pragma unroll
      for (int i = 0; i < 4; ++i)
        As[k][r + 16 * i] = A[(size_t)(m0 + r + 16 * i) * K + (k0 + k)];
    }
    {
      const int n = tid & 63, kq = tid >> 6;
#pragma unroll
      for (int i = 0; i < 4; ++i)
        Bs[kq + 4 * i][n] = W[(size_t)(k0 + kq + 4 * i) * N + (n0 + n)];
    }
    __syncthreads();
#pragma unroll
    for (int kk = 0; kk < 16; ++kk) {
      const float4 a = *(const float4*)&As[kk][ty * 4];
      const float4 b = *(const float4*)&Bs[kk][tx * 4];
      const float av[4] = {a.x, a.y, a.z, a.w};
      const float bv[4] = {b.x, b.y, b.z, b.w};
#pragma unroll
      for (int i = 0; i < 4; ++i)
#pragma unroll
        for (int j = 0; j < 4; ++j)
          acc[i][j] = fmaf(av[i], bv[j], acc[i][j]);
    }
    __syncthreads();
  }
#pragma unroll
  for (int i = 0; i < 4; ++i) {
    const int m = m0 + ty * 4 + i;
#pragma unroll
    for (int j = 0; j < 4; ++j) {
      const int n = n0 + tx * 4 + j;
      float v = acc[i][j] + bias[n];
      if (EPI == 1) v = gelu_f(v);
      if (EPI == 2) v += res[(size_t)m * N + n];
      C[(size_t)m * N + n] = v;
    }
  }
}

// ---------------- scores[bh] = (Q_bh @ Kb_bh^T) / 8 ----------------
__global__ __launch_bounds__(256) void scores_qkt(
    const float* __restrict__ q, const float* __restrict__ kb,
    float* __restrict__ out) {
  const int bh = blockIdx.z;
  const int b = bh >> 4, h = bh & 15;
  const float* Ab = q + (size_t)b * T_ * D_ + h * DH_;   // A(t,k), lda=D
  const float* Bb = kb + (size_t)b * T_ * D_ + h * DH_;  // B(s,k), ldb=D
  float* Cb = out + (size_t)bh * T_ * T_;
  __shared__ float As[16][68];
  __shared__ float Bs[16][68];
  const int tid = threadIdx.x;
  const int tx = tid & 15, ty = tid >> 4;
  const int m0 = blockIdx.y * 64, n0 = blockIdx.x * 64;
  float acc[4][4] = {};
  for (int k0 = 0; k0 < DH_; k0 += 16) {
    const int k = tid & 15, r = tid >> 4;
#pragma unroll
    for (int i = 0; i < 4; ++i) {
      As[k][r + 16 * i] = Ab[(size_t)(m0 + r + 16 * i) * D_ + (k0 + k)];
      Bs[k][r + 16 * i] = Bb[(size_t)(n0 + r + 16 * i) * D_ + (k0 + k)];
    }
    __syncthreads();
#pragma unroll
    for (int kk = 0; kk < 16; ++kk) {
      const float4 a = *(const float4*)&As[kk][ty * 4];
      const float4 b = *(const float4*)&Bs[kk][tx * 4];
      const float av[4] = {a.x, a.y, a.z, a.w};
      const float bv[4] = {b.x, b.y, b.z, b.w};
#pragma unroll
      for (int i = 0; i < 4; ++i)
#pragma unroll
        for (int j = 0; j < 4; ++j)
          acc[i][j] = fmaf(av[i], bv[j], acc[i][j]);
    }
    __syncthreads();
  }
#pragma unroll
  for (int i = 0; i < 4; ++i)
#pragma unroll
    for (int j = 0; j < 4; ++j)
      Cb[(size_t)(m0 + ty * 4 + i) * T_ + (n0 + tx * 4 + j)] = acc[i][j] * 0.125f;
}

// ---------------- softmax in place over rows of 1024 ----------------
__global__ __launch_bounds__(256) void softmax_rows(float* __restrict__ p) {
  __shared__ float s4[4];
  float* row = p + (size_t)blockIdx.x * T_;
  const int t = threadIdx.x;
  float4 v = ((float4*)row)[t];
  float mx = blk_max256(fmaxf(fmaxf(v.x, v.y), fmaxf(v.z, v.w)), s4);
  v.x = __expf(v.x - mx); v.y = __expf(v.y - mx);
  v.z = __expf(v.z - mx); v.w = __expf(v.w - mx);
  float inv = 1.0f / blk_sum256(v.x + v.y + v.z + v.w, s4);
  v.x *= inv; v.y *= inv; v.z *= inv; v.w *= inv;
  ((float4*)row)[t] = v;
}

// ---------------- ctx[bh] = attn_bh @ V_bh  (M=1024, N=64, K=1024) ----------
__global__ __launch_bounds__(256) void ctx_av(
    const float* __restrict__ attn, const float* __restrict__ v,
    float* __restrict__ ctx) {
  const int bh = blockIdx.z;
  const int b = bh >> 4, h = bh & 15;
  const float* Ab = attn + (size_t)bh * T_ * T_;          // A(t,s), lda=T
  const float* Bb = v + (size_t)b * T_ * D_ + h * DH_;    // B(s,j), ldb=D
  float* Cb = ctx + (size_t)b * T_ * D_ + h * DH_;        // C(t,j), ldc=D
  __shared__ float As[16][68];
  __shared__ float Bs[16][68];
  const int tid = threadIdx.x;
  const int tx = tid & 15, ty = tid >> 4;
  const int m0 = blockIdx.y * 64;  // single N tile (N=64)
  float acc[4][4] = {};
  for (int k0 = 0; k0 < T_; k0 += 16) {
    {
      const int k = tid & 15, r = tid >> 4;
#pragma unroll
      for (int i = 0; i < 4; ++i)
        As[k][r + 16 * i] = Ab[(size_t)(m0 + r + 16 * i) * T_ + (k0 + k)];
    }
    {
      const int n = tid & 63, kq = tid >> 6;
#pragma unroll
      for (int i = 0; i < 4; ++i)
        Bs[kq + 4 * i][n] = Bb[(size_t)(k0 + kq + 4 * i) * D_ + n];
    }
    __syncthreads();
#pragma unroll
    for (int kk = 0; kk < 16; ++kk) {
      const float4 a = *(const float4*)&As[kk][ty * 4];
      const float4 b = *(const float4*)&Bs[kk][tx * 4];
      const float av[4] = {a.x, a.y, a.z, a.w};
      const float bv[4] = {b.x, b.y, b.z, b.w};
#pragma unroll
      for (int i = 0; i < 4; ++i)
#pragma unroll
        for (int j = 0; j < 4; ++j)
          acc[i][j] = fmaf(av[i], bv[j], acc[i][j]);
    }
    __syncthreads();
  }
#pragma unroll
  for (int i = 0; i < 4; ++i)
#pragma unroll
    for (int j = 0; j < 4; ++j)
      Cb[(size_t)(m0 + ty * 4 + i) * D_ + (tx * 4 + j)] = acc[i][j];
}

extern "C" void kernel_launch(void* const* d_in, const int* in_sizes, int n_in,
                              void* d_out, int out_size, void* d_ws, size_t ws_size,
                              hipStream_t stream) {
  const float* x    = (const float*)d_in[0];
  const float* sp   = (const float*)d_in[1];
  const float* ed   = (const float*)d_in[2];
  const float* ln1g = (const float*)d_in[3];
  const float* ln1b = (const float*)d_in[4];
  const float* Wq   = (const float*)d_in[5];
  const float* bq   = (const float*)d_in[6];
  const float* Wk   = (const float*)d_in[7];
  const float* bk   = (const float*)d_in[8];
  const float* Wv   = (const float*)d_in[9];
  const float* bv   = (const float*)d_in[10];
  const float* Wo   = (const float*)d_in[11];
  const float* bo   = (const float*)d_in[12];
  const float* ln2g = (const float*)d_in[13];
  const float* ln2b = (const float*)d_in[14];
  const float* W1   = (const float*)d_in[15];
  const float* b1   = (const float*)d_in[16];
  const float* W2   = (const float*)d_in[17];
  const float* b2   = (const float*)d_in[18];
  const float* lnbg = (const float*)d_in[19];
  const float* lnbb = (const float*)d_in[20];

  float* out_x = (float*)d_out;       // B*T*D
  float* attn  = out_x + BTD;         // B*H*T*T (output #2, also scores scratch)

  float* ws  = (float*)d_ws;
  float* xn  = ws;            // post-LN1 x (= residual); later reused for y (post-LN2)
  float* q   = ws + BTD;
  float* kb  = ws + 2 * BTD;
  float* vv  = ws + 3 * BTD;
  float* ctx = ws + 4 * BTD;
  float* tt  = ws + 5 * BTD;  // post-Wo + residual; later reused for h2
  float* h1  = ws + BTD;      // 16.78M floats, overlaps q/kb/vv/ctx (dead by then)
  float* h2  = ws + 5 * BTD;  // overlaps tt (dead by then)

  dim3 blk(256);
  dim3 g_dd(D_ / 64, BT_ / 64);  // (16, 64)

  // 1. LN1
  ln_rows<<<BT_, blk, 0, stream>>>(x, nullptr, ln1g, ln1b, xn);
  // 2-4. Q, K, V
  gemm_bias<0><<<g_dd, blk, 0, stream>>>(xn, Wq, bq, nullptr, q, BT_, D_, D_);
  gemm_bias<0><<<g_dd, blk, 0, stream>>>(xn, Wk, bk, nullptr, kb, BT_, D_, D_);
  gemm_bias<0><<<g_dd, blk, 0, stream>>>(xn, Wv, bv, nullptr, vv, BT_, D_, D_);
  // 5. kb += spatial + edge
  add3_kernel<<<(int)(BTD / 4 / 256), blk, 0, stream>>>(kb, sp, ed, (int)(BTD / 4));
  // 6. scores -> d_out attn region
  scores_qkt<<<dim3(T_ / 64, T_ / 64, B_ * H_), blk, 0, stream>>>(q, kb, attn);
  // 7. softmax in place (this IS output #2)
  softmax_rows<<<B_ * H_ * T_, blk, 0, stream>>>(attn);
  // 8. ctx = attn @ V
  ctx_av<<<dim3(1, T_ / 64, B_ * H_), blk, 0, stream>>>(attn, vv, ctx);
  // 9. tt = ctx @ Wo + bo + xn (residual)
  gemm_bias<2><<<g_dd, blk, 0, stream>>>(ctx, Wo, bo, xn, tt, BT_, D_, D_);
  // 10. y = LN2(tt) -> reuse xn buffer
  ln_rows<<<BT_, blk, 0, stream>>>(tt, nullptr, ln2g, ln2b, xn);
  // 11. h1 = gelu(y @ W1 + b1)
  gemm_bias<1><<<dim3(F_ / 64, BT_ / 64), blk, 0, stream>>>(xn, W1, b1, nullptr, h1, BT_, F_, D_);
  // 12. h2 = h1 @ W2 + b2
  gemm_bias<0><<<g_dd, blk, 0, stream>>>(h1, W2, b2, nullptr, h2, BT_, D_, F_);
  // 13. out = LN(y + h2)
  ln_rows<<<BT_, blk, 0, stream>>>(xn, h2, lnbg, lnbb, out_x);
}

// Round 3
// 701.959 us; speedup vs baseline: 2.6907x; 2.6907x over previous
//
#include <hip/hip_runtime.h>
#include <hip/hip_bf16.h>
#include <math.h>

#define B_ 4
#define T_ 1024
#define D_ 1024
#define H_ 16
#define DH_ 64
#define F_ 4096
#define BT_ (B_ * T_)
#define BTD ((size_t)B_ * T_ * D_)

typedef short bf16x8 __attribute__((ext_vector_type(8)));
typedef float f32x4 __attribute__((ext_vector_type(4)));

__device__ __forceinline__ unsigned short f2b(float f) {
  __hip_bfloat16 h = __float2bfloat16(f);
  return *reinterpret_cast<unsigned short*>(&h);
}

__device__ __forceinline__ void gload16(const unsigned short* g, unsigned short* l) {
  __builtin_amdgcn_global_load_lds(
      (const __attribute__((address_space(1))) unsigned int*)(const void*)g,
      (__attribute__((address_space(3))) unsigned int*)(void*)l, 16, 0, 0);
}

__device__ __forceinline__ float gelu_f(float x) {
  float x3 = x * x * x;
  return 0.5f * x * (1.0f + tanhf(0.79788456080286536f * (x + 0.044715f * x3)));
}

// ---------------- block reductions (256 threads, wave64) ----------------
__device__ __forceinline__ float blk_sum256(float v, float* s4) {
#pragma unroll
  for (int off = 32; off > 0; off >>= 1) v += __shfl_down(v, off);
  if ((threadIdx.x & 63) == 0) s4[threadIdx.x >> 6] = v;
  __syncthreads();
  float t = s4[0] + s4[1] + s4[2] + s4[3];
  __syncthreads();
  return t;
}
__device__ __forceinline__ float blk_max256(float v, float* s4) {
#pragma unroll
  for (int off = 32; off > 0; off >>= 1) v = fmaxf(v, __shfl_down(v, off));
  if ((threadIdx.x & 63) == 0) s4[threadIdx.x >> 6] = v;
  __syncthreads();
  float t = fmaxf(fmaxf(s4[0], s4[1]), fmaxf(s4[2], s4[3]));
  __syncthreads();
  return t;
}

// ---------------- LayerNorm rows of D=1024, fp32 out + optional bf16 out ----
__global__ __launch_bounds__(256) void ln_rows(
    const float* __restrict__ in, const float* __restrict__ in2,
    const float* __restrict__ g, const float* __restrict__ bb,
    float* __restrict__ outf, unsigned short* __restrict__ outb) {
  __shared__ float s4[4];
  const size_t base = (size_t)blockIdx.x * D_;
  const int t = threadIdx.x;
  float4 v = ((const float4*)(in + base))[t];
  if (in2) {
    float4 w = ((const float4*)(in2 + base))[t];
    v.x += w.x; v.y += w.y; v.z += w.z; v.w += w.w;
  }
  float mean = blk_sum256(v.x + v.y + v.z + v.w, s4) * (1.0f / D_);
  float dx = v.x - mean, dy = v.y - mean, dz = v.z - mean, dw = v.w - mean;
  float var = blk_sum256(dx * dx + dy * dy + dz * dz + dw * dw, s4) * (1.0f / D_);
  float rstd = rsqrtf(var + 1e-5f);
  float4 gv = ((const float4*)g)[t];
  float4 bv = ((const float4*)bb)[t];
  float4 o;
  o.x = dx * rstd * gv.x + bv.x;
  o.y = dy * rstd * gv.y + bv.y;
  o.z = dz * rstd * gv.z + bv.z;
  o.w = dw * rstd * gv.w + bv.w;
  if (outf) ((float4*)(outf + base))[t] = o;
  if (outb) {
    unsigned short o4[4] = {f2b(o.x), f2b(o.y), f2b(o.z), f2b(o.w)};
    *(uint2*)(&outb[base + (size_t)t * 4]) = *(uint2*)o4;
  }
}

// ---------------- softmax rows of 1024 in place (fp32) ----------------
__global__ __launch_bounds__(256) void softmax_rows(float* __restrict__ p) {
  __shared__ float s4[4];
  float* row = p + (size_t)blockIdx.x * T_;
  const int t = threadIdx.x;
  float4 v = ((float4*)row)[t];
  float mx = blk_max256(fmaxf(fmaxf(v.x, v.y), fmaxf(v.z, v.w)), s4);
  v.x = __expf(v.x - mx); v.y = __expf(v.y - mx);
  v.z = __expf(v.z - mx); v.w = __expf(v.w - mx);
  float inv = 1.0f / blk_sum256(v.x + v.y + v.z + v.w, s4);
  v.x *= inv; v.y *= inv; v.z *= inv; v.w *= inv;
  ((float4*)row)[t] = v;
}

// ---------------- transpose+cast fp32 [R][C] -> bf16 [C][R] ----------------
__global__ __launch_bounds__(256) void tcast_t(
    const float* __restrict__ in, unsigned short* __restrict__ out, int R, int C) {
  __shared__ unsigned short tile[32][33];
  const int c0 = blockIdx.x * 32, r0 = blockIdx.y * 32;
  const int col = threadIdx.x & 31, rq = threadIdx.x >> 5;
#pragma unroll
  for (int i = 0; i < 4; ++i) {
    int r = rq + i * 8;
    tile[r][col] = f2b(in[(size_t)(r0 + r) * C + c0 + col]);
  }
  __syncthreads();
#pragma unroll
  for (int i = 0; i < 4; ++i) {
    int r = rq + i * 8;
    out[(size_t)(c0 + r) * R + r0 + col] = tile[col][r];
  }
}

// four 1024x1024 weights at once (z selects)
__global__ __launch_bounds__(256) void tcast4(
    const float* w0, const float* w1, const float* w2, const float* w3,
    unsigned short* o0, unsigned short* o1, unsigned short* o2, unsigned short* o3) {
  __shared__ unsigned short tile[32][33];
  const float* in = blockIdx.z == 0 ? w0 : blockIdx.z == 1 ? w1 : blockIdx.z == 2 ? w2 : w3;
  unsigned short* out = blockIdx.z == 0 ? o0 : blockIdx.z == 1 ? o1 : blockIdx.z == 2 ? o2 : o3;
  const int c0 = blockIdx.x * 32, r0 = blockIdx.y * 32;
  const int col = threadIdx.x & 31, rq = threadIdx.x >> 5;
#pragma unroll
  for (int i = 0; i < 4; ++i) {
    int r = rq + i * 8;
    tile[r][col] = f2b(in[(size_t)(r0 + r) * D_ + c0 + col]);
  }
  __syncthreads();
#pragma unroll
  for (int i = 0; i < 4; ++i) {
    int r = rq + i * 8;
    out[(size_t)(c0 + r) * D_ + r0 + col] = tile[col][r];
  }
}

// ---------------- scores[bh] = (Q_bh @ Kb_bh^T) / 8  (fp32, round-1) --------
__global__ __launch_bounds__(256) void scores_qkt(
    const float* __restrict__ q, const float* __restrict__ kb,
    float* __restrict__ out) {
  const int bh = blockIdx.z;
  const int b = bh >> 4, h = bh & 15;
  const float* Ab = q + (size_t)b * T_ * D_ + h * DH_;
  const float* Bb = kb + (size_t)b * T_ * D_ + h * DH_;
  float* Cb = out + (size_t)bh * T_ * T_;
  __shared__ float As[16][68];
  __shared__ float Bs[16][68];
  const int tid = threadIdx.x;
  const int tx = tid & 15, ty = tid >> 4;
  const int m0 = blockIdx.y * 64, n0 = blockIdx.x * 64;
  float acc[4][4] = {};
  for (int k0 = 0; k0 < DH_; k0 += 16) {
    const int k = tid & 15, r = tid >> 4;
#pragma unroll
    for (int i = 0; i < 4; ++i) {
      As[k][r + 16 * i] = Ab[(size_t)(m0 + r + 16 * i) * D_ + (k0 + k)];
      Bs[k][r + 16 * i] = Bb[(size_t)(n0 + r + 16 * i) * D_ + (k0 + k)];
    }
    __syncthreads();
#pragma unroll
    for (int kk = 0; kk < 16; ++kk) {
      const float4 a = *(const float4*)&As[kk][ty * 4];
      const float4 b = *(const float4*)&Bs[kk][tx * 4];
      const float av[4] = {a.x, a.y, a.z, a.w};
      const float bv[4] = {b.x, b.y, b.z, b.w};
#pragma unroll
      for (int i = 0; i < 4; ++i)
#pragma unroll
        for (int j = 0; j < 4; ++j)
          acc[i][j] = fmaf(av[i], bv[j], acc[i][j]);
    }
    __syncthreads();
  }
#pragma unroll
  for (int i = 0; i < 4; ++i)
#pragma unroll
    for (int j = 0; j < 4; ++j)
      Cb[(size_t)(m0 + ty * 4 + i) * T_ + (n0 + tx * 4 + j)] = acc[i][j] * 0.125f;
}

// ---------------- ctx[bh] = attn_bh @ V_bh (fp32 in, bf16 out) --------------
__global__ __launch_bounds__(256) void ctx_av(
    const float* __restrict__ attn, const float* __restrict__ v,
    unsigned short* __restrict__ ctxb) {
  const int bh = blockIdx.z;
  const int b = bh >> 4, h = bh & 15;
  const float* Ab = attn + (size_t)bh * T_ * T_;
  const float* Bb = v + (size_t)b * T_ * D_ + h * DH_;
  unsigned short* Cb = ctxb + (size_t)b * T_ * D_ + h * DH_;
  __shared__ float As[16][68];
  __shared__ float Bs[16][68];
  const int tid = threadIdx.x;
  const int tx = tid & 15, ty = tid >> 4;
  const int m0 = blockIdx.y * 64;
  float acc[4][4] = {};
  for (int k0 = 0; k0 < T_; k0 += 16) {
    {
      const int k = tid & 15, r = tid >> 4;
#pragma unroll
      for (int i = 0; i < 4; ++i)
        As[k][r + 16 * i] = Ab[(size_t)(m0 + r + 16 * i) * T_ + (k0 + k)];
    }
    {
      const int n = tid & 63, kq = tid >> 6;
#pragma unroll
      for (int i = 0; i < 4; ++i)
        Bs[kq + 4 * i][n] = Bb[(size_t)(k0 + kq + 4 * i) * D_ + n];
    }
    __syncthreads();
#pragma unroll
    for (int kk = 0; kk < 16; ++kk) {
      const float4 a = *(const float4*)&As[kk][ty * 4];
      const float4 b = *(const float4*)&Bs[kk][tx * 4];
      const float av[4] = {a.x, a.y, a.z, a.w};
      const float bv[4] = {b.x, b.y, b.z, b.w};
#pragma unroll
      for (int i = 0; i < 4; ++i)
#pragma unroll
        for (int j = 0; j < 4; ++j)
          acc[i][j] = fmaf(av[i], bv[j], acc[i][j]);
    }
    __syncthreads();
  }
#pragma unroll
  for (int i = 0; i < 4; ++i)
#pragma unroll
    for (int j = 0; j < 4; ++j)
      Cb[(size_t)(m0 + ty * 4 + i) * D_ + (tx * 4 + j)] = f2b(acc[i][j]);
}

// ---------------- MFMA NT GEMM: C[M][N] = A[M][K] @ Bn[N][K]^T ----------------
// BM=128, BK=64, 256 threads = 4 waves (2x2), wave tile 64 x (BN/2).
// EPI: 0=bias, 1=bias+gelu, 2=bias+res1, 3=scale only, 4=bias+res1+res2
template <int BN, int EPI, bool WF32, bool WB16>
__global__ __launch_bounds__(256) void gemm_nt(
    const unsigned short* __restrict__ A, int lda,
    const unsigned short* __restrict__ Bm, int ldb,
    float* __restrict__ Cf, unsigned short* __restrict__ Cb, int ldc,
    const float* __restrict__ bias, const float* __restrict__ r1,
    const float* __restrict__ r2, float scale, int K) {
  constexpr int BM = 128, BK = 64;
  constexpr int WN = BN / 2;
  constexpr int FN = WN / 16;
  __shared__ __align__(16) unsigned short As[BM * BK];
  __shared__ __align__(16) unsigned short Bs[BN * BK];
  const int tid = threadIdx.x;
  const int l = tid & 63;
  const int w = tid >> 6;
  const int wm = w >> 1, wn = w & 1;
  const unsigned short* Ab = A + (size_t)blockIdx.y * BM * lda;
  const unsigned short* Bb = Bm + (size_t)blockIdx.x * BN * ldb;

  const int ar = tid >> 3;
  const int ac = tid & 7;
  const int aswz = ((ac ^ (ar & 7)) << 3);

  f32x4 acc[4][FN] = {};

  for (int k0 = 0; k0 < K; k0 += BK) {
#pragma unroll
    for (int i = 0; i < 4; ++i)
      gload16(Ab + (size_t)(ar + 32 * i) * lda + k0 + aswz, &As[(size_t)(i * 256 + tid) * 8]);
#pragma unroll
    for (int i = 0; i < BN / 32; ++i)
      gload16(Bb + (size_t)(ar + 32 * i) * ldb + k0 + aswz, &Bs[(size_t)(i * 256 + tid) * 8]);
    __syncthreads();

    bf16x8 af[4][2], bfr[FN][2];
    const int lk = l >> 4;
#pragma unroll
    for (int mi = 0; mi < 4; ++mi) {
      const int row = wm * 64 + mi * 16 + (l & 15);
#pragma unroll
      for (int kk = 0; kk < 2; ++kk) {
        const int ch = (kk * 4 + lk) ^ (row & 7);
        af[mi][kk] = *(const bf16x8*)&As[row * BK + ch * 8];
      }
    }
#pragma unroll
    for (int ni = 0; ni < FN; ++ni) {
      const int row = wn * WN + ni * 16 + (l & 15);
#pragma unroll
      for (int kk = 0; kk < 2; ++kk) {
        const int ch = (kk * 4 + lk) ^ (row & 7);
        bfr[ni][kk] = *(const bf16x8*)&Bs[row * BK + ch * 8];
      }
    }
#pragma unroll
    for (int kk = 0; kk < 2; ++kk)
#pragma unroll
      for (int mi = 0; mi < 4; ++mi)
#pragma unroll
        for (int ni = 0; ni < FN; ++ni)
          acc[mi][ni] = __builtin_amdgcn_mfma_f32_16x16x32_bf16(
              af[mi][kk], bfr[ni][kk], acc[mi][ni], 0, 0, 0);
    __syncthreads();
  }

  const int crow0 = blockIdx.y * BM + wm * 64 + (l >> 4) * 4;
  const int ccol0 = blockIdx.x * BN + wn * WN + (l & 15);
#pragma unroll
  for (int mi = 0; mi < 4; ++mi)
#pragma unroll
    for (int ni = 0; ni < FN; ++ni)
#pragma unroll
      for (int r = 0; r < 4; ++r) {
        const int row = crow0 + mi * 16 + r;
        const int col = ccol0 + ni * 16;
        float v = acc[mi][ni][r] * scale;
        if (EPI != 3) v += bias[col];
        if (EPI == 1) v = gelu_f(v);
        const size_t off = (size_t)row * ldc + col;
        if (EPI == 2) v += r1[off];
        if (EPI == 4) v += r1[off] + r2[off];
        if (WF32) Cf[off] = v;
        if (WB16) Cb[off] = f2b(v);
      }
}

extern "C" void kernel_launch(void* const* d_in, const int* in_sizes, int n_in,
                              void* d_out, int out_size, void* d_ws, size_t ws_size,
                              hipStream_t stream) {
  const float* x    = (const float*)d_in[0];
  const float* sp   = (const float*)d_in[1];
  const float* ed   = (const float*)d_in[2];
  const float* ln1g = (const float*)d_in[3];
  const float* ln1b = (const float*)d_in[4];
  const float* Wq   = (const float*)d_in[5];
  const float* bq   = (const float*)d_in[6];
  const float* Wk   = (const float*)d_in[7];
  const float* bk   = (const float*)d_in[8];
  const float* Wv   = (const float*)d_in[9];
  const float* bvv  = (const float*)d_in[10];
  const float* Wo   = (const float*)d_in[11];
  const float* bo   = (const float*)d_in[12];
  const float* ln2g = (const float*)d_in[13];
  const float* ln2b = (const float*)d_in[14];
  const float* W1   = (const float*)d_in[15];
  const float* b1   = (const float*)d_in[16];
  const float* W2   = (const float*)d_in[17];
  const float* b2   = (const float*)d_in[18];
  const float* lnbg = (const float*)d_in[19];
  const float* lnbb = (const float*)d_in[20];

  float* out_x = (float*)d_out;        // B*T*D fp32
  float* attn  = out_x + BTD;          // B*H*T*T fp32 (output #2)
  float* tt    = out_x;                // post-Wo+residual scratch in out x region

  const size_t MB = 1 << 20;
  char* wsb = (char*)d_ws;
  float*          xn    = (float*)(wsb);                    // [0,16) fp32; reused as y
  unsigned short* xn_b  = (unsigned short*)(wsb + 16 * MB); // [16,24): xn_b -> ctx_b -> y_b
  unsigned short* WqT   = (unsigned short*)(wsb + 24 * MB);
  unsigned short* WkT   = (unsigned short*)(wsb + 26 * MB);
  unsigned short* WvT   = (unsigned short*)(wsb + 28 * MB);
  unsigned short* WoT   = (unsigned short*)(wsb + 30 * MB);
  unsigned short* W1T   = (unsigned short*)(wsb + 32 * MB); // [32,40)
  unsigned short* W2T   = (unsigned short*)(wsb + 40 * MB); // [40,48)
  float*          q     = (float*)(wsb + 48 * MB);          // [48,64) fp32
  float*          kb    = (float*)(wsb + 64 * MB);          // [64,80) fp32
  float*          vv    = (float*)(wsb + 80 * MB);          // [80,96) fp32
  unsigned short* ctx_b = xn_b;                             // [16,24) (xn_b dead after QKV)
  unsigned short* h1_b  = (unsigned short*)(wsb + 48 * MB); // [48,80) over q,kb (dead)
  float*          h2    = (float*)(wsb + 80 * MB);          // [80,96) over vv (dead)
  float*          y     = xn;
  unsigned short* y_b   = xn_b;

  dim3 blk(256);
  dim3 g_dd(8, 32);

  // 1. LN1 -> xn (fp32 residual) + xn_b (bf16 GEMM operand)
  ln_rows<<<BT_, blk, 0, stream>>>(x, nullptr, ln1g, ln1b, xn, xn_b);
  // 2. weight transpose+cast
  tcast4<<<dim3(32, 32, 4), blk, 0, stream>>>(Wq, Wk, Wv, Wo, WqT, WkT, WvT, WoT);
  tcast_t<<<dim3(128, 32), blk, 0, stream>>>(W1, W1T, 1024, 4096);
  tcast_t<<<dim3(32, 128), blk, 0, stream>>>(W2, W2T, 4096, 1024);
  // 3-5. Q, K(+sp+ed), V -> fp32 (MFMA)
  gemm_nt<128, 0, true, false><<<g_dd, blk, 0, stream>>>(
      xn_b, D_, WqT, D_, q, nullptr, D_, bq, nullptr, nullptr, 1.f, D_);
  gemm_nt<128, 4, true, false><<<g_dd, blk, 0, stream>>>(
      xn_b, D_, WkT, D_, kb, nullptr, D_, bk, sp, ed, 1.f, D_);
  gemm_nt<128, 0, true, false><<<g_dd, blk, 0, stream>>>(
      xn_b, D_, WvT, D_, vv, nullptr, D_, bvv, nullptr, nullptr, 1.f, D_);
  // 6. scores = Q @ Kb^T / 8 -> d_out attn region (fp32 vector kernel)
  scores_qkt<<<dim3(16, 16, 64), blk, 0, stream>>>(q, kb, attn);
  // 7. softmax in place (fp32)
  softmax_rows<<<B_ * H_ * T_, blk, 0, stream>>>(attn);
  // 8. ctx = attn @ V -> bf16 (fp32 vector kernel)
  ctx_av<<<dim3(1, 16, 64), blk, 0, stream>>>(attn, vv, ctx_b);
  // 9. tt = ctx @ Wo + bo + xn (MFMA)
  gemm_nt<128, 2, true, false><<<g_dd, blk, 0, stream>>>(
      ctx_b, D_, WoT, D_, tt, nullptr, D_, bo, xn, nullptr, 1.f, D_);
  // 10. y = LN2(tt)
  ln_rows<<<BT_, blk, 0, stream>>>(tt, nullptr, ln2g, ln2b, y, y_b);
  // 11. h1 = gelu(y @ W1 + b1) -> bf16 (MFMA)
  gemm_nt<128, 1, false, true><<<dim3(32, 32), blk, 0, stream>>>(
      y_b, D_, W1T, D_, nullptr, h1_b, F_, b1, nullptr, nullptr, 1.f, D_);
  // 12. h2 = h1 @ W2 + b2 (MFMA, fp32 out)
  gemm_nt<128, 0, true, false><<<g_dd, blk, 0, stream>>>(
      h1_b, F_, W2T, F_, h2, nullptr, D_, b2, nullptr, nullptr, 1.f, F_);
  // 13. out = LN(y + h2)
  ln_rows<<<BT_, blk, 0, stream>>>(y, h2, lnbg, lnbb, out_x, nullptr);
}

// Round 4
// 622.368 us; speedup vs baseline: 3.0348x; 1.1279x over previous
//
#include <hip/hip_runtime.h>
#include <hip/hip_bf16.h>
#include <hip/hip_fp16.h>
#include <math.h>

#define B_ 4
#define T_ 1024
#define D_ 1024
#define H_ 16
#define DH_ 64
#define F_ 4096
#define BT_ (B_ * T_)
#define BTD ((size_t)B_ * T_ * D_)

typedef short bf16x8 __attribute__((ext_vector_type(8)));
typedef _Float16 f16x8 __attribute__((ext_vector_type(8)));
typedef float f32x4 __attribute__((ext_vector_type(4)));

__device__ __forceinline__ unsigned short f2b(float f) {
  __hip_bfloat16 h = __float2bfloat16(f);
  return *reinterpret_cast<unsigned short*>(&h);
}
__device__ __forceinline__ unsigned short f2h(float f) {
  __half h = __float2half(f);
  return *reinterpret_cast<unsigned short*>(&h);
}

__device__ __forceinline__ void gload16(const unsigned short* g, unsigned short* l) {
  __builtin_amdgcn_global_load_lds(
      (const __attribute__((address_space(1))) unsigned int*)(const void*)g,
      (__attribute__((address_space(3))) unsigned int*)(void*)l, 16, 0, 0);
}

__device__ __forceinline__ float gelu_f(float x) {
  float x3 = x * x * x;
  return 0.5f * x * (1.0f + tanhf(0.79788456080286536f * (x + 0.044715f * x3)));
}

// ---------------- block reductions (256 threads, wave64) ----------------
__device__ __forceinline__ float blk_sum256(float v, float* s4) {
#pragma unroll
  for (int off = 32; off > 0; off >>= 1) v += __shfl_down(v, off);
  if ((threadIdx.x & 63) == 0) s4[threadIdx.x >> 6] = v;
  __syncthreads();
  float t = s4[0] + s4[1] + s4[2] + s4[3];
  __syncthreads();
  return t;
}
__device__ __forceinline__ float blk_max256(float v, float* s4) {
#pragma unroll
  for (int off = 32; off > 0; off >>= 1) v = fmaxf(v, __shfl_down(v, off));
  if ((threadIdx.x & 63) == 0) s4[threadIdx.x >> 6] = v;
  __syncthreads();
  float t = fmaxf(fmaxf(s4[0], s4[1]), fmaxf(s4[2], s4[3]));
  __syncthreads();
  return t;
}

// ---------------- LayerNorm rows of D=1024, fp32 out + optional bf16 out ----
__global__ __launch_bounds__(256) void ln_rows(
    const float* __restrict__ in, const float* __restrict__ in2,
    const float* __restrict__ g, const float* __restrict__ bb,
    float* __restrict__ outf, unsigned short* __restrict__ outb) {
  __shared__ float s4[4];
  const size_t base = (size_t)blockIdx.x * D_;
  const int t = threadIdx.x;
  float4 v = ((const float4*)(in + base))[t];
  if (in2) {
    float4 w = ((const float4*)(in2 + base))[t];
    v.x += w.x; v.y += w.y; v.z += w.z; v.w += w.w;
  }
  float mean = blk_sum256(v.x + v.y + v.z + v.w, s4) * (1.0f / D_);
  float dx = v.x - mean, dy = v.y - mean, dz = v.z - mean, dw = v.w - mean;
  float var = blk_sum256(dx * dx + dy * dy + dz * dz + dw * dw, s4) * (1.0f / D_);
  float rstd = rsqrtf(var + 1e-5f);
  float4 gv = ((const float4*)g)[t];
  float4 bv = ((const float4*)bb)[t];
  float4 o;
  o.x = dx * rstd * gv.x + bv.x;
  o.y = dy * rstd * gv.y + bv.y;
  o.z = dz * rstd * gv.z + bv.z;
  o.w = dw * rstd * gv.w + bv.w;
  if (outf) ((float4*)(outf + base))[t] = o;
  if (outb) {
    unsigned short o4[4] = {f2b(o.x), f2b(o.y), f2b(o.z), f2b(o.w)};
    *(uint2*)(&outb[base + (size_t)t * 4]) = *(uint2*)o4;
  }
}

// ---------------- softmax rows of 1024 in place (fp32) ----------------
__global__ __launch_bounds__(256) void softmax_rows(float* __restrict__ p) {
  __shared__ float s4[4];
  float* row = p + (size_t)blockIdx.x * T_;
  const int t = threadIdx.x;
  float4 v = ((float4*)row)[t];
  float mx = blk_max256(fmaxf(fmaxf(v.x, v.y), fmaxf(v.z, v.w)), s4);
  v.x = __expf(v.x - mx); v.y = __expf(v.y - mx);
  v.z = __expf(v.z - mx); v.w = __expf(v.w - mx);
  float inv = 1.0f / blk_sum256(v.x + v.y + v.z + v.w, s4);
  v.x *= inv; v.y *= inv; v.z *= inv; v.w *= inv;
  ((float4*)row)[t] = v;
}

// ---------------- transpose+cast fp32 [R][C] -> bf16 [C][R] ----------------
__global__ __launch_bounds__(256) void tcast_t(
    const float* __restrict__ in, unsigned short* __restrict__ out, int R, int C) {
  __shared__ unsigned short tile[32][33];
  const int c0 = blockIdx.x * 32, r0 = blockIdx.y * 32;
  const int col = threadIdx.x & 31, rq = threadIdx.x >> 5;
#pragma unroll
  for (int i = 0; i < 4; ++i) {
    int r = rq + i * 8;
    tile[r][col] = f2b(in[(size_t)(r0 + r) * C + c0 + col]);
  }
  __syncthreads();
#pragma unroll
  for (int i = 0; i < 4; ++i) {
    int r = rq + i * 8;
    out[(size_t)(c0 + r) * R + r0 + col] = tile[col][r];
  }
}

// four 1024x1024 weights at once (z selects)
__global__ __launch_bounds__(256) void tcast4(
    const float* w0, const float* w1, const float* w2, const float* w3,
    unsigned short* o0, unsigned short* o1, unsigned short* o2, unsigned short* o3) {
  __shared__ unsigned short tile[32][33];
  const float* in = blockIdx.z == 0 ? w0 : blockIdx.z == 1 ? w1 : blockIdx.z == 2 ? w2 : w3;
  unsigned short* out = blockIdx.z == 0 ? o0 : blockIdx.z == 1 ? o1 : blockIdx.z == 2 ? o2 : o3;
  const int c0 = blockIdx.x * 32, r0 = blockIdx.y * 32;
  const int col = threadIdx.x & 31, rq = threadIdx.x >> 5;
#pragma unroll
  for (int i = 0; i < 4; ++i) {
    int r = rq + i * 8;
    tile[r][col] = f2b(in[(size_t)(r0 + r) * D_ + c0 + col]);
  }
  __syncthreads();
#pragma unroll
  for (int i = 0; i < 4; ++i) {
    int r = rq + i * 8;
    out[(size_t)(c0 + r) * D_ + r0 + col] = tile[col][r];
  }
}

// ---------------- scores (MFMA f16, standalone): attn[bh][t][s] = Q.Kb^T/8 --
// grid (8, 8, 64): x = s-tile (BN=128), y = t-tile (BM=128), z = b*16+h.
// Q,K are f16 [B][T][D], head h occupies cols [h*64, h*64+64). K-depth = 64.
__global__ __launch_bounds__(256) void scores_mfma(
    const unsigned short* __restrict__ qh, const unsigned short* __restrict__ kh,
    float* __restrict__ attn) {
  constexpr int BM = 128, BN = 128, BK = 64;
  __shared__ __align__(16) unsigned short As[BM * BK];
  __shared__ __align__(16) unsigned short Bs[BN * BK];
  const int tid = threadIdx.x;
  const int l = tid & 63, w = tid >> 6;
  const int wm = w >> 1, wn = w & 1;
  const int bh = blockIdx.z, b = bh >> 4, h = bh & 15;
  const unsigned short* Ab = qh + (size_t)b * T_ * D_ + h * DH_ + (size_t)blockIdx.y * BM * D_;
  const unsigned short* Bb = kh + (size_t)b * T_ * D_ + h * DH_ + (size_t)blockIdx.x * BN * D_;

  // staging: chunk c = i*256+tid -> LDS row c>>3, chunk c&7 (linear); global
  // source chunk is XORed with row&7 (T2: swizzle source, linear dest).
  const int ar = tid >> 3, ac = tid & 7;
  const int aswz = ((ac ^ (ar & 7)) << 3);
#pragma unroll
  for (int i = 0; i < 4; ++i) {
    gload16(Ab + (size_t)(ar + 32 * i) * D_ + aswz, &As[(size_t)(i * 256 + tid) * 8]);
    gload16(Bb + (size_t)(ar + 32 * i) * D_ + aswz, &Bs[(size_t)(i * 256 + tid) * 8]);
  }
  __syncthreads();

  const int lk = l >> 4, lr = l & 15;
  f16x8 af[4][2], bfr[4][2];
#pragma unroll
  for (int mi = 0; mi < 4; ++mi) {
    const int row = wm * 64 + mi * 16 + lr;
#pragma unroll
    for (int kk = 0; kk < 2; ++kk) {
      const int ch = (kk * 4 + lk) ^ (row & 7);
      af[mi][kk] = *(const f16x8*)&As[row * BK + ch * 8];
    }
  }
#pragma unroll
  for (int ni = 0; ni < 4; ++ni) {
    const int row = wn * 64 + ni * 16 + lr;
#pragma unroll
    for (int kk = 0; kk < 2; ++kk) {
      const int ch = (kk * 4 + lk) ^ (row & 7);
      bfr[ni][kk] = *(const f16x8*)&Bs[row * BK + ch * 8];
    }
  }
  f32x4 acc[4][4] = {};
#pragma unroll
  for (int kk = 0; kk < 2; ++kk)
#pragma unroll
    for (int mi = 0; mi < 4; ++mi)
#pragma unroll
      for (int ni = 0; ni < 4; ++ni)
        acc[mi][ni] = __builtin_amdgcn_mfma_f32_16x16x32_f16(
            af[mi][kk], bfr[ni][kk], acc[mi][ni], 0, 0, 0);

  float* Cb = attn + (size_t)bh * T_ * T_;
  const int crow0 = blockIdx.y * BM + wm * 64 + lk * 4;
  const int ccol0 = blockIdx.x * BN + wn * 64 + lr;
#pragma unroll
  for (int mi = 0; mi < 4; ++mi)
#pragma unroll
    for (int ni = 0; ni < 4; ++ni)
#pragma unroll
      for (int r = 0; r < 4; ++r)
        Cb[(size_t)(crow0 + mi * 16 + r) * T_ + (ccol0 + ni * 16)] = acc[mi][ni][r] * 0.125f;
}

// ---------------- ctx[bh] = attn_bh @ V_bh (fp32 in, bf16 out) --------------
__global__ __launch_bounds__(256) void ctx_av(
    const float* __restrict__ attn, const float* __restrict__ v,
    unsigned short* __restrict__ ctxb) {
  const int bh = blockIdx.z;
  const int b = bh >> 4, h = bh & 15;
  const float* Ab = attn + (size_t)bh * T_ * T_;
  const float* Bb = v + (size_t)b * T_ * D_ + h * DH_;
  unsigned short* Cb = ctxb + (size_t)b * T_ * D_ + h * DH_;
  __shared__ float As[16][68];
  __shared__ float Bs[16][68];
  const int tid = threadIdx.x;
  const int tx = tid & 15, ty = tid >> 4;
  const int m0 = blockIdx.y * 64;
  float acc[4][4] = {};
  for (int k0 = 0; k0 < T_; k0 += 16) {
    {
      const int k = tid & 15, r = tid >> 4;
#pragma unroll
      for (int i = 0; i < 4; ++i)
        As[k][r + 16 * i] = Ab[(size_t)(m0 + r + 16 * i) * T_ + (k0 + k)];
    }
    {
      const int n = tid & 63, kq = tid >> 6;
#pragma unroll
      for (int i = 0; i < 4; ++i)
        Bs[kq + 4 * i][n] = Bb[(size_t)(k0 + kq + 4 * i) * D_ + n];
    }
    __syncthreads();
#pragma unroll
    for (int kk = 0; kk < 16; ++kk) {
      const float4 a = *(const float4*)&As[kk][ty * 4];
      const float4 b = *(const float4*)&Bs[kk][tx * 4];
      const float av[4] = {a.x, a.y, a.z, a.w};
      const float bv[4] = {b.x, b.y, b.z, b.w};
#pragma unroll
      for (int i = 0; i < 4; ++i)
#pragma unroll
        for (int j = 0; j < 4; ++j)
          acc[i][j] = fmaf(av[i], bv[j], acc[i][j]);
    }
    __syncthreads();
  }
#pragma unroll
  for (int i = 0; i < 4; ++i)
#pragma unroll
    for (int j = 0; j < 4; ++j)
      Cb[(size_t)(m0 + ty * 4 + i) * D_ + (tx * 4 + j)] = f2b(acc[i][j]);
}

// ---------------- MFMA NT GEMM: C[M][N] = A[M][K] @ Bn[N][K]^T ----------------
// BM=128, BK=64, 256 threads = 4 waves (2x2), wave tile 64 x (BN/2).
// EPI: 0=bias, 1=bias+gelu, 2=bias+res1, 3=scale only, 4=bias+res1+res2
// W16 writes 16-bit: FP16 ? f16 : bf16.
template <int BN, int EPI, bool WF32, bool W16, bool FP16 = false>
__global__ __launch_bounds__(256) void gemm_nt(
    const unsigned short* __restrict__ A, int lda,
    const unsigned short* __restrict__ Bm, int ldb,
    float* __restrict__ Cf, unsigned short* __restrict__ Cb, int ldc,
    const float* __restrict__ bias, const float* __restrict__ r1,
    const float* __restrict__ r2, float scale, int K) {
  constexpr int BM = 128, BK = 64;
  constexpr int WN = BN / 2;
  constexpr int FN = WN / 16;
  __shared__ __align__(16) unsigned short As[BM * BK];
  __shared__ __align__(16) unsigned short Bs[BN * BK];
  const int tid = threadIdx.x;
  const int l = tid & 63;
  const int w = tid >> 6;
  const int wm = w >> 1, wn = w & 1;
  const unsigned short* Ab = A + (size_t)blockIdx.y * BM * lda;
  const unsigned short* Bb = Bm + (size_t)blockIdx.x * BN * ldb;

  const int ar = tid >> 3;
  const int ac = tid & 7;
  const int aswz = ((ac ^ (ar & 7)) << 3);

  f32x4 acc[4][FN] = {};

  for (int k0 = 0; k0 < K; k0 += BK) {
#pragma unroll
    for (int i = 0; i < 4; ++i)
      gload16(Ab + (size_t)(ar + 32 * i) * lda + k0 + aswz, &As[(size_t)(i * 256 + tid) * 8]);
#pragma unroll
    for (int i = 0; i < BN / 32; ++i)
      gload16(Bb + (size_t)(ar + 32 * i) * ldb + k0 + aswz, &Bs[(size_t)(i * 256 + tid) * 8]);
    __syncthreads();

    bf16x8 af[4][2], bfr[FN][2];
    const int lk = l >> 4;
#pragma unroll
    for (int mi = 0; mi < 4; ++mi) {
      const int row = wm * 64 + mi * 16 + (l & 15);
#pragma unroll
      for (int kk = 0; kk < 2; ++kk) {
        const int ch = (kk * 4 + lk) ^ (row & 7);
        af[mi][kk] = *(const bf16x8*)&As[row * BK + ch * 8];
      }
    }
#pragma unroll
    for (int ni = 0; ni < FN; ++ni) {
      const int row = wn * WN + ni * 16 + (l & 15);
#pragma unroll
      for (int kk = 0; kk < 2; ++kk) {
        const int ch = (kk * 4 + lk) ^ (row & 7);
        bfr[ni][kk] = *(const bf16x8*)&Bs[row * BK + ch * 8];
      }
    }
#pragma unroll
    for (int kk = 0; kk < 2; ++kk)
#pragma unroll
      for (int mi = 0; mi < 4; ++mi)
#pragma unroll
        for (int ni = 0; ni < FN; ++ni)
          acc[mi][ni] = __builtin_amdgcn_mfma_f32_16x16x32_bf16(
              af[mi][kk], bfr[ni][kk], acc[mi][ni], 0, 0, 0);
    __syncthreads();
  }

  const int crow0 = blockIdx.y * BM + wm * 64 + (l >> 4) * 4;
  const int ccol0 = blockIdx.x * BN + wn * WN + (l & 15);
#pragma unroll
  for (int mi = 0; mi < 4; ++mi)
#pragma unroll
    for (int ni = 0; ni < FN; ++ni)
#pragma unroll
      for (int r = 0; r < 4; ++r) {
        const int row = crow0 + mi * 16 + r;
        const int col = ccol0 + ni * 16;
        float v = acc[mi][ni][r] * scale;
        if (EPI != 3) v += bias[col];
        if (EPI == 1) v = gelu_f(v);
        const size_t off = (size_t)row * ldc + col;
        if (EPI == 2) v += r1[off];
        if (EPI == 4) v += r1[off] + r2[off];
        if (WF32) Cf[off] = v;
        if (W16) Cb[off] = FP16 ? f2h(v) : f2b(v);
      }
}

extern "C" void kernel_launch(void* const* d_in, const int* in_sizes, int n_in,
                              void* d_out, int out_size, void* d_ws, size_t ws_size,
                              hipStream_t stream) {
  const float* x    = (const float*)d_in[0];
  const float* sp   = (const float*)d_in[1];
  const float* ed   = (const float*)d_in[2];
  const float* ln1g = (const float*)d_in[3];
  const float* ln1b = (const float*)d_in[4];
  const float* Wq   = (const float*)d_in[5];
  const float* bq   = (const float*)d_in[6];
  const float* Wk   = (const float*)d_in[7];
  const float* bk   = (const float*)d_in[8];
  const float* Wv   = (const float*)d_in[9];
  const float* bvv  = (const float*)d_in[10];
  const float* Wo   = (const float*)d_in[11];
  const float* bo   = (const float*)d_in[12];
  const float* ln2g = (const float*)d_in[13];
  const float* ln2b = (const float*)d_in[14];
  const float* W1   = (const float*)d_in[15];
  const float* b1   = (const float*)d_in[16];
  const float* W2   = (const float*)d_in[17];
  const float* b2   = (const float*)d_in[18];
  const float* lnbg = (const float*)d_in[19];
  const float* lnbb = (const float*)d_in[20];

  float* out_x = (float*)d_out;        // B*T*D fp32
  float* attn  = out_x + BTD;          // B*H*T*T fp32 (output #2)
  float* tt    = out_x;                // post-Wo+residual scratch in out x region

  const size_t MB = 1 << 20;
  char* wsb = (char*)d_ws;
  float*          xn    = (float*)(wsb);                    // [0,16) fp32; reused as y
  unsigned short* xn_b  = (unsigned short*)(wsb + 16 * MB); // [16,24): xn_b -> ctx_b -> y_b
  unsigned short* WqT   = (unsigned short*)(wsb + 24 * MB);
  unsigned short* WkT   = (unsigned short*)(wsb + 26 * MB);
  unsigned short* WvT   = (unsigned short*)(wsb + 28 * MB);
  unsigned short* WoT   = (unsigned short*)(wsb + 30 * MB);
  unsigned short* W1T   = (unsigned short*)(wsb + 32 * MB); // [32,40)
  unsigned short* W2T   = (unsigned short*)(wsb + 40 * MB); // [40,48)
  unsigned short* q_h   = (unsigned short*)(wsb + 48 * MB); // [48,56) f16
  unsigned short* kb_h  = (unsigned short*)(wsb + 56 * MB); // [56,64) f16
  float*          vv    = (float*)(wsb + 64 * MB);          // [64,80) fp32
  unsigned short* ctx_b = xn_b;                             // [16,24) (xn_b dead after QKV)
  unsigned short* h1_b  = (unsigned short*)(wsb + 48 * MB); // [48,80) over q_h,kb_h,vv (dead)
  float*          h2    = (float*)(wsb + 80 * MB);          // [80,96)
  float*          y     = xn;
  unsigned short* y_b   = xn_b;

  dim3 blk(256);
  dim3 g_dd(8, 32);

  // 1. LN1 -> xn (fp32 residual) + xn_b (bf16 GEMM operand)
  ln_rows<<<BT_, blk, 0, stream>>>(x, nullptr, ln1g, ln1b, xn, xn_b);
  // 2. weight transpose+cast
  tcast4<<<dim3(32, 32, 4), blk, 0, stream>>>(Wq, Wk, Wv, Wo, WqT, WkT, WvT, WoT);
  tcast_t<<<dim3(128, 32), blk, 0, stream>>>(W1, W1T, 1024, 4096);
  tcast_t<<<dim3(32, 128), blk, 0, stream>>>(W2, W2T, 4096, 1024);
  // 3-5. Q -> f16, K(+sp+ed) -> f16, V -> fp32 (MFMA)
  gemm_nt<128, 0, false, true, true><<<g_dd, blk, 0, stream>>>(
      xn_b, D_, WqT, D_, nullptr, q_h, D_, bq, nullptr, nullptr, 1.f, D_);
  gemm_nt<128, 4, false, true, true><<<g_dd, blk, 0, stream>>>(
      xn_b, D_, WkT, D_, nullptr, kb_h, D_, bk, sp, ed, 1.f, D_);
  gemm_nt<128, 0, true, false><<<g_dd, blk, 0, stream>>>(
      xn_b, D_, WvT, D_, vv, nullptr, D_, bvv, nullptr, nullptr, 1.f, D_);
  // 6. scores = Q @ Kb^T / 8 -> d_out attn region (MFMA f16, standalone)
  scores_mfma<<<dim3(8, 8, 64), blk, 0, stream>>>(q_h, kb_h, attn);
  // 7. softmax in place (fp32)
  softmax_rows<<<B_ * H_ * T_, blk, 0, stream>>>(attn);
  // 8. ctx = attn @ V -> bf16 (fp32 vector kernel)
  ctx_av<<<dim3(1, 16, 64), blk, 0, stream>>>(attn, vv, ctx_b);
  // 9. tt = ctx @ Wo + bo + xn (MFMA)
  gemm_nt<128, 2, true, false><<<g_dd, blk, 0, stream>>>(
      ctx_b, D_, WoT, D_, tt, nullptr, D_, bo, xn, nullptr, 1.f, D_);
  // 10. y = LN2(tt)
  ln_rows<<<BT_, blk, 0, stream>>>(tt, nullptr, ln2g, ln2b, y, y_b);
  // 11. h1 = gelu(y @ W1 + b1) -> bf16 (MFMA)
  gemm_nt<128, 1, false, true><<<dim3(32, 32), blk, 0, stream>>>(
      y_b, D_, W1T, D_, nullptr, h1_b, F_, b1, nullptr, nullptr, 1.f, D_);
  // 12. h2 = h1 @ W2 + b2 (MFMA, fp32 out)
  gemm_nt<128, 0, true, false><<<g_dd, blk, 0, stream>>>(
      h1_b, F_, W2T, F_, h2, nullptr, D_, b2, nullptr, nullptr, 1.f, F_);
  // 13. out = LN(y + h2)
  ln_rows<<<BT_, blk, 0, stream>>>(y, h2, lnbg, lnbb, out_x, nullptr);
}

// Round 6
// 543.900 us; speedup vs baseline: 3.4726x; 1.1443x over previous
//
#include <hip/hip_runtime.h>
#include <hip/hip_bf16.h>
#include <hip/hip_fp16.h>
#include <math.h>

#define B_ 4
#define T_ 1024
#define D_ 1024
#define H_ 16
#define DH_ 64
#define F_ 4096
#define BT_ (B_ * T_)
#define BTD ((size_t)B_ * T_ * D_)

typedef short bf16x8 __attribute__((ext_vector_type(8)));
typedef _Float16 f16x8 __attribute__((ext_vector_type(8)));
typedef float f32x4 __attribute__((ext_vector_type(4)));

__device__ __forceinline__ unsigned short f2b(float f) {
  __hip_bfloat16 h = __float2bfloat16(f);
  return *reinterpret_cast<unsigned short*>(&h);
}
__device__ __forceinline__ unsigned short f2h(float f) {
  __half h = __float2half(f);
  return *reinterpret_cast<unsigned short*>(&h);
}

__device__ __forceinline__ void gload16(const unsigned short* g, unsigned short* l) {
  __builtin_amdgcn_global_load_lds(
      (const __attribute__((address_space(1))) unsigned int*)(const void*)g,
      (__attribute__((address_space(3))) unsigned int*)(void*)l, 16, 0, 0);
}

__device__ __forceinline__ float gelu_f(float x) {
  float x3 = x * x * x;
  return 0.5f * x * (1.0f + tanhf(0.79788456080286536f * (x + 0.044715f * x3)));
}

// ---------------- block reductions (256 threads, wave64) ----------------
__device__ __forceinline__ float blk_sum256(float v, float* s4) {
#pragma unroll
  for (int off = 32; off > 0; off >>= 1) v += __shfl_down(v, off);
  if ((threadIdx.x & 63) == 0) s4[threadIdx.x >> 6] = v;
  __syncthreads();
  float t = s4[0] + s4[1] + s4[2] + s4[3];
  __syncthreads();
  return t;
}
__device__ __forceinline__ float blk_max256(float v, float* s4) {
#pragma unroll
  for (int off = 32; off > 0; off >>= 1) v = fmaxf(v, __shfl_down(v, off));
  if ((threadIdx.x & 63) == 0) s4[threadIdx.x >> 6] = v;
  __syncthreads();
  float t = fmaxf(fmaxf(s4[0], s4[1]), fmaxf(s4[2], s4[3]));
  __syncthreads();
  return t;
}

// ---------------- LayerNorm rows of D=1024, fp32 out + optional bf16 out ----
__global__ __launch_bounds__(256) void ln_rows(
    const float* __restrict__ in, const float* __restrict__ in2,
    const float* __restrict__ g, const float* __restrict__ bb,
    float* __restrict__ outf, unsigned short* __restrict__ outb) {
  __shared__ float s4[4];
  const size_t base = (size_t)blockIdx.x * D_;
  const int t = threadIdx.x;
  float4 v = ((const float4*)(in + base))[t];
  if (in2) {
    float4 w = ((const float4*)(in2 + base))[t];
    v.x += w.x; v.y += w.y; v.z += w.z; v.w += w.w;
  }
  float mean = blk_sum256(v.x + v.y + v.z + v.w, s4) * (1.0f / D_);
  float dx = v.x - mean, dy = v.y - mean, dz = v.z - mean, dw = v.w - mean;
  float var = blk_sum256(dx * dx + dy * dy + dz * dz + dw * dw, s4) * (1.0f / D_);
  float rstd = rsqrtf(var + 1e-5f);
  float4 gv = ((const float4*)g)[t];
  float4 bv = ((const float4*)bb)[t];
  float4 o;
  o.x = dx * rstd * gv.x + bv.x;
  o.y = dy * rstd * gv.y + bv.y;
  o.z = dz * rstd * gv.z + bv.z;
  o.w = dw * rstd * gv.w + bv.w;
  if (outf) ((float4*)(outf + base))[t] = o;
  if (outb) {
    unsigned short o4[4] = {f2b(o.x), f2b(o.y), f2b(o.z), f2b(o.w)};
    *(uint2*)(&outb[base + (size_t)t * 4]) = *(uint2*)o4;
  }
}

// ---------------- softmax rows of 1024 in place (fp32) ----------------
__global__ __launch_bounds__(256) void softmax_rows(float* __restrict__ p) {
  __shared__ float s4[4];
  float* row = p + (size_t)blockIdx.x * T_;
  const int t = threadIdx.x;
  float4 v = ((float4*)row)[t];
  float mx = blk_max256(fmaxf(fmaxf(v.x, v.y), fmaxf(v.z, v.w)), s4);
  v.x = __expf(v.x - mx); v.y = __expf(v.y - mx);
  v.z = __expf(v.z - mx); v.w = __expf(v.w - mx);
  float inv = 1.0f / blk_sum256(v.x + v.y + v.z + v.w, s4);
  v.x *= inv; v.y *= inv; v.z *= inv; v.w *= inv;
  ((float4*)row)[t] = v;
}

// ---------------- transpose+cast fp32 [R][C] -> bf16 [C][R] ----------------
__global__ __launch_bounds__(256) void tcast_t(
    const float* __restrict__ in, unsigned short* __restrict__ out, int R, int C) {
  __shared__ unsigned short tile[32][33];
  const int c0 = blockIdx.x * 32, r0 = blockIdx.y * 32;
  const int col = threadIdx.x & 31, rq = threadIdx.x >> 5;
#pragma unroll
  for (int i = 0; i < 4; ++i) {
    int r = rq + i * 8;
    tile[r][col] = f2b(in[(size_t)(r0 + r) * C + c0 + col]);
  }
  __syncthreads();
#pragma unroll
  for (int i = 0; i < 4; ++i) {
    int r = rq + i * 8;
    out[(size_t)(c0 + r) * R + r0 + col] = tile[col][r];
  }
}

// four 1024x1024 weights at once (z selects)
__global__ __launch_bounds__(256) void tcast4(
    const float* w0, const float* w1, const float* w2, const float* w3,
    unsigned short* o0, unsigned short* o1, unsigned short* o2, unsigned short* o3) {
  __shared__ unsigned short tile[32][33];
  const float* in = blockIdx.z == 0 ? w0 : blockIdx.z == 1 ? w1 : blockIdx.z == 2 ? w2 : w3;
  unsigned short* out = blockIdx.z == 0 ? o0 : blockIdx.z == 1 ? o1 : blockIdx.z == 2 ? o2 : o3;
  const int c0 = blockIdx.x * 32, r0 = blockIdx.y * 32;
  const int col = threadIdx.x & 31, rq = threadIdx.x >> 5;
#pragma unroll
  for (int i = 0; i < 4; ++i) {
    int r = rq + i * 8;
    tile[r][col] = f2b(in[(size_t)(r0 + r) * D_ + c0 + col]);
  }
  __syncthreads();
#pragma unroll
  for (int i = 0; i < 4; ++i) {
    int r = rq + i * 8;
    out[(size_t)(c0 + r) * D_ + r0 + col] = tile[col][r];
  }
}

// ---------------- scores (MFMA f16, standalone): attn[bh][t][s] = Q.Kb^T/8 --
__global__ __launch_bounds__(256) void scores_mfma(
    const unsigned short* __restrict__ qh, const unsigned short* __restrict__ kh,
    float* __restrict__ attn) {
  constexpr int BM = 128, BN = 128, BK = 64;
  __shared__ __align__(16) unsigned short As[BM * BK];
  __shared__ __align__(16) unsigned short Bs[BN * BK];
  const int tid = threadIdx.x;
  const int l = tid & 63, w = tid >> 6;
  const int wm = w >> 1, wn = w & 1;
  const int bh = blockIdx.z, b = bh >> 4, h = bh & 15;
  const unsigned short* Ab = qh + (size_t)b * T_ * D_ + h * DH_ + (size_t)blockIdx.y * BM * D_;
  const unsigned short* Bb = kh + (size_t)b * T_ * D_ + h * DH_ + (size_t)blockIdx.x * BN * D_;

  const int ar = tid >> 3, ac = tid & 7;
  const int aswz = ((ac ^ (ar & 7)) << 3);
#pragma unroll
  for (int i = 0; i < 4; ++i) {
    gload16(Ab + (size_t)(ar + 32 * i) * D_ + aswz, &As[(size_t)(i * 256 + tid) * 8]);
    gload16(Bb + (size_t)(ar + 32 * i) * D_ + aswz, &Bs[(size_t)(i * 256 + tid) * 8]);
  }
  __syncthreads();

  const int lk = l >> 4, lr = l & 15;
  f16x8 af[4][2], bfr[4][2];
#pragma unroll
  for (int mi = 0; mi < 4; ++mi) {
    const int row = wm * 64 + mi * 16 + lr;
#pragma unroll
    for (int kk = 0; kk < 2; ++kk) {
      const int ch = (kk * 4 + lk) ^ (row & 7);
      af[mi][kk] = *(const f16x8*)&As[row * BK + ch * 8];
    }
  }
#pragma unroll
  for (int ni = 0; ni < 4; ++ni) {
    const int row = wn * 64 + ni * 16 + lr;
#pragma unroll
    for (int kk = 0; kk < 2; ++kk) {
      const int ch = (kk * 4 + lk) ^ (row & 7);
      bfr[ni][kk] = *(const f16x8*)&Bs[row * BK + ch * 8];
    }
  }
  f32x4 acc[4][4] = {};
#pragma unroll
  for (int kk = 0; kk < 2; ++kk)
#pragma unroll
    for (int mi = 0; mi < 4; ++mi)
#pragma unroll
      for (int ni = 0; ni < 4; ++ni)
        acc[mi][ni] = __builtin_amdgcn_mfma_f32_16x16x32_f16(
            af[mi][kk], bfr[ni][kk], acc[mi][ni], 0, 0, 0);

  float* Cb = attn + (size_t)bh * T_ * T_;
  const int crow0 = blockIdx.y * BM + wm * 64 + lk * 4;
  const int ccol0 = blockIdx.x * BN + wn * 64 + lr;
#pragma unroll
  for (int mi = 0; mi < 4; ++mi)
#pragma unroll
    for (int ni = 0; ni < 4; ++ni)
#pragma unroll
      for (int r = 0; r < 4; ++r)
        Cb[(size_t)(crow0 + mi * 16 + r) * T_ + (ccol0 + ni * 16)] = acc[mi][ni][r] * 0.125f;
}

// ---------------- ctx (MFMA f16): ctx[b][t][h*64+j] ------------------------
// A = attn fp32 [bh][t][s] (read from d_out, converted to f16 during staging),
// B = vt f16 [bh][j][s], K = T. grid (1, 8, 64). BM=128, BN=64, BK=64.
__global__ __launch_bounds__(256) void ctx_mfma(
    const float* __restrict__ af32, const unsigned short* __restrict__ vt,
    unsigned short* __restrict__ ctxb) {
  constexpr int BM = 128, BK = 64;
  __shared__ __align__(16) unsigned short As[BM * BK];
  __shared__ __align__(16) unsigned short Bs[64 * BK];
  const int tid = threadIdx.x;
  const int l = tid & 63, w = tid >> 6;
  const int wm = w >> 1, wn = w & 1;
  const int bh = blockIdx.z, b = bh >> 4, h = bh & 15;
  const float* Ab = af32 + (size_t)bh * T_ * T_ + (size_t)blockIdx.y * BM * T_;
  const unsigned short* Bb = vt + (size_t)bh * 64 * T_;
  const int ar = tid >> 3, ac = tid & 7;
  const int aswz = ((ac ^ (ar & 7)) << 3);
  const int lk = l >> 4, lr = l & 15;

  f32x4 acc[4][2] = {};
  for (int k0 = 0; k0 < T_; k0 += BK) {
    // A: fp32 -> f16 reg-staged, swizzle applied on the LDS WRITE address
    // (content: As[row][c] = G[row][c ^ (row&7)], same as gload16 path).
#pragma unroll
    for (int i = 0; i < 4; ++i) {
      const int row = ar + 32 * i;
      const float4 v0 = *(const float4*)&Ab[(size_t)row * T_ + k0 + ac * 8];
      const float4 v1 = *(const float4*)&Ab[(size_t)row * T_ + k0 + ac * 8 + 4];
      unsigned short __attribute__((aligned(16))) p8[8] = {
          f2h(v0.x), f2h(v0.y), f2h(v0.z), f2h(v0.w),
          f2h(v1.x), f2h(v1.y), f2h(v1.z), f2h(v1.w)};
      *(uint4*)&As[row * BK + aswz] = *(uint4*)p8;
    }
    // B: f16 direct, swizzled global source + linear LDS dest
#pragma unroll
    for (int i = 0; i < 2; ++i)
      gload16(Bb + (size_t)(ar + 32 * i) * T_ + k0 + aswz, &Bs[(size_t)(i * 256 + tid) * 8]);
    __syncthreads();

    f16x8 af[4][2], bfr[2][2];
#pragma unroll
    for (int mi = 0; mi < 4; ++mi) {
      const int row = wm * 64 + mi * 16 + lr;
#pragma unroll
      for (int kk = 0; kk < 2; ++kk)
        af[mi][kk] = *(const f16x8*)&As[row * BK + (((kk * 4 + lk) ^ (row & 7)) << 3)];
    }
#pragma unroll
    for (int ni = 0; ni < 2; ++ni) {
      const int row = wn * 32 + ni * 16 + lr;
#pragma unroll
      for (int kk = 0; kk < 2; ++kk)
        bfr[ni][kk] = *(const f16x8*)&Bs[row * BK + (((kk * 4 + lk) ^ (row & 7)) << 3)];
    }
#pragma unroll
    for (int kk = 0; kk < 2; ++kk)
#pragma unroll
      for (int mi = 0; mi < 4; ++mi)
#pragma unroll
        for (int ni = 0; ni < 2; ++ni)
          acc[mi][ni] = __builtin_amdgcn_mfma_f32_16x16x32_f16(
              af[mi][kk], bfr[ni][kk], acc[mi][ni], 0, 0, 0);
    __syncthreads();
  }

  unsigned short* Cb = ctxb + (size_t)b * T_ * D_ + h * DH_;
  const int crow0 = blockIdx.y * BM + wm * 64 + lk * 4;
  const int ccol0 = wn * 32 + lr;
#pragma unroll
  for (int mi = 0; mi < 4; ++mi)
#pragma unroll
    for (int ni = 0; ni < 2; ++ni)
#pragma unroll
      for (int r = 0; r < 4; ++r)
        Cb[(size_t)(crow0 + mi * 16 + r) * D_ + ccol0 + ni * 16] = f2b(acc[mi][ni][r]);
}

// ---------------- MFMA NT GEMM: C[M][N] = A[M][K] @ Bn[N][K]^T ----------------
// EPI: 0=bias, 1=bias+gelu, 2=bias+res1, 3=scale only, 4=bias+res1+res2,
//      5=bias + f16 write TRANSPOSED per head: vt[(b*16+h)*64 + j][t]
template <int BN, int EPI, bool WF32, bool W16, bool FP16 = false>
__global__ __launch_bounds__(256) void gemm_nt(
    const unsigned short* __restrict__ A, int lda,
    const unsigned short* __restrict__ Bm, int ldb,
    float* __restrict__ Cf, unsigned short* __restrict__ Cb, int ldc,
    const float* __restrict__ bias, const float* __restrict__ r1,
    const float* __restrict__ r2, float scale, int K) {
  constexpr int BM = 128, BK = 64;
  constexpr int WN = BN / 2;
  constexpr int FN = WN / 16;
  __shared__ __align__(16) unsigned short As[BM * BK];
  __shared__ __align__(16) unsigned short Bs[BN * BK];
  const int tid = threadIdx.x;
  const int l = tid & 63;
  const int w = tid >> 6;
  const int wm = w >> 1, wn = w & 1;
  const unsigned short* Ab = A + (size_t)blockIdx.y * BM * lda;
  const unsigned short* Bb = Bm + (size_t)blockIdx.x * BN * ldb;

  const int ar = tid >> 3;
  const int ac = tid & 7;
  const int aswz = ((ac ^ (ar & 7)) << 3);

  f32x4 acc[4][FN] = {};

  for (int k0 = 0; k0 < K; k0 += BK) {
#pragma unroll
    for (int i = 0; i < 4; ++i)
      gload16(Ab + (size_t)(ar + 32 * i) * lda + k0 + aswz, &As[(size_t)(i * 256 + tid) * 8]);
#pragma unroll
    for (int i = 0; i < BN / 32; ++i)
      gload16(Bb + (size_t)(ar + 32 * i) * ldb + k0 + aswz, &Bs[(size_t)(i * 256 + tid) * 8]);
    __syncthreads();

    bf16x8 af[4][2], bfr[FN][2];
    const int lk = l >> 4;
#pragma unroll
    for (int mi = 0; mi < 4; ++mi) {
      const int row = wm * 64 + mi * 16 + (l & 15);
#pragma unroll
      for (int kk = 0; kk < 2; ++kk) {
        const int ch = (kk * 4 + lk) ^ (row & 7);
        af[mi][kk] = *(const bf16x8*)&As[row * BK + ch * 8];
      }
    }
#pragma unroll
    for (int ni = 0; ni < FN; ++ni) {
      const int row = wn * WN + ni * 16 + (l & 15);
#pragma unroll
      for (int kk = 0; kk < 2; ++kk) {
        const int ch = (kk * 4 + lk) ^ (row & 7);
        bfr[ni][kk] = *(const bf16x8*)&Bs[row * BK + ch * 8];
      }
    }
#pragma unroll
    for (int kk = 0; kk < 2; ++kk)
#pragma unroll
      for (int mi = 0; mi < 4; ++mi)
#pragma unroll
        for (int ni = 0; ni < FN; ++ni)
          acc[mi][ni] = __builtin_amdgcn_mfma_f32_16x16x32_bf16(
              af[mi][kk], bfr[ni][kk], acc[mi][ni], 0, 0, 0);
    __syncthreads();
  }

  const int crow0 = blockIdx.y * BM + wm * 64 + (l >> 4) * 4;
  const int ccol0 = blockIdx.x * BN + wn * WN + (l & 15);
  if constexpr (EPI == 5) {
#pragma unroll
    for (int mi = 0; mi < 4; ++mi)
#pragma unroll
      for (int ni = 0; ni < FN; ++ni) {
        const int row0 = crow0 + mi * 16;  // b*1024 + t0, t0 multiple of 4
        const int col = ccol0 + ni * 16;   // h*64 + j
        unsigned short __attribute__((aligned(8))) p4[4];
#pragma unroll
        for (int r = 0; r < 4; ++r) p4[r] = f2h(acc[mi][ni][r] + bias[col]);
        const int bidx = row0 >> 10, t0 = row0 & 1023;
        const int hh = col >> 6, j = col & 63;
        *(uint2*)&Cb[(((size_t)bidx * 16 + hh) * 64 + j) * T_ + t0] = *(uint2*)p4;
      }
  } else {
#pragma unroll
    for (int mi = 0; mi < 4; ++mi)
#pragma unroll
      for (int ni = 0; ni < FN; ++ni)
#pragma unroll
        for (int r = 0; r < 4; ++r) {
          const int row = crow0 + mi * 16 + r;
          const int col = ccol0 + ni * 16;
          float v = acc[mi][ni][r] * scale;
          if (EPI != 3) v += bias[col];
          if (EPI == 1) v = gelu_f(v);
          const size_t off = (size_t)row * ldc + col;
          if (EPI == 2) v += r1[off];
          if (EPI == 4) v += r1[off] + r2[off];
          if (WF32) Cf[off] = v;
          if (W16) Cb[off] = FP16 ? f2h(v) : f2b(v);
        }
  }
}

extern "C" void kernel_launch(void* const* d_in, const int* in_sizes, int n_in,
                              void* d_out, int out_size, void* d_ws, size_t ws_size,
                              hipStream_t stream) {
  const float* x    = (const float*)d_in[0];
  const float* sp   = (const float*)d_in[1];
  const float* ed   = (const float*)d_in[2];
  const float* ln1g = (const float*)d_in[3];
  const float* ln1b = (const float*)d_in[4];
  const float* Wq   = (const float*)d_in[5];
  const float* bq   = (const float*)d_in[6];
  const float* Wk   = (const float*)d_in[7];
  const float* bk   = (const float*)d_in[8];
  const float* Wv   = (const float*)d_in[9];
  const float* bvv  = (const float*)d_in[10];
  const float* Wo   = (const float*)d_in[11];
  const float* bo   = (const float*)d_in[12];
  const float* ln2g = (const float*)d_in[13];
  const float* ln2b = (const float*)d_in[14];
  const float* W1   = (const float*)d_in[15];
  const float* b1   = (const float*)d_in[16];
  const float* W2   = (const float*)d_in[17];
  const float* b2   = (const float*)d_in[18];
  const float* lnbg = (const float*)d_in[19];
  const float* lnbb = (const float*)d_in[20];

  float* out_x = (float*)d_out;        // B*T*D fp32
  float* attn  = out_x + BTD;          // B*H*T*T fp32 (output #2)
  float* tt    = out_x;                // post-Wo+residual scratch in out x region

  const size_t MB = 1 << 20;
  char* wsb = (char*)d_ws;
  float*          xn    = (float*)(wsb);                    // [0,16) fp32; reused as y
  unsigned short* xn_b  = (unsigned short*)(wsb + 16 * MB); // [16,24): xn_b -> ctx_b -> y_b
  unsigned short* WqT   = (unsigned short*)(wsb + 24 * MB);
  unsigned short* WkT   = (unsigned short*)(wsb + 26 * MB);
  unsigned short* WvT   = (unsigned short*)(wsb + 28 * MB);
  unsigned short* WoT   = (unsigned short*)(wsb + 30 * MB);
  unsigned short* W1T   = (unsigned short*)(wsb + 32 * MB); // [32,40)
  unsigned short* W2T   = (unsigned short*)(wsb + 40 * MB); // [40,48)
  unsigned short* q_h   = (unsigned short*)(wsb + 48 * MB); // [48,56) f16, dead after scores
  unsigned short* kb_h  = (unsigned short*)(wsb + 56 * MB); // [56,64) f16, dead after scores
  unsigned short* vt    = (unsigned short*)(wsb + 80 * MB); // [80,88) f16 V^T, dead after ctx
  unsigned short* ctx_b = xn_b;                             // [16,24)
  unsigned short* h1_b  = (unsigned short*)(wsb + 48 * MB); // [48,80) (q_h/kb_h dead)
  float*          h2    = (float*)(wsb + 80 * MB);          // [80,96) (vt dead)
  float*          y     = xn;
  unsigned short* y_b   = xn_b;

  dim3 blk(256);
  dim3 g_dd(8, 32);

  // 1. LN1 -> xn (fp32 residual) + xn_b (bf16 GEMM operand)
  ln_rows<<<BT_, blk, 0, stream>>>(x, nullptr, ln1g, ln1b, xn, xn_b);
  // 2. weight transpose+cast
  tcast4<<<dim3(32, 32, 4), blk, 0, stream>>>(Wq, Wk, Wv, Wo, WqT, WkT, WvT, WoT);
  tcast_t<<<dim3(128, 32), blk, 0, stream>>>(W1, W1T, 1024, 4096);
  tcast_t<<<dim3(32, 128), blk, 0, stream>>>(W2, W2T, 4096, 1024);
  // 3-5. Q -> f16, K(+sp+ed) -> f16, V -> f16 transposed per head (MFMA)
  gemm_nt<128, 0, false, true, true><<<g_dd, blk, 0, stream>>>(
      xn_b, D_, WqT, D_, nullptr, q_h, D_, bq, nullptr, nullptr, 1.f, D_);
  gemm_nt<128, 4, false, true, true><<<g_dd, blk, 0, stream>>>(
      xn_b, D_, WkT, D_, nullptr, kb_h, D_, bk, sp, ed, 1.f, D_);
  gemm_nt<128, 5, false, true, true><<<g_dd, blk, 0, stream>>>(
      xn_b, D_, WvT, D_, nullptr, vt, D_, bvv, nullptr, nullptr, 1.f, D_);
  // 6. scores = Q @ Kb^T / 8 -> d_out attn region (MFMA f16)
  scores_mfma<<<dim3(8, 8, 64), blk, 0, stream>>>(q_h, kb_h, attn);
  // 7. softmax in place (fp32) — this IS output #2
  softmax_rows<<<B_ * H_ * T_, blk, 0, stream>>>(attn);
  // 8. ctx = attn @ V -> bf16 (MFMA f16; A converted fp32->f16 in staging)
  ctx_mfma<<<dim3(1, 8, 64), blk, 0, stream>>>(attn, vt, ctx_b);
  // 9. tt = ctx @ Wo + bo + xn (MFMA)
  gemm_nt<128, 2, true, false><<<g_dd, blk, 0, stream>>>(
      ctx_b, D_, WoT, D_, tt, nullptr, D_, bo, xn, nullptr, 1.f, D_);
  // 10. y = LN2(tt)
  ln_rows<<<BT_, blk, 0, stream>>>(tt, nullptr, ln2g, ln2b, y, y_b);
  // 11. h1 = gelu(y @ W1 + b1) -> bf16 (MFMA)
  gemm_nt<128, 1, false, true><<<dim3(32, 32), blk, 0, stream>>>(
      y_b, D_, W1T, D_, nullptr, h1_b, F_, b1, nullptr, nullptr, 1.f, D_);
  // 12. h2 = h1 @ W2 + b2 (MFMA, fp32 out)
  gemm_nt<128, 0, true, false><<<g_dd, blk, 0, stream>>>(
      h1_b, F_, W2T, F_, h2, nullptr, D_, b2, nullptr, nullptr, 1.f, F_);
  // 13. out = LN(y + h2)
  ln_rows<<<BT_, blk, 0, stream>>>(y, h2, lnbg, lnbb, out_x, nullptr);
}

// Round 8
// 449.457 us; speedup vs baseline: 4.2023x; 1.2101x over previous
//
#include <hip/hip_runtime.h>
#include <hip/hip_bf16.h>
#include <hip/hip_fp16.h>
#include <math.h>

#define B_ 4
#define T_ 1024
#define D_ 1024
#define H_ 16
#define DH_ 64
#define F_ 4096
#define BT_ (B_ * T_)
#define BTD ((size_t)B_ * T_ * D_)

typedef short bf16x8 __attribute__((ext_vector_type(8)));
typedef _Float16 f16x8 __attribute__((ext_vector_type(8)));
typedef float f32x4 __attribute__((ext_vector_type(4)));

__device__ __forceinline__ unsigned short f2b(float f) {
  __hip_bfloat16 h = __float2bfloat16(f);
  return *reinterpret_cast<unsigned short*>(&h);
}
__device__ __forceinline__ unsigned short f2h(float f) {
  __half h = __float2half(f);
  return *reinterpret_cast<unsigned short*>(&h);
}

__device__ __forceinline__ void gload16(const unsigned short* g, unsigned short* l) {
  __builtin_amdgcn_global_load_lds(
      (const __attribute__((address_space(1))) unsigned int*)(const void*)g,
      (__attribute__((address_space(3))) unsigned int*)(void*)l, 16, 0, 0);
}

__device__ __forceinline__ float gelu_f(float x) {
  float x3 = x * x * x;
  return 0.5f * x * (1.0f + tanhf(0.79788456080286536f * (x + 0.044715f * x3)));
}

// ---------------- block reductions (256 threads, wave64) ----------------
__device__ __forceinline__ float blk_sum256(float v, float* s4) {
#pragma unroll
  for (int off = 32; off > 0; off >>= 1) v += __shfl_down(v, off);
  if ((threadIdx.x & 63) == 0) s4[threadIdx.x >> 6] = v;
  __syncthreads();
  float t = s4[0] + s4[1] + s4[2] + s4[3];
  __syncthreads();
  return t;
}

// ---------------- LayerNorm rows of D=1024, fp32 out + optional bf16 out ----
__global__ __launch_bounds__(256) void ln_rows(
    const float* __restrict__ in, const float* __restrict__ in2,
    const float* __restrict__ g, const float* __restrict__ bb,
    float* __restrict__ outf, unsigned short* __restrict__ outb) {
  __shared__ float s4[4];
  const size_t base = (size_t)blockIdx.x * D_;
  const int t = threadIdx.x;
  float4 v = ((const float4*)(in + base))[t];
  if (in2) {
    float4 w = ((const float4*)(in2 + base))[t];
    v.x += w.x; v.y += w.y; v.z += w.z; v.w += w.w;
  }
  float mean = blk_sum256(v.x + v.y + v.z + v.w, s4) * (1.0f / D_);
  float dx = v.x - mean, dy = v.y - mean, dz = v.z - mean, dw = v.w - mean;
  float var = blk_sum256(dx * dx + dy * dy + dz * dz + dw * dw, s4) * (1.0f / D_);
  float rstd = rsqrtf(var + 1e-5f);
  float4 gv = ((const float4*)g)[t];
  float4 bv = ((const float4*)bb)[t];
  float4 o;
  o.x = dx * rstd * gv.x + bv.x;
  o.y = dy * rstd * gv.y + bv.y;
  o.z = dz * rstd * gv.z + bv.z;
  o.w = dw * rstd * gv.w + bv.w;
  if (outf) ((float4*)(outf + base))[t] = o;
  if (outb) {
    unsigned short o4[4] = {f2b(o.x), f2b(o.y), f2b(o.z), f2b(o.w)};
    *(uint2*)(&outb[base + (size_t)t * 4]) = *(uint2*)o4;
  }
}

// ---------------- transpose+cast fp32 [R][C] -> bf16 [C][R] ----------------
__global__ __launch_bounds__(256) void tcast_t(
    const float* __restrict__ in, unsigned short* __restrict__ out, int R, int C) {
  __shared__ unsigned short tile[32][33];
  const int c0 = blockIdx.x * 32, r0 = blockIdx.y * 32;
  const int col = threadIdx.x & 31, rq = threadIdx.x >> 5;
#pragma unroll
  for (int i = 0; i < 4; ++i) {
    int r = rq + i * 8;
    tile[r][col] = f2b(in[(size_t)(r0 + r) * C + c0 + col]);
  }
  __syncthreads();
#pragma unroll
  for (int i = 0; i < 4; ++i) {
    int r = rq + i * 8;
    out[(size_t)(c0 + r) * R + r0 + col] = tile[col][r];
  }
}

// four 1024x1024 weights at once (z selects)
__global__ __launch_bounds__(256) void tcast4(
    const float* w0, const float* w1, const float* w2, const float* w3,
    unsigned short* o0, unsigned short* o1, unsigned short* o2, unsigned short* o3) {
  __shared__ unsigned short tile[32][33];
  const float* in = blockIdx.z == 0 ? w0 : blockIdx.z == 1 ? w1 : blockIdx.z == 2 ? w2 : w3;
  unsigned short* out = blockIdx.z == 0 ? o0 : blockIdx.z == 1 ? o1 : blockIdx.z == 2 ? o2 : o3;
  const int c0 = blockIdx.x * 32, r0 = blockIdx.y * 32;
  const int col = threadIdx.x & 31, rq = threadIdx.x >> 5;
#pragma unroll
  for (int i = 0; i < 4; ++i) {
    int r = rq + i * 8;
    tile[r][col] = f2b(in[(size_t)(r0 + r) * D_ + c0 + col]);
  }
  __syncthreads();
#pragma unroll
  for (int i = 0; i < 4; ++i) {
    int r = rq + i * 8;
    out[(size_t)(c0 + r) * D_ + r0 + col] = tile[col][r];
  }
}

// ---------------- fused attention: scores + softmax + ctx -------------------
// grid (8, 64): x = t-tile (128 rows), y = bh. 256 threads = 4 waves (2x2).
// Phase A: stream K s-tiles, QK^T, accumulate row exp-sums per wave, then
//   cross-wave combine (each wave only covers its wn-half of s!).
// Phase B: re-stream K + V s-tiles, recompute QK^T, p = exp(s/8)/l, write p
//   (fp32, final attn output), round-trip p f16 through swizzled LDS, PV MFMA.
__global__ __launch_bounds__(256) void attn_fused(
    const unsigned short* __restrict__ qh, const unsigned short* __restrict__ kh,
    const unsigned short* __restrict__ vt, float* __restrict__ attn,
    unsigned short* __restrict__ ctxb) {
  __shared__ __align__(16) unsigned short Qs[128 * 64];   // 16 KB
  __shared__ __align__(16) unsigned short Ks[128 * 64];   // 16 KB
  __shared__ __align__(16) unsigned short Vs[64 * 128];   // 16 KB
  __shared__ __align__(16) unsigned short Ps[128 * 128];  // 32 KB
  const int tid = threadIdx.x;
  const int l = tid & 63, w = tid >> 6;
  const int wm = w >> 1, wn = w & 1;
  const int lk = l >> 4, lr = l & 15;
  const int bh = blockIdx.y, b = bh >> 4, h = bh & 15;
  const unsigned short* Qg = qh + (size_t)b * T_ * D_ + h * DH_ + (size_t)blockIdx.x * 128 * D_;
  const unsigned short* Kg = kh + (size_t)b * T_ * D_ + h * DH_;
  const unsigned short* Vg = vt + (size_t)bh * 64 * T_;

  // staging coords for 128x64 f16 tiles (8 chunks of 16B per row)
  const int ar = tid >> 3, ac = tid & 7;
  const int aswz = ((ac ^ (ar & 7)) << 3);

  // stage Q once, hold fragments in registers for both phases
#pragma unroll
  for (int i = 0; i < 4; ++i)
    gload16(Qg + (size_t)(ar + 32 * i) * D_ + aswz, &Qs[(size_t)(i * 256 + tid) * 8]);
  __syncthreads();
  f16x8 qf[4][2];
#pragma unroll
  for (int mi = 0; mi < 4; ++mi) {
    const int row = wm * 64 + mi * 16 + lr;
#pragma unroll
    for (int kk = 0; kk < 2; ++kk)
      qf[mi][kk] = *(const f16x8*)&Qs[row * 64 + (((kk * 4 + lk) ^ (row & 7)) << 3)];
  }

  float lsum[4][4] = {};  // [mi][r] partial row exp-sums (this wave's wn-half only)

  // ---- phase A ----
  for (int st = 0; st < 8; ++st) {
    __syncthreads();  // prev kf reads done before overwrite
#pragma unroll
    for (int i = 0; i < 4; ++i)
      gload16(Kg + (size_t)(st * 128 + ar + 32 * i) * D_ + aswz, &Ks[(size_t)(i * 256 + tid) * 8]);
    __syncthreads();
    f16x8 kf[4][2];
#pragma unroll
    for (int ni = 0; ni < 4; ++ni) {
      const int row = wn * 64 + ni * 16 + lr;
#pragma unroll
      for (int kk = 0; kk < 2; ++kk)
        kf[ni][kk] = *(const f16x8*)&Ks[row * 64 + (((kk * 4 + lk) ^ (row & 7)) << 3)];
    }
    f32x4 acc[4][4] = {};
#pragma unroll
    for (int kk = 0; kk < 2; ++kk)
#pragma unroll
      for (int mi = 0; mi < 4; ++mi)
#pragma unroll
        for (int ni = 0; ni < 4; ++ni)
          acc[mi][ni] = __builtin_amdgcn_mfma_f32_16x16x32_f16(
              qf[mi][kk], kf[ni][kk], acc[mi][ni], 0, 0, 0);
#pragma unroll
    for (int mi = 0; mi < 4; ++mi)
#pragma unroll
      for (int r = 0; r < 4; ++r) {
        float v = __expf(acc[mi][0][r] * 0.125f) + __expf(acc[mi][1][r] * 0.125f) +
                  __expf(acc[mi][2][r] * 0.125f) + __expf(acc[mi][3][r] * 0.125f);
        v += __shfl_xor(v, 1); v += __shfl_xor(v, 2);
        v += __shfl_xor(v, 4); v += __shfl_xor(v, 8);
        lsum[mi][r] += v;
      }
  }

  // ---- cross-wave combine of the two wn-halves (sL aliases head of Ps) ----
  float* sL = (float*)Ps;  // sL[2][128]: [wn][row]; Ps not yet in use
  if (lr == 0) {
#pragma unroll
    for (int mi = 0; mi < 4; ++mi)
#pragma unroll
      for (int r = 0; r < 4; ++r)
        sL[wn * 128 + wm * 64 + mi * 16 + lk * 4 + r] = lsum[mi][r];
  }
  __syncthreads();
  float rl[4][4];
#pragma unroll
  for (int mi = 0; mi < 4; ++mi)
#pragma unroll
    for (int r = 0; r < 4; ++r) {
      const int row = wm * 64 + mi * 16 + lk * 4 + r;
      rl[mi][r] = 1.0f / (sL[row] + sL[128 + row]);
    }
  __syncthreads();  // sL reads retired before Ps writes begin

  // ---- phase B ----
  float* Cg = attn + (size_t)bh * T_ * T_;
  f32x4 cacc[4][2] = {};
  for (int st = 0; st < 8; ++st) {
    __syncthreads();  // prev Ps/kf/vf reads done before overwrite
#pragma unroll
    for (int i = 0; i < 4; ++i)
      gload16(Kg + (size_t)(st * 128 + ar + 32 * i) * D_ + aswz, &Ks[(size_t)(i * 256 + tid) * 8]);
#pragma unroll
    for (int i = 0; i < 4; ++i) {
      const int c = i * 256 + tid;
      const int row = c >> 4, ch = c & 15;  // Vs: 64 rows x 16 chunks
      gload16(Vg + (size_t)row * T_ + st * 128 + ((ch ^ (row & 7)) << 3), &Vs[(size_t)c * 8]);
    }
    __syncthreads();
    f16x8 kf[4][2], vf[2][4];
#pragma unroll
    for (int ni = 0; ni < 4; ++ni) {
      const int row = wn * 64 + ni * 16 + lr;
#pragma unroll
      for (int kk = 0; kk < 2; ++kk)
        kf[ni][kk] = *(const f16x8*)&Ks[row * 64 + (((kk * 4 + lk) ^ (row & 7)) << 3)];
    }
#pragma unroll
    for (int ni = 0; ni < 2; ++ni) {
      const int row = wn * 32 + ni * 16 + lr;
#pragma unroll
      for (int kk = 0; kk < 4; ++kk)
        vf[ni][kk] = *(const f16x8*)&Vs[row * 128 + (((kk * 4 + lk) ^ (row & 7)) << 3)];
    }
    f32x4 acc[4][4] = {};
#pragma unroll
    for (int kk = 0; kk < 2; ++kk)
#pragma unroll
      for (int mi = 0; mi < 4; ++mi)
#pragma unroll
        for (int ni = 0; ni < 4; ++ni)
          acc[mi][ni] = __builtin_amdgcn_mfma_f32_16x16x32_f16(
              qf[mi][kk], kf[ni][kk], acc[mi][ni], 0, 0, 0);
    // normalize, write fp32 attn, stash f16 P in swizzled LDS
#pragma unroll
    for (int mi = 0; mi < 4; ++mi) {
      const int trow = wm * 64 + mi * 16 + lk * 4;
#pragma unroll
      for (int ni = 0; ni < 4; ++ni) {
        const int scol = wn * 64 + ni * 16 + lr;
#pragma unroll
        for (int r = 0; r < 4; ++r) {
          const int t = trow + r;
          float p = __expf(acc[mi][ni][r] * 0.125f) * rl[mi][r];
          Cg[(size_t)(blockIdx.x * 128 + t) * T_ + (st * 128 + scol)] = p;
          Ps[t * 128 + (scol ^ ((t & 7) << 3))] = f2h(p);
        }
      }
    }
    __syncthreads();  // Ps visible
    // PV: ctx[t][j] += P[t][s] * vt[j][s]
#pragma unroll
    for (int kk = 0; kk < 4; ++kk) {
      f16x8 af[4];
#pragma unroll
      for (int mi = 0; mi < 4; ++mi) {
        const int row = wm * 64 + mi * 16 + lr;
        af[mi] = *(const f16x8*)&Ps[row * 128 + (((kk * 4 + lk) ^ (row & 7)) << 3)];
      }
#pragma unroll
      for (int mi = 0; mi < 4; ++mi)
#pragma unroll
        for (int ni = 0; ni < 2; ++ni)
          cacc[mi][ni] = __builtin_amdgcn_mfma_f32_16x16x32_f16(
              af[mi], vf[ni][kk], cacc[mi][ni], 0, 0, 0);
    }
  }

  unsigned short* Cb = ctxb + (size_t)b * T_ * D_ + h * DH_;
  const int crow0 = blockIdx.x * 128 + wm * 64 + lk * 4;
  const int ccol0 = wn * 32 + lr;
#pragma unroll
  for (int mi = 0; mi < 4; ++mi)
#pragma unroll
    for (int ni = 0; ni < 2; ++ni)
#pragma unroll
      for (int r = 0; r < 4; ++r)
        Cb[(size_t)(crow0 + mi * 16 + r) * D_ + ccol0 + ni * 16] = f2b(cacc[mi][ni][r]);
}

// ---------------- MFMA NT GEMM: C[M][N] = A[M][K] @ Bn[N][K]^T ----------------
// EPI: 0=bias, 1=bias+gelu, 2=bias+res1, 3=scale only, 4=bias+res1+res2,
//      5=bias + f16 write TRANSPOSED per head: vt[(b*16+h)*64 + j][t]
template <int BN, int EPI, bool WF32, bool W16, bool FP16 = false>
__global__ __launch_bounds__(256) void gemm_nt(
    const unsigned short* __restrict__ A, int lda,
    const unsigned short* __restrict__ Bm, int ldb,
    float* __restrict__ Cf, unsigned short* __restrict__ Cb, int ldc,
    const float* __restrict__ bias, const float* __restrict__ r1,
    const float* __restrict__ r2, float scale, int K) {
  constexpr int BM = 128, BK = 64;
  constexpr int WN = BN / 2;
  constexpr int FN = WN / 16;
  __shared__ __align__(16) unsigned short As[BM * BK];
  __shared__ __align__(16) unsigned short Bs[BN * BK];
  const int tid = threadIdx.x;
  const int l = tid & 63;
  const int w = tid >> 6;
  const int wm = w >> 1, wn = w & 1;
  const unsigned short* Ab = A + (size_t)blockIdx.y * BM * lda;
  const unsigned short* Bb = Bm + (size_t)blockIdx.x * BN * ldb;

  const int ar = tid >> 3;
  const int ac = tid & 7;
  const int aswz = ((ac ^ (ar & 7)) << 3);

  f32x4 acc[4][FN] = {};

  for (int k0 = 0; k0 < K; k0 += BK) {
#pragma unroll
    for (int i = 0; i < 4; ++i)
      gload16(Ab + (size_t)(ar + 32 * i) * lda + k0 + aswz, &As[(size_t)(i * 256 + tid) * 8]);
#pragma unroll
    for (int i = 0; i < BN / 32; ++i)
      gload16(Bb + (size_t)(ar + 32 * i) * ldb + k0 + aswz, &Bs[(size_t)(i * 256 + tid) * 8]);
    __syncthreads();

    bf16x8 af[4][2], bfr[FN][2];
    const int lk = l >> 4;
#pragma unroll
    for (int mi = 0; mi < 4; ++mi) {
      const int row = wm * 64 + mi * 16 + (l & 15);
#pragma unroll
      for (int kk = 0; kk < 2; ++kk) {
        const int ch = (kk * 4 + lk) ^ (row & 7);
        af[mi][kk] = *(const bf16x8*)&As[row * BK + ch * 8];
      }
    }
#pragma unroll
    for (int ni = 0; ni < FN; ++ni) {
      const int row = wn * WN + ni * 16 + (l & 15);
#pragma unroll
      for (int kk = 0; kk < 2; ++kk) {
        const int ch = (kk * 4 + lk) ^ (row & 7);
        bfr[ni][kk] = *(const bf16x8*)&Bs[row * BK + ch * 8];
      }
    }
#pragma unroll
    for (int kk = 0; kk < 2; ++kk)
#pragma unroll
      for (int mi = 0; mi < 4; ++mi)
#pragma unroll
        for (int ni = 0; ni < FN; ++ni)
          acc[mi][ni] = __builtin_amdgcn_mfma_f32_16x16x32_bf16(
              af[mi][kk], bfr[ni][kk], acc[mi][ni], 0, 0, 0);
    __syncthreads();
  }

  const int crow0 = blockIdx.y * BM + wm * 64 + (l >> 4) * 4;
  const int ccol0 = blockIdx.x * BN + wn * WN + (l & 15);
  if constexpr (EPI == 5) {
#pragma unroll
    for (int mi = 0; mi < 4; ++mi)
#pragma unroll
      for (int ni = 0; ni < FN; ++ni) {
        const int row0 = crow0 + mi * 16;  // b*1024 + t0, t0 multiple of 4
        const int col = ccol0 + ni * 16;   // h*64 + j
        unsigned short __attribute__((aligned(8))) p4[4];
#pragma unroll
        for (int r = 0; r < 4; ++r) p4[r] = f2h(acc[mi][ni][r] + bias[col]);
        const int bidx = row0 >> 10, t0 = row0 & 1023;
        const int hh = col >> 6, j = col & 63;
        *(uint2*)&Cb[(((size_t)bidx * 16 + hh) * 64 + j) * T_ + t0] = *(uint2*)p4;
      }
  } else {
#pragma unroll
    for (int mi = 0; mi < 4; ++mi)
#pragma unroll
      for (int ni = 0; ni < FN; ++ni)
#pragma unroll
        for (int r = 0; r < 4; ++r) {
          const int row = crow0 + mi * 16 + r;
          const int col = ccol0 + ni * 16;
          float v = acc[mi][ni][r] * scale;
          if (EPI != 3) v += bias[col];
          if (EPI == 1) v = gelu_f(v);
          const size_t off = (size_t)row * ldc + col;
          if (EPI == 2) v += r1[off];
          if (EPI == 4) v += r1[off] + r2[off];
          if (WF32) Cf[off] = v;
          if (W16) Cb[off] = FP16 ? f2h(v) : f2b(v);
        }
  }
}

extern "C" void kernel_launch(void* const* d_in, const int* in_sizes, int n_in,
                              void* d_out, int out_size, void* d_ws, size_t ws_size,
                              hipStream_t stream) {
  const float* x    = (const float*)d_in[0];
  const float* sp   = (const float*)d_in[1];
  const float* ed   = (const float*)d_in[2];
  const float* ln1g = (const float*)d_in[3];
  const float* ln1b = (const float*)d_in[4];
  const float* Wq   = (const float*)d_in[5];
  const float* bq   = (const float*)d_in[6];
  const float* Wk   = (const float*)d_in[7];
  const float* bk   = (const float*)d_in[8];
  const float* Wv   = (const float*)d_in[9];
  const float* bvv  = (const float*)d_in[10];
  const float* Wo   = (const float*)d_in[11];
  const float* bo   = (const float*)d_in[12];
  const float* ln2g = (const float*)d_in[13];
  const float* ln2b = (const float*)d_in[14];
  const float* W1   = (const float*)d_in[15];
  const float* b1   = (const float*)d_in[16];
  const float* W2   = (const float*)d_in[17];
  const float* b2   = (const float*)d_in[18];
  const float* lnbg = (const float*)d_in[19];
  const float* lnbb = (const float*)d_in[20];

  float* out_x = (float*)d_out;        // B*T*D fp32
  float* attn  = out_x + BTD;          // B*H*T*T fp32 (output #2)
  float* tt    = out_x;                // post-Wo+residual scratch in out x region

  const size_t MB = 1 << 20;
  char* wsb = (char*)d_ws;
  float*          xn    = (float*)(wsb);                    // [0,16) fp32; reused as y
  unsigned short* xn_b  = (unsigned short*)(wsb + 16 * MB); // [16,24): xn_b -> ctx_b -> y_b
  unsigned short* WqT   = (unsigned short*)(wsb + 24 * MB);
  unsigned short* WkT   = (unsigned short*)(wsb + 26 * MB);
  unsigned short* WvT   = (unsigned short*)(wsb + 28 * MB);
  unsigned short* WoT   = (unsigned short*)(wsb + 30 * MB);
  unsigned short* W1T   = (unsigned short*)(wsb + 32 * MB); // [32,40)
  unsigned short* W2T   = (unsigned short*)(wsb + 40 * MB); // [40,48)
  unsigned short* q_h   = (unsigned short*)(wsb + 48 * MB); // [48,56) f16, dead after attn
  unsigned short* kb_h  = (unsigned short*)(wsb + 56 * MB); // [56,64) f16, dead after attn
  unsigned short* vt    = (unsigned short*)(wsb + 80 * MB); // [80,88) f16 V^T, dead after attn
  unsigned short* ctx_b = xn_b;                             // [16,24)
  unsigned short* h1_b  = (unsigned short*)(wsb + 48 * MB); // [48,80) (q_h/kb_h dead)
  float*          h2    = (float*)(wsb + 80 * MB);          // [80,96) (vt dead)
  float*          y     = xn;
  unsigned short* y_b   = xn_b;

  dim3 blk(256);
  dim3 g_dd(8, 32);

  // 1. LN1 -> xn (fp32 residual) + xn_b (bf16 GEMM operand)
  ln_rows<<<BT_, blk, 0, stream>>>(x, nullptr, ln1g, ln1b, xn, xn_b);
  // 2. weight transpose+cast
  tcast4<<<dim3(32, 32, 4), blk, 0, stream>>>(Wq, Wk, Wv, Wo, WqT, WkT, WvT, WoT);
  tcast_t<<<dim3(128, 32), blk, 0, stream>>>(W1, W1T, 1024, 4096);
  tcast_t<<<dim3(32, 128), blk, 0, stream>>>(W2, W2T, 4096, 1024);
  // 3-5. Q -> f16, K(+sp+ed) -> f16, V -> f16 transposed per head (MFMA)
  gemm_nt<128, 0, false, true, true><<<g_dd, blk, 0, stream>>>(
      xn_b, D_, WqT, D_, nullptr, q_h, D_, bq, nullptr, nullptr, 1.f, D_);
  gemm_nt<128, 4, false, true, true><<<g_dd, blk, 0, stream>>>(
      xn_b, D_, WkT, D_, nullptr, kb_h, D_, bk, sp, ed, 1.f, D_);
  gemm_nt<128, 5, false, true, true><<<g_dd, blk, 0, stream>>>(
      xn_b, D_, WvT, D_, nullptr, vt, D_, bvv, nullptr, nullptr, 1.f, D_);
  // 6. fused scores + softmax + ctx (attn fp32 -> d_out, ctx bf16 -> ws)
  attn_fused<<<dim3(8, 64), blk, 0, stream>>>(q_h, kb_h, vt, attn, ctx_b);
  // 7. tt = ctx @ Wo + bo + xn (MFMA)
  gemm_nt<128, 2, true, false><<<g_dd, blk, 0, stream>>>(
      ctx_b, D_, WoT, D_, tt, nullptr, D_, bo, xn, nullptr, 1.f, D_);
  // 8. y = LN2(tt)
  ln_rows<<<BT_, blk, 0, stream>>>(tt, nullptr, ln2g, ln2b, y, y_b);
  // 9. h1 = gelu(y @ W1 + b1) -> bf16 (MFMA)
  gemm_nt<128, 1, false, true><<<dim3(32, 32), blk, 0, stream>>>(
      y_b, D_, W1T, D_, nullptr, h1_b, F_, b1, nullptr, nullptr, 1.f, D_);
  // 10. h2 = h1 @ W2 + b2 (MFMA, fp32 out)
  gemm_nt<128, 0, true, false><<<g_dd, blk, 0, stream>>>(
      h1_b, F_, W2T, F_, h2, nullptr, D_, b2, nullptr, nullptr, 1.f, F_);
  // 11. out = LN(y + h2)
  ln_rows<<<BT_, blk, 0, stream>>>(y, h2, lnbg, lnbb, out_x, nullptr);
}

// Round 9
// 440.540 us; speedup vs baseline: 4.2873x; 1.0202x over previous
//
#include <hip/hip_runtime.h>
#include <hip/hip_bf16.h>
#include <hip/hip_fp16.h>
#include <math.h>

#define B_ 4
#define T_ 1024
#define D_ 1024
#define H_ 16
#define DH_ 64
#define F_ 4096
#define BT_ (B_ * T_)
#define BTD ((size_t)B_ * T_ * D_)

typedef short bf16x8 __attribute__((ext_vector_type(8)));
typedef _Float16 f16x8 __attribute__((ext_vector_type(8)));
typedef float f32x4 __attribute__((ext_vector_type(4)));

__device__ __forceinline__ unsigned short f2b(float f) {
  __hip_bfloat16 h = __float2bfloat16(f);
  return *reinterpret_cast<unsigned short*>(&h);
}
__device__ __forceinline__ unsigned short f2h(float f) {
  __half h = __float2half(f);
  return *reinterpret_cast<unsigned short*>(&h);
}

__device__ __forceinline__ void gload16(const unsigned short* g, unsigned short* l) {
  __builtin_amdgcn_global_load_lds(
      (const __attribute__((address_space(1))) unsigned int*)(const void*)g,
      (__attribute__((address_space(3))) unsigned int*)(void*)l, 16, 0, 0);
}

// tanh-approx GELU via sigmoid identity: 0.5*(1+tanh(z)) = sigmoid(2z).
// gelu(x) = x * sigmoid(1.5957691216*(x + 0.044715*x^3)); __expf = HW v_exp.
__device__ __forceinline__ float gelu_f(float x) {
  float z2 = 1.5957691216057308f * (x + 0.044715f * x * x * x);
  return x / (1.0f + __expf(-z2));
}

// ---------------- block reductions (256 threads, wave64) ----------------
__device__ __forceinline__ float blk_sum256(float v, float* s4) {
#pragma unroll
  for (int off = 32; off > 0; off >>= 1) v += __shfl_down(v, off);
  if ((threadIdx.x & 63) == 0) s4[threadIdx.x >> 6] = v;
  __syncthreads();
  float t = s4[0] + s4[1] + s4[2] + s4[3];
  __syncthreads();
  return t;
}

// ---------------- LayerNorm rows of D=1024, fp32 out + optional bf16 out ----
__global__ __launch_bounds__(256) void ln_rows(
    const float* __restrict__ in, const float* __restrict__ in2,
    const float* __restrict__ g, const float* __restrict__ bb,
    float* __restrict__ outf, unsigned short* __restrict__ outb) {
  __shared__ float s4[4];
  const size_t base = (size_t)blockIdx.x * D_;
  const int t = threadIdx.x;
  float4 v = ((const float4*)(in + base))[t];
  if (in2) {
    float4 w = ((const float4*)(in2 + base))[t];
    v.x += w.x; v.y += w.y; v.z += w.z; v.w += w.w;
  }
  float mean = blk_sum256(v.x + v.y + v.z + v.w, s4) * (1.0f / D_);
  float dx = v.x - mean, dy = v.y - mean, dz = v.z - mean, dw = v.w - mean;
  float var = blk_sum256(dx * dx + dy * dy + dz * dz + dw * dw, s4) * (1.0f / D_);
  float rstd = rsqrtf(var + 1e-5f);
  float4 gv = ((const float4*)g)[t];
  float4 bv = ((const float4*)bb)[t];
  float4 o;
  o.x = dx * rstd * gv.x + bv.x;
  o.y = dy * rstd * gv.y + bv.y;
  o.z = dz * rstd * gv.z + bv.z;
  o.w = dw * rstd * gv.w + bv.w;
  if (outf) ((float4*)(outf + base))[t] = o;
  if (outb) {
    unsigned short o4[4] = {f2b(o.x), f2b(o.y), f2b(o.z), f2b(o.w)};
    *(uint2*)(&outb[base + (size_t)t * 4]) = *(uint2*)o4;
  }
}

// ---------------- transpose+cast fp32 [R][C] -> bf16 [C][R] ----------------
__global__ __launch_bounds__(256) void tcast_t(
    const float* __restrict__ in, unsigned short* __restrict__ out, int R, int C) {
  __shared__ unsigned short tile[32][33];
  const int c0 = blockIdx.x * 32, r0 = blockIdx.y * 32;
  const int col = threadIdx.x & 31, rq = threadIdx.x >> 5;
#pragma unroll
  for (int i = 0; i < 4; ++i) {
    int r = rq + i * 8;
    tile[r][col] = f2b(in[(size_t)(r0 + r) * C + c0 + col]);
  }
  __syncthreads();
#pragma unroll
  for (int i = 0; i < 4; ++i) {
    int r = rq + i * 8;
    out[(size_t)(c0 + r) * R + r0 + col] = tile[col][r];
  }
}

// four 1024x1024 weights at once (z selects)
__global__ __launch_bounds__(256) void tcast4(
    const float* w0, const float* w1, const float* w2, const float* w3,
    unsigned short* o0, unsigned short* o1, unsigned short* o2, unsigned short* o3) {
  __shared__ unsigned short tile[32][33];
  const float* in = blockIdx.z == 0 ? w0 : blockIdx.z == 1 ? w1 : blockIdx.z == 2 ? w2 : w3;
  unsigned short* out = blockIdx.z == 0 ? o0 : blockIdx.z == 1 ? o1 : blockIdx.z == 2 ? o2 : o3;
  const int c0 = blockIdx.x * 32, r0 = blockIdx.y * 32;
  const int col = threadIdx.x & 31, rq = threadIdx.x >> 5;
#pragma unroll
  for (int i = 0; i < 4; ++i) {
    int r = rq + i * 8;
    tile[r][col] = f2b(in[(size_t)(r0 + r) * D_ + c0 + col]);
  }
  __syncthreads();
#pragma unroll
  for (int i = 0; i < 4; ++i) {
    int r = rq + i * 8;
    out[(size_t)(c0 + r) * D_ + r0 + col] = tile[col][r];
  }
}

// ---------------- fused attention: scores + softmax + ctx -------------------
// grid (8, 64): x = t-tile (128 rows), y = bh. 256 threads = 4 waves (2x2).
__global__ __launch_bounds__(256) void attn_fused(
    const unsigned short* __restrict__ qh, const unsigned short* __restrict__ kh,
    const unsigned short* __restrict__ vt, float* __restrict__ attn,
    unsigned short* __restrict__ ctxb) {
  __shared__ __align__(16) unsigned short Qs[128 * 64];   // 16 KB
  __shared__ __align__(16) unsigned short Ks[128 * 64];   // 16 KB
  __shared__ __align__(16) unsigned short Vs[64 * 128];   // 16 KB
  __shared__ __align__(16) unsigned short Ps[128 * 128];  // 32 KB
  const int tid = threadIdx.x;
  const int l = tid & 63, w = tid >> 6;
  const int wm = w >> 1, wn = w & 1;
  const int lk = l >> 4, lr = l & 15;
  const int bh = blockIdx.y, b = bh >> 4, h = bh & 15;
  const unsigned short* Qg = qh + (size_t)b * T_ * D_ + h * DH_ + (size_t)blockIdx.x * 128 * D_;
  const unsigned short* Kg = kh + (size_t)b * T_ * D_ + h * DH_;
  const unsigned short* Vg = vt + (size_t)bh * 64 * T_;

  const int ar = tid >> 3, ac = tid & 7;
  const int aswz = ((ac ^ (ar & 7)) << 3);

  // stage Q once, hold fragments in registers for both phases
#pragma unroll
  for (int i = 0; i < 4; ++i)
    gload16(Qg + (size_t)(ar + 32 * i) * D_ + aswz, &Qs[(size_t)(i * 256 + tid) * 8]);
  __syncthreads();
  f16x8 qf[4][2];
#pragma unroll
  for (int mi = 0; mi < 4; ++mi) {
    const int row = wm * 64 + mi * 16 + lr;
#pragma unroll
    for (int kk = 0; kk < 2; ++kk)
      qf[mi][kk] = *(const f16x8*)&Qs[row * 64 + (((kk * 4 + lk) ^ (row & 7)) << 3)];
  }

  float lsum[4][4] = {};  // [mi][r] partial row exp-sums (this wave's wn-half only)

  // ---- phase A ----
  for (int st = 0; st < 8; ++st) {
    __syncthreads();
#pragma unroll
    for (int i = 0; i < 4; ++i)
      gload16(Kg + (size_t)(st * 128 + ar + 32 * i) * D_ + aswz, &Ks[(size_t)(i * 256 + tid) * 8]);
    __syncthreads();
    f16x8 kf[4][2];
#pragma unroll
    for (int ni = 0; ni < 4; ++ni) {
      const int row = wn * 64 + ni * 16 + lr;
#pragma unroll
      for (int kk = 0; kk < 2; ++kk)
        kf[ni][kk] = *(const f16x8*)&Ks[row * 64 + (((kk * 4 + lk) ^ (row & 7)) << 3)];
    }
    f32x4 acc[4][4] = {};
#pragma unroll
    for (int kk = 0; kk < 2; ++kk)
#pragma unroll
      for (int mi = 0; mi < 4; ++mi)
#pragma unroll
        for (int ni = 0; ni < 4; ++ni)
          acc[mi][ni] = __builtin_amdgcn_mfma_f32_16x16x32_f16(
              qf[mi][kk], kf[ni][kk], acc[mi][ni], 0, 0, 0);
#pragma unroll
    for (int mi = 0; mi < 4; ++mi)
#pragma unroll
      for (int r = 0; r < 4; ++r) {
        float v = __expf(acc[mi][0][r] * 0.125f) + __expf(acc[mi][1][r] * 0.125f) +
                  __expf(acc[mi][2][r] * 0.125f) + __expf(acc[mi][3][r] * 0.125f);
        v += __shfl_xor(v, 1); v += __shfl_xor(v, 2);
        v += __shfl_xor(v, 4); v += __shfl_xor(v, 8);
        lsum[mi][r] += v;
      }
  }

  // ---- cross-wave combine of the two wn-halves (sL aliases head of Ps) ----
  float* sL = (float*)Ps;  // sL[2][128]: [wn][row]; Ps not yet in use
  if (lr == 0) {
#pragma unroll
    for (int mi = 0; mi < 4; ++mi)
#pragma unroll
      for (int r = 0; r < 4; ++r)
        sL[wn * 128 + wm * 64 + mi * 16 + lk * 4 + r] = lsum[mi][r];
  }
  __syncthreads();
  float rl[4][4];
#pragma unroll
  for (int mi = 0; mi < 4; ++mi)
#pragma unroll
    for (int r = 0; r < 4; ++r) {
      const int row = wm * 64 + mi * 16 + lk * 4 + r;
      rl[mi][r] = 1.0f / (sL[row] + sL[128 + row]);
    }
  __syncthreads();  // sL reads retired before Ps writes begin

  // ---- phase B ----
  float* Cg = attn + (size_t)bh * T_ * T_;
  f32x4 cacc[4][2] = {};
  for (int st = 0; st < 8; ++st) {
    __syncthreads();
#pragma unroll
    for (int i = 0; i < 4; ++i)
      gload16(Kg + (size_t)(st * 128 + ar + 32 * i) * D_ + aswz, &Ks[(size_t)(i * 256 + tid) * 8]);
#pragma unroll
    for (int i = 0; i < 4; ++i) {
      const int c = i * 256 + tid;
      const int row = c >> 4, ch = c & 15;  // Vs: 64 rows x 16 chunks
      gload16(Vg + (size_t)row * T_ + st * 128 + ((ch ^ (row & 7)) << 3), &Vs[(size_t)c * 8]);
    }
    __syncthreads();
    f16x8 kf[4][2], vf[2][4];
#pragma unroll
    for (int ni = 0; ni < 4; ++ni) {
      const int row = wn * 64 + ni * 16 + lr;
#pragma unroll
      for (int kk = 0; kk < 2; ++kk)
        kf[ni][kk] = *(const f16x8*)&Ks[row * 64 + (((kk * 4 + lk) ^ (row & 7)) << 3)];
    }
#pragma unroll
    for (int ni = 0; ni < 2; ++ni) {
      const int row = wn * 32 + ni * 16 + lr;
#pragma unroll
      for (int kk = 0; kk < 4; ++kk)
        vf[ni][kk] = *(const f16x8*)&Vs[row * 128 + (((kk * 4 + lk) ^ (row & 7)) << 3)];
    }
    f32x4 acc[4][4] = {};
#pragma unroll
    for (int kk = 0; kk < 2; ++kk)
#pragma unroll
      for (int mi = 0; mi < 4; ++mi)
#pragma unroll
        for (int ni = 0; ni < 4; ++ni)
          acc[mi][ni] = __builtin_amdgcn_mfma_f32_16x16x32_f16(
              qf[mi][kk], kf[ni][kk], acc[mi][ni], 0, 0, 0);
    // normalize, write fp32 attn, stash f16 P in swizzled LDS
#pragma unroll
    for (int mi = 0; mi < 4; ++mi) {
      const int trow = wm * 64 + mi * 16 + lk * 4;
#pragma unroll
      for (int ni = 0; ni < 4; ++ni) {
        const int scol = wn * 64 + ni * 16 + lr;
#pragma unroll
        for (int r = 0; r < 4; ++r) {
          const int t = trow + r;
          float p = __expf(acc[mi][ni][r] * 0.125f) * rl[mi][r];
          Cg[(size_t)(blockIdx.x * 128 + t) * T_ + (st * 128 + scol)] = p;
          Ps[t * 128 + (scol ^ ((t & 7) << 3))] = f2h(p);
        }
      }
    }
    __syncthreads();  // Ps visible
    // PV: ctx[t][j] += P[t][s] * vt[j][s]
#pragma unroll
    for (int kk = 0; kk < 4; ++kk) {
      f16x8 af[4];
#pragma unroll
      for (int mi = 0; mi < 4; ++mi) {
        const int row = wm * 64 + mi * 16 + lr;
        af[mi] = *(const f16x8*)&Ps[row * 128 + (((kk * 4 + lk) ^ (row & 7)) << 3)];
      }
#pragma unroll
      for (int mi = 0; mi < 4; ++mi)
#pragma unroll
        for (int ni = 0; ni < 2; ++ni)
          cacc[mi][ni] = __builtin_amdgcn_mfma_f32_16x16x32_f16(
              af[mi], vf[ni][kk], cacc[mi][ni], 0, 0, 0);
    }
  }

  unsigned short* Cb = ctxb + (size_t)b * T_ * D_ + h * DH_;
  const int crow0 = blockIdx.x * 128 + wm * 64 + lk * 4;
  const int ccol0 = wn * 32 + lr;
#pragma unroll
  for (int mi = 0; mi < 4; ++mi)
#pragma unroll
    for (int ni = 0; ni < 2; ++ni)
#pragma unroll
      for (int r = 0; r < 4; ++r)
        Cb[(size_t)(crow0 + mi * 16 + r) * D_ + ccol0 + ni * 16] = f2b(cacc[mi][ni][r]);
}

// ---------------- MFMA NT GEMM: C[M][N] = A[M][K] @ Bn[N][K]^T ----------------
// EPI: 0=bias, 1=bias+gelu, 2=bias+res1, 3=scale only, 4=bias+res1+res2,
//      5=bias + f16 write TRANSPOSED per head: vt[(b*16+h)*64 + j][t]
template <int BN, int EPI, bool WF32, bool W16, bool FP16 = false>
__global__ __launch_bounds__(256) void gemm_nt(
    const unsigned short* __restrict__ A, int lda,
    const unsigned short* __restrict__ Bm, int ldb,
    float* __restrict__ Cf, unsigned short* __restrict__ Cb, int ldc,
    const float* __restrict__ bias, const float* __restrict__ r1,
    const float* __restrict__ r2, float scale, int K) {
  constexpr int BM = 128, BK = 64;
  constexpr int WN = BN / 2;
  constexpr int FN = WN / 16;
  __shared__ __align__(16) unsigned short As[BM * BK];
  __shared__ __align__(16) unsigned short Bs[BN * BK];
  const int tid = threadIdx.x;
  const int l = tid & 63;
  const int w = tid >> 6;
  const int wm = w >> 1, wn = w & 1;
  const unsigned short* Ab = A + (size_t)blockIdx.y * BM * lda;
  const unsigned short* Bb = Bm + (size_t)blockIdx.x * BN * ldb;

  const int ar = tid >> 3;
  const int ac = tid & 7;
  const int aswz = ((ac ^ (ar & 7)) << 3);

  f32x4 acc[4][FN] = {};

  for (int k0 = 0; k0 < K; k0 += BK) {
#pragma unroll
    for (int i = 0; i < 4; ++i)
      gload16(Ab + (size_t)(ar + 32 * i) * lda + k0 + aswz, &As[(size_t)(i * 256 + tid) * 8]);
#pragma unroll
    for (int i = 0; i < BN / 32; ++i)
      gload16(Bb + (size_t)(ar + 32 * i) * ldb + k0 + aswz, &Bs[(size_t)(i * 256 + tid) * 8]);
    __syncthreads();

    bf16x8 af[4][2], bfr[FN][2];
    const int lk = l >> 4;
#pragma unroll
    for (int mi = 0; mi < 4; ++mi) {
      const int row = wm * 64 + mi * 16 + (l & 15);
#pragma unroll
      for (int kk = 0; kk < 2; ++kk) {
        const int ch = (kk * 4 + lk) ^ (row & 7);
        af[mi][kk] = *(const bf16x8*)&As[row * BK + ch * 8];
      }
    }
#pragma unroll
    for (int ni = 0; ni < FN; ++ni) {
      const int row = wn * WN + ni * 16 + (l & 15);
#pragma unroll
      for (int kk = 0; kk < 2; ++kk) {
        const int ch = (kk * 4 + lk) ^ (row & 7);
        bfr[ni][kk] = *(const bf16x8*)&Bs[row * BK + ch * 8];
      }
    }
#pragma unroll
    for (int kk = 0; kk < 2; ++kk)
#pragma unroll
      for (int mi = 0; mi < 4; ++mi)
#pragma unroll
        for (int ni = 0; ni < FN; ++ni)
          acc[mi][ni] = __builtin_amdgcn_mfma_f32_16x16x32_bf16(
              af[mi][kk], bfr[ni][kk], acc[mi][ni], 0, 0, 0);
    __syncthreads();
  }

  const int crow0 = blockIdx.y * BM + wm * 64 + (l >> 4) * 4;
  const int ccol0 = blockIdx.x * BN + wn * WN + (l & 15);
  if constexpr (EPI == 5) {
#pragma unroll
    for (int mi = 0; mi < 4; ++mi)
#pragma unroll
      for (int ni = 0; ni < FN; ++ni) {
        const int row0 = crow0 + mi * 16;  // b*1024 + t0, t0 multiple of 4
        const int col = ccol0 + ni * 16;   // h*64 + j
        unsigned short __attribute__((aligned(8))) p4[4];
#pragma unroll
        for (int r = 0; r < 4; ++r) p4[r] = f2h(acc[mi][ni][r] + bias[col]);
        const int bidx = row0 >> 10, t0 = row0 & 1023;
        const int hh = col >> 6, j = col & 63;
        *(uint2*)&Cb[(((size_t)bidx * 16 + hh) * 64 + j) * T_ + t0] = *(uint2*)p4;
      }
  } else {
#pragma unroll
    for (int mi = 0; mi < 4; ++mi)
#pragma unroll
      for (int ni = 0; ni < FN; ++ni)
#pragma unroll
        for (int r = 0; r < 4; ++r) {
          const int row = crow0 + mi * 16 + r;
          const int col = ccol0 + ni * 16;
          float v = acc[mi][ni][r] * scale;
          if (EPI != 3) v += bias[col];
          if (EPI == 1) v = gelu_f(v);
          const size_t off = (size_t)row * ldc + col;
          if (EPI == 2) v += r1[off];
          if (EPI == 4) v += r1[off] + r2[off];
          if (WF32) Cf[off] = v;
          if (W16) Cb[off] = FP16 ? f2h(v) : f2b(v);
        }
  }
}

extern "C" void kernel_launch(void* const* d_in, const int* in_sizes, int n_in,
                              void* d_out, int out_size, void* d_ws, size_t ws_size,
                              hipStream_t stream) {
  const float* x    = (const float*)d_in[0];
  const float* sp   = (const float*)d_in[1];
  const float* ed   = (const float*)d_in[2];
  const float* ln1g = (const float*)d_in[3];
  const float* ln1b = (const float*)d_in[4];
  const float* Wq   = (const float*)d_in[5];
  const float* bq   = (const float*)d_in[6];
  const float* Wk   = (const float*)d_in[7];
  const float* bk   = (const float*)d_in[8];
  const float* Wv   = (const float*)d_in[9];
  const float* bvv  = (const float*)d_in[10];
  const float* Wo   = (const float*)d_in[11];
  const float* bo   = (const float*)d_in[12];
  const float* ln2g = (const float*)d_in[13];
  const float* ln2b = (const float*)d_in[14];
  const float* W1   = (const float*)d_in[15];
  const float* b1   = (const float*)d_in[16];
  const float* W2   = (const float*)d_in[17];
  const float* b2   = (const float*)d_in[18];
  const float* lnbg = (const float*)d_in[19];
  const float* lnbb = (const float*)d_in[20];

  float* out_x = (float*)d_out;        // B*T*D fp32
  float* attn  = out_x + BTD;          // B*H*T*T fp32 (output #2)
  float* tt    = out_x;                // post-Wo+residual scratch in out x region

  const size_t MB = 1 << 20;
  char* wsb = (char*)d_ws;
  float*          xn    = (float*)(wsb);                    // [0,16) fp32; reused as y
  unsigned short* xn_b  = (unsigned short*)(wsb + 16 * MB); // [16,24): xn_b -> ctx_b -> y_b
  unsigned short* WqT   = (unsigned short*)(wsb + 24 * MB);
  unsigned short* WkT   = (unsigned short*)(wsb + 26 * MB);
  unsigned short* WvT   = (unsigned short*)(wsb + 28 * MB);
  unsigned short* WoT   = (unsigned short*)(wsb + 30 * MB);
  unsigned short* W1T   = (unsigned short*)(wsb + 32 * MB); // [32,40)
  unsigned short* W2T   = (unsigned short*)(wsb + 40 * MB); // [40,48)
  unsigned short* q_h   = (unsigned short*)(wsb + 48 * MB); // [48,56) f16, dead after attn
  unsigned short* kb_h  = (unsigned short*)(wsb + 56 * MB); // [56,64) f16, dead after attn
  unsigned short* vt    = (unsigned short*)(wsb + 80 * MB); // [80,88) f16 V^T, dead after attn
  unsigned short* ctx_b = xn_b;                             // [16,24)
  unsigned short* h1_b  = (unsigned short*)(wsb + 48 * MB); // [48,80) (q_h/kb_h dead)
  float*          h2    = (float*)(wsb + 80 * MB);          // [80,96) (vt dead)
  float*          y     = xn;
  unsigned short* y_b   = xn_b;

  dim3 blk(256);
  dim3 g_dd(8, 32);

  // 1. LN1 -> xn (fp32 residual) + xn_b (bf16 GEMM operand)
  ln_rows<<<BT_, blk, 0, stream>>>(x, nullptr, ln1g, ln1b, xn, xn_b);
  // 2. weight transpose+cast
  tcast4<<<dim3(32, 32, 4), blk, 0, stream>>>(Wq, Wk, Wv, Wo, WqT, WkT, WvT, WoT);
  tcast_t<<<dim3(128, 32), blk, 0, stream>>>(W1, W1T, 1024, 4096);
  tcast_t<<<dim3(32, 128), blk, 0, stream>>>(W2, W2T, 4096, 1024);
  // 3-5. Q -> f16, K(+sp+ed) -> f16, V -> f16 transposed per head (MFMA)
  gemm_nt<128, 0, false, true, true><<<g_dd, blk, 0, stream>>>(
      xn_b, D_, WqT, D_, nullptr, q_h, D_, bq, nullptr, nullptr, 1.f, D_);
  gemm_nt<128, 4, false, true, true><<<g_dd, blk, 0, stream>>>(
      xn_b, D_, WkT, D_, nullptr, kb_h, D_, bk, sp, ed, 1.f, D_);
  gemm_nt<128, 5, false, true, true><<<g_dd, blk, 0, stream>>>(
      xn_b, D_, WvT, D_, nullptr, vt, D_, bvv, nullptr, nullptr, 1.f, D_);
  // 6. fused scores + softmax + ctx (attn fp32 -> d_out, ctx bf16 -> ws)
  attn_fused<<<dim3(8, 64), blk, 0, stream>>>(q_h, kb_h, vt, attn, ctx_b);
  // 7. tt = ctx @ Wo + bo + xn (MFMA)
  gemm_nt<128, 2, true, false><<<g_dd, blk, 0, stream>>>(
      ctx_b, D_, WoT, D_, tt, nullptr, D_, bo, xn, nullptr, 1.f, D_);
  // 8. y = LN2(tt)
  ln_rows<<<BT_, blk, 0, stream>>>(tt, nullptr, ln2g, ln2b, y, y_b);
  // 9. h1 = gelu(y @ W1 + b1) -> bf16 (MFMA, fast gelu)
  gemm_nt<128, 1, false, true><<<dim3(32, 32), blk, 0, stream>>>(
      y_b, D_, W1T, D_, nullptr, h1_b, F_, b1, nullptr, nullptr, 1.f, D_);
  // 10. h2 = y + (h1 @ W2 + b2)  (MFMA, fp32 out; final-LN input prefused)
  gemm_nt<128, 2, true, false><<<g_dd, blk, 0, stream>>>(
      h1_b, F_, W2T, F_, h2, nullptr, D_, b2, y, nullptr, 1.f, F_);
  // 11. out = LN(h2)
  ln_rows<<<BT_, blk, 0, stream>>>(h2, nullptr, lnbg, lnbb, out_x, nullptr);
}

// Round 10
// 414.373 us; speedup vs baseline: 4.5581x; 1.0631x over previous
//
#include <hip/hip_runtime.h>
#include <hip/hip_bf16.h>
#include <hip/hip_fp16.h>
#include <math.h>

#define B_ 4
#define T_ 1024
#define D_ 1024
#define H_ 16
#define DH_ 64
#define F_ 4096
#define BT_ (B_ * T_)
#define BTD ((size_t)B_ * T_ * D_)

typedef short bf16x8 __attribute__((ext_vector_type(8)));
typedef _Float16 f16x8 __attribute__((ext_vector_type(8)));
typedef float f32x4 __attribute__((ext_vector_type(4)));

__device__ __forceinline__ unsigned short f2b(float f) {
  __hip_bfloat16 h = __float2bfloat16(f);
  return *reinterpret_cast<unsigned short*>(&h);
}
__device__ __forceinline__ unsigned short f2h(float f) {
  __half h = __float2half(f);
  return *reinterpret_cast<unsigned short*>(&h);
}

__device__ __forceinline__ void gload16(const unsigned short* g, unsigned short* l) {
  __builtin_amdgcn_global_load_lds(
      (const __attribute__((address_space(1))) unsigned int*)(const void*)g,
      (__attribute__((address_space(3))) unsigned int*)(void*)l, 16, 0, 0);
}

// tanh-approx GELU via sigmoid identity: 0.5*(1+tanh(z)) = sigmoid(2z).
__device__ __forceinline__ float gelu_f(float x) {
  float z2 = 1.5957691216057308f * (x + 0.044715f * x * x * x);
  return x / (1.0f + __expf(-z2));
}

// ---------------- block reductions (256 threads, wave64) ----------------
__device__ __forceinline__ float blk_sum256(float v, float* s4) {
#pragma unroll
  for (int off = 32; off > 0; off >>= 1) v += __shfl_down(v, off);
  if ((threadIdx.x & 63) == 0) s4[threadIdx.x >> 6] = v;
  __syncthreads();
  float t = s4[0] + s4[1] + s4[2] + s4[3];
  __syncthreads();
  return t;
}

// ---------------- LayerNorm rows of D=1024, fp32 out + optional bf16 out ----
__global__ __launch_bounds__(256) void ln_rows(
    const float* __restrict__ in, const float* __restrict__ in2,
    const float* __restrict__ g, const float* __restrict__ bb,
    float* __restrict__ outf, unsigned short* __restrict__ outb) {
  __shared__ float s4[4];
  const size_t base = (size_t)blockIdx.x * D_;
  const int t = threadIdx.x;
  float4 v = ((const float4*)(in + base))[t];
  if (in2) {
    float4 w = ((const float4*)(in2 + base))[t];
    v.x += w.x; v.y += w.y; v.z += w.z; v.w += w.w;
  }
  float mean = blk_sum256(v.x + v.y + v.z + v.w, s4) * (1.0f / D_);
  float dx = v.x - mean, dy = v.y - mean, dz = v.z - mean, dw = v.w - mean;
  float var = blk_sum256(dx * dx + dy * dy + dz * dz + dw * dw, s4) * (1.0f / D_);
  float rstd = rsqrtf(var + 1e-5f);
  float4 gv = ((const float4*)g)[t];
  float4 bv = ((const float4*)bb)[t];
  float4 o;
  o.x = dx * rstd * gv.x + bv.x;
  o.y = dy * rstd * gv.y + bv.y;
  o.z = dz * rstd * gv.z + bv.z;
  o.w = dw * rstd * gv.w + bv.w;
  if (outf) ((float4*)(outf + base))[t] = o;
  if (outb) {
    unsigned short o4[4] = {f2b(o.x), f2b(o.y), f2b(o.z), f2b(o.w)};
    *(uint2*)(&outb[base + (size_t)t * 4]) = *(uint2*)o4;
  }
}

// ---------------- transpose+cast fp32 [R][C] -> bf16 [C][R] ----------------
__global__ __launch_bounds__(256) void tcast_t(
    const float* __restrict__ in, unsigned short* __restrict__ out, int R, int C) {
  __shared__ unsigned short tile[32][33];
  const int c0 = blockIdx.x * 32, r0 = blockIdx.y * 32;
  const int col = threadIdx.x & 31, rq = threadIdx.x >> 5;
#pragma unroll
  for (int i = 0; i < 4; ++i) {
    int r = rq + i * 8;
    tile[r][col] = f2b(in[(size_t)(r0 + r) * C + c0 + col]);
  }
  __syncthreads();
#pragma unroll
  for (int i = 0; i < 4; ++i) {
    int r = rq + i * 8;
    out[(size_t)(c0 + r) * R + r0 + col] = tile[col][r];
  }
}

// four 1024x1024 weights at once (z selects)
__global__ __launch_bounds__(256) void tcast4(
    const float* w0, const float* w1, const float* w2, const float* w3,
    unsigned short* o0, unsigned short* o1, unsigned short* o2, unsigned short* o3) {
  __shared__ unsigned short tile[32][33];
  const float* in = blockIdx.z == 0 ? w0 : blockIdx.z == 1 ? w1 : blockIdx.z == 2 ? w2 : w3;
  unsigned short* out = blockIdx.z == 0 ? o0 : blockIdx.z == 1 ? o1 : blockIdx.z == 2 ? o2 : o3;
  const int c0 = blockIdx.x * 32, r0 = blockIdx.y * 32;
  const int col = threadIdx.x & 31, rq = threadIdx.x >> 5;
#pragma unroll
  for (int i = 0; i < 4; ++i) {
    int r = rq + i * 8;
    tile[r][col] = f2b(in[(size_t)(r0 + r) * D_ + c0 + col]);
  }
  __syncthreads();
#pragma unroll
  for (int i = 0; i < 4; ++i) {
    int r = rq + i * 8;
    out[(size_t)(c0 + r) * D_ + r0 + col] = tile[col][r];
  }
}

// ---------------- fused attention: scores + softmax + ctx -------------------
__global__ __launch_bounds__(256) void attn_fused(
    const unsigned short* __restrict__ qh, const unsigned short* __restrict__ kh,
    const unsigned short* __restrict__ vt, float* __restrict__ attn,
    unsigned short* __restrict__ ctxb) {
  __shared__ __align__(16) unsigned short Qs[128 * 64];
  __shared__ __align__(16) unsigned short Ks[128 * 64];
  __shared__ __align__(16) unsigned short Vs[64 * 128];
  __shared__ __align__(16) unsigned short Ps[128 * 128];
  const int tid = threadIdx.x;
  const int l = tid & 63, w = tid >> 6;
  const int wm = w >> 1, wn = w & 1;
  const int lk = l >> 4, lr = l & 15;
  const int bh = blockIdx.y, b = bh >> 4, h = bh & 15;
  const unsigned short* Qg = qh + (size_t)b * T_ * D_ + h * DH_ + (size_t)blockIdx.x * 128 * D_;
  const unsigned short* Kg = kh + (size_t)b * T_ * D_ + h * DH_;
  const unsigned short* Vg = vt + (size_t)bh * 64 * T_;

  const int ar = tid >> 3, ac = tid & 7;
  const int aswz = ((ac ^ (ar & 7)) << 3);

#pragma unroll
  for (int i = 0; i < 4; ++i)
    gload16(Qg + (size_t)(ar + 32 * i) * D_ + aswz, &Qs[(size_t)(i * 256 + tid) * 8]);
  __syncthreads();
  f16x8 qf[4][2];
#pragma unroll
  for (int mi = 0; mi < 4; ++mi) {
    const int row = wm * 64 + mi * 16 + lr;
#pragma unroll
    for (int kk = 0; kk < 2; ++kk)
      qf[mi][kk] = *(const f16x8*)&Qs[row * 64 + (((kk * 4 + lk) ^ (row & 7)) << 3)];
  }

  float lsum[4][4] = {};

  // ---- phase A ----
  for (int st = 0; st < 8; ++st) {
    __syncthreads();
#pragma unroll
    for (int i = 0; i < 4; ++i)
      gload16(Kg + (size_t)(st * 128 + ar + 32 * i) * D_ + aswz, &Ks[(size_t)(i * 256 + tid) * 8]);
    __syncthreads();
    f16x8 kf[4][2];
#pragma unroll
    for (int ni = 0; ni < 4; ++ni) {
      const int row = wn * 64 + ni * 16 + lr;
#pragma unroll
      for (int kk = 0; kk < 2; ++kk)
        kf[ni][kk] = *(const f16x8*)&Ks[row * 64 + (((kk * 4 + lk) ^ (row & 7)) << 3)];
    }
    f32x4 acc[4][4] = {};
#pragma unroll
    for (int kk = 0; kk < 2; ++kk)
#pragma unroll
      for (int mi = 0; mi < 4; ++mi)
#pragma unroll
        for (int ni = 0; ni < 4; ++ni)
          acc[mi][ni] = __builtin_amdgcn_mfma_f32_16x16x32_f16(
              qf[mi][kk], kf[ni][kk], acc[mi][ni], 0, 0, 0);
#pragma unroll
    for (int mi = 0; mi < 4; ++mi)
#pragma unroll
      for (int r = 0; r < 4; ++r) {
        float v = __expf(acc[mi][0][r] * 0.125f) + __expf(acc[mi][1][r] * 0.125f) +
                  __expf(acc[mi][2][r] * 0.125f) + __expf(acc[mi][3][r] * 0.125f);
        v += __shfl_xor(v, 1); v += __shfl_xor(v, 2);
        v += __shfl_xor(v, 4); v += __shfl_xor(v, 8);
        lsum[mi][r] += v;
      }
  }

  float* sL = (float*)Ps;
  if (lr == 0) {
#pragma unroll
    for (int mi = 0; mi < 4; ++mi)
#pragma unroll
      for (int r = 0; r < 4; ++r)
        sL[wn * 128 + wm * 64 + mi * 16 + lk * 4 + r] = lsum[mi][r];
  }
  __syncthreads();
  float rl[4][4];
#pragma unroll
  for (int mi = 0; mi < 4; ++mi)
#pragma unroll
    for (int r = 0; r < 4; ++r) {
      const int row = wm * 64 + mi * 16 + lk * 4 + r;
      rl[mi][r] = 1.0f / (sL[row] + sL[128 + row]);
    }
  __syncthreads();

  // ---- phase B ----
  float* Cg = attn + (size_t)bh * T_ * T_;
  f32x4 cacc[4][2] = {};
  for (int st = 0; st < 8; ++st) {
    __syncthreads();
#pragma unroll
    for (int i = 0; i < 4; ++i)
      gload16(Kg + (size_t)(st * 128 + ar + 32 * i) * D_ + aswz, &Ks[(size_t)(i * 256 + tid) * 8]);
#pragma unroll
    for (int i = 0; i < 4; ++i) {
      const int c = i * 256 + tid;
      const int row = c >> 4, ch = c & 15;
      gload16(Vg + (size_t)row * T_ + st * 128 + ((ch ^ (row & 7)) << 3), &Vs[(size_t)c * 8]);
    }
    __syncthreads();
    f16x8 kf[4][2], vf[2][4];
#pragma unroll
    for (int ni = 0; ni < 4; ++ni) {
      const int row = wn * 64 + ni * 16 + lr;
#pragma unroll
      for (int kk = 0; kk < 2; ++kk)
        kf[ni][kk] = *(const f16x8*)&Ks[row * 64 + (((kk * 4 + lk) ^ (row & 7)) << 3)];
    }
#pragma unroll
    for (int ni = 0; ni < 2; ++ni) {
      const int row = wn * 32 + ni * 16 + lr;
#pragma unroll
      for (int kk = 0; kk < 4; ++kk)
        vf[ni][kk] = *(const f16x8*)&Vs[row * 128 + (((kk * 4 + lk) ^ (row & 7)) << 3)];
    }
    f32x4 acc[4][4] = {};
#pragma unroll
    for (int kk = 0; kk < 2; ++kk)
#pragma unroll
      for (int mi = 0; mi < 4; ++mi)
#pragma unroll
        for (int ni = 0; ni < 4; ++ni)
          acc[mi][ni] = __builtin_amdgcn_mfma_f32_16x16x32_f16(
              qf[mi][kk], kf[ni][kk], acc[mi][ni], 0, 0, 0);
#pragma unroll
    for (int mi = 0; mi < 4; ++mi) {
      const int trow = wm * 64 + mi * 16 + lk * 4;
#pragma unroll
      for (int ni = 0; ni < 4; ++ni) {
        const int scol = wn * 64 + ni * 16 + lr;
#pragma unroll
        for (int r = 0; r < 4; ++r) {
          const int t = trow + r;
          float p = __expf(acc[mi][ni][r] * 0.125f) * rl[mi][r];
          Cg[(size_t)(blockIdx.x * 128 + t) * T_ + (st * 128 + scol)] = p;
          Ps[t * 128 + (scol ^ ((t & 7) << 3))] = f2h(p);
        }
      }
    }
    __syncthreads();
#pragma unroll
    for (int kk = 0; kk < 4; ++kk) {
      f16x8 af[4];
#pragma unroll
      for (int mi = 0; mi < 4; ++mi) {
        const int row = wm * 64 + mi * 16 + lr;
        af[mi] = *(const f16x8*)&Ps[row * 128 + (((kk * 4 + lk) ^ (row & 7)) << 3)];
      }
#pragma unroll
      for (int mi = 0; mi < 4; ++mi)
#pragma unroll
        for (int ni = 0; ni < 2; ++ni)
          cacc[mi][ni] = __builtin_amdgcn_mfma_f32_16x16x32_f16(
              af[mi], vf[ni][kk], cacc[mi][ni], 0, 0, 0);
    }
  }

  unsigned short* Cb = ctxb + (size_t)b * T_ * D_ + h * DH_;
  const int crow0 = blockIdx.x * 128 + wm * 64 + lk * 4;
  const int ccol0 = wn * 32 + lr;
#pragma unroll
  for (int mi = 0; mi < 4; ++mi)
#pragma unroll
    for (int ni = 0; ni < 2; ++ni)
#pragma unroll
      for (int r = 0; r < 4; ++r)
        Cb[(size_t)(crow0 + mi * 16 + r) * D_ + ccol0 + ni * 16] = f2b(cacc[mi][ni][r]);
}

// ---------------- MFMA NT GEMM: C[M][N] = A[M][K] @ Bn[N][K]^T ----------------
// EPI: 0=bias, 1=bias+gelu, 2=bias+res1, 3=scale only, 4=bias+res1+res2,
//      5=bias + f16 write TRANSPOSED per head: vt[(b*16+h)*64 + j][t]
// DB: double-buffered LDS, one barrier per K-step (for 1-block/CU grids).
template <int BN, int EPI, bool WF32, bool W16, bool FP16 = false, bool DB = false>
__global__ __launch_bounds__(256) void gemm_nt(
    const unsigned short* __restrict__ A, int lda,
    const unsigned short* __restrict__ Bm, int ldb,
    float* __restrict__ Cf, unsigned short* __restrict__ Cb, int ldc,
    const float* __restrict__ bias, const float* __restrict__ r1,
    const float* __restrict__ r2, float scale, int K) {
  constexpr int BM = 128, BK = 64;
  constexpr int WN = BN / 2;
  constexpr int FN = WN / 16;
  constexpr int NB = DB ? 2 : 1;
  __shared__ __align__(16) unsigned short As[NB][BM * BK];
  __shared__ __align__(16) unsigned short Bs[NB][BN * BK];
  const int tid = threadIdx.x;
  const int l = tid & 63;
  const int w = tid >> 6;
  const int wm = w >> 1, wn = w & 1;
  const int lr = l & 15, lk = l >> 4;
  const unsigned short* Ab = A + (size_t)blockIdx.y * BM * lda;
  const unsigned short* Bb = Bm + (size_t)blockIdx.x * BN * ldb;

  const int ar = tid >> 3;
  const int ac = tid & 7;
  const int aswz = ((ac ^ (ar & 7)) << 3);

  f32x4 acc[4][FN] = {};

  auto stage = [&](int buf, int k0) {
#pragma unroll
    for (int i = 0; i < 4; ++i)
      gload16(Ab + (size_t)(ar + 32 * i) * lda + k0 + aswz, &As[buf][(size_t)(i * 256 + tid) * 8]);
#pragma unroll
    for (int i = 0; i < BN / 32; ++i)
      gload16(Bb + (size_t)(ar + 32 * i) * ldb + k0 + aswz, &Bs[buf][(size_t)(i * 256 + tid) * 8]);
  };
  auto compute = [&](int buf) {
    bf16x8 af[4][2], bfr[FN][2];
#pragma unroll
    for (int mi = 0; mi < 4; ++mi) {
      const int row = wm * 64 + mi * 16 + lr;
#pragma unroll
      for (int kk = 0; kk < 2; ++kk)
        af[mi][kk] = *(const bf16x8*)&As[buf][row * BK + (((kk * 4 + lk) ^ (row & 7)) << 3)];
    }
#pragma unroll
    for (int ni = 0; ni < FN; ++ni) {
      const int row = wn * WN + ni * 16 + lr;
#pragma unroll
      for (int kk = 0; kk < 2; ++kk)
        bfr[ni][kk] = *(const bf16x8*)&Bs[buf][row * BK + (((kk * 4 + lk) ^ (row & 7)) << 3)];
    }
#pragma unroll
    for (int kk = 0; kk < 2; ++kk)
#pragma unroll
      for (int mi = 0; mi < 4; ++mi)
#pragma unroll
        for (int ni = 0; ni < FN; ++ni)
          acc[mi][ni] = __builtin_amdgcn_mfma_f32_16x16x32_bf16(
              af[mi][kk], bfr[ni][kk], acc[mi][ni], 0, 0, 0);
  };

  if constexpr (DB) {
    const int nt = K / BK;
    stage(0, 0);
    int cur = 0;
    for (int t = 0; t < nt; ++t) {
      __syncthreads();                       // vmcnt drain -> buf[cur] ready
      if (t + 1 < nt) stage(cur ^ 1, (t + 1) * BK);
      compute(cur);
      cur ^= 1;
    }
  } else {
    for (int k0 = 0; k0 < K; k0 += BK) {
      stage(0, k0);
      __syncthreads();
      compute(0);
      __syncthreads();
    }
  }

  const int crow0 = blockIdx.y * BM + wm * 64 + lk * 4;
  const int ccol0 = blockIdx.x * BN + wn * WN + lr;
  if constexpr (EPI == 5) {
#pragma unroll
    for (int mi = 0; mi < 4; ++mi)
#pragma unroll
      for (int ni = 0; ni < FN; ++ni) {
        const int row0 = crow0 + mi * 16;
        const int col = ccol0 + ni * 16;
        unsigned short __attribute__((aligned(8))) p4[4];
#pragma unroll
        for (int r = 0; r < 4; ++r) p4[r] = f2h(acc[mi][ni][r] + bias[col]);
        const int bidx = row0 >> 10, t0 = row0 & 1023;
        const int hh = col >> 6, j = col & 63;
        *(uint2*)&Cb[(((size_t)bidx * 16 + hh) * 64 + j) * T_ + t0] = *(uint2*)p4;
      }
  } else {
#pragma unroll
    for (int mi = 0; mi < 4; ++mi)
#pragma unroll
      for (int ni = 0; ni < FN; ++ni)
#pragma unroll
        for (int r = 0; r < 4; ++r) {
          const int row = crow0 + mi * 16 + r;
          const int col = ccol0 + ni * 16;
          float v = acc[mi][ni][r] * scale;
          if (EPI != 3) v += bias[col];
          if (EPI == 1) v = gelu_f(v);
          const size_t off = (size_t)row * ldc + col;
          if (EPI == 2) v += r1[off];
          if (EPI == 4) v += r1[off] + r2[off];
          if (WF32) Cf[off] = v;
          if (W16) Cb[off] = FP16 ? f2h(v) : f2b(v);
        }
  }
}

// ---------------- fused QKV: one N=3072 GEMM over contiguous WqT|WkT|WvT ----
// grid (24, 32): blockIdx.x 0-7 -> Q (f16), 8-15 -> K (+sp+ed, f16),
// 16-23 -> V (f16 transposed per head into vt).
__global__ __launch_bounds__(256) void gemm_qkv(
    const unsigned short* __restrict__ A, const unsigned short* __restrict__ Wt,
    const float* __restrict__ bq, const float* __restrict__ bk,
    const float* __restrict__ bv, const float* __restrict__ sp,
    const float* __restrict__ ed, unsigned short* __restrict__ q_h,
    unsigned short* __restrict__ kb_h, unsigned short* __restrict__ vt) {
  constexpr int BM = 128, BN = 128, BK = 64, K = 1024;
  __shared__ __align__(16) unsigned short As[BM * BK];
  __shared__ __align__(16) unsigned short Bs[BN * BK];
  const int tid = threadIdx.x;
  const int l = tid & 63, w = tid >> 6;
  const int wm = w >> 1, wn = w & 1;
  const int lr = l & 15, lk = l >> 4;
  const unsigned short* Ab = A + (size_t)blockIdx.y * BM * D_;
  const unsigned short* Bb = Wt + (size_t)blockIdx.x * BN * D_;
  const int ar = tid >> 3, ac = tid & 7;
  const int aswz = ((ac ^ (ar & 7)) << 3);

  f32x4 acc[4][4] = {};
  for (int k0 = 0; k0 < K; k0 += BK) {
#pragma unroll
    for (int i = 0; i < 4; ++i) {
      gload16(Ab + (size_t)(ar + 32 * i) * D_ + k0 + aswz, &As[(size_t)(i * 256 + tid) * 8]);
      gload16(Bb + (size_t)(ar + 32 * i) * D_ + k0 + aswz, &Bs[(size_t)(i * 256 + tid) * 8]);
    }
    __syncthreads();
    bf16x8 af[4][2], bfr[4][2];
#pragma unroll
    for (int mi = 0; mi < 4; ++mi) {
      const int row = wm * 64 + mi * 16 + lr;
#pragma unroll
      for (int kk = 0; kk < 2; ++kk)
        af[mi][kk] = *(const bf16x8*)&As[row * BK + (((kk * 4 + lk) ^ (row & 7)) << 3)];
    }
#pragma unroll
    for (int ni = 0; ni < 4; ++ni) {
      const int row = wn * 64 + ni * 16 + lr;
#pragma unroll
      for (int kk = 0; kk < 2; ++kk)
        bfr[ni][kk] = *(const bf16x8*)&Bs[row * BK + (((kk * 4 + lk) ^ (row & 7)) << 3)];
    }
#pragma unroll
    for (int kk = 0; kk < 2; ++kk)
#pragma unroll
      for (int mi = 0; mi < 4; ++mi)
#pragma unroll
        for (int ni = 0; ni < 4; ++ni)
          acc[mi][ni] = __builtin_amdgcn_mfma_f32_16x16x32_bf16(
              af[mi][kk], bfr[ni][kk], acc[mi][ni], 0, 0, 0);
    __syncthreads();
  }

  const int seg = blockIdx.x >> 3;  // 0=Q, 1=K, 2=V
  const float* bias = seg == 0 ? bq : seg == 1 ? bk : bv;
  const int crow0 = blockIdx.y * BM + wm * 64 + lk * 4;
  const int ccol0 = blockIdx.x * BN + wn * 64 + lr;  // global col in [0,3072)
  if (seg == 2) {
#pragma unroll
    for (int mi = 0; mi < 4; ++mi)
#pragma unroll
      for (int ni = 0; ni < 4; ++ni) {
        const int row0 = crow0 + mi * 16;          // b*1024 + t0
        const int col = (ccol0 + ni * 16) & 1023;  // h*64 + j
        unsigned short __attribute__((aligned(8))) p4[4];
#pragma unroll
        for (int r = 0; r < 4; ++r) p4[r] = f2h(acc[mi][ni][r] + bias[col]);
        const int bidx = row0 >> 10, t0 = row0 & 1023;
        const int hh = col >> 6, j = col & 63;
        *(uint2*)&vt[(((size_t)bidx * 16 + hh) * 64 + j) * T_ + t0] = *(uint2*)p4;
      }
  } else {
    unsigned short* out = seg == 0 ? q_h : kb_h;
#pragma unroll
    for (int mi = 0; mi < 4; ++mi)
#pragma unroll
      for (int ni = 0; ni < 4; ++ni)
#pragma unroll
        for (int r = 0; r < 4; ++r) {
          const int row = crow0 + mi * 16 + r;
          const int col = (ccol0 + ni * 16) & 1023;
          float v = acc[mi][ni][r] + bias[col];
          const size_t off = (size_t)row * D_ + col;
          if (seg == 1) v += sp[off] + ed[off];
          out[off] = f2h(v);
        }
  }
}

extern "C" void kernel_launch(void* const* d_in, const int* in_sizes, int n_in,
                              void* d_out, int out_size, void* d_ws, size_t ws_size,
                              hipStream_t stream) {
  const float* x    = (const float*)d_in[0];
  const float* sp   = (const float*)d_in[1];
  const float* ed   = (const float*)d_in[2];
  const float* ln1g = (const float*)d_in[3];
  const float* ln1b = (const float*)d_in[4];
  const float* Wq   = (const float*)d_in[5];
  const float* bq   = (const float*)d_in[6];
  const float* Wk   = (const float*)d_in[7];
  const float* bk   = (const float*)d_in[8];
  const float* Wv   = (const float*)d_in[9];
  const float* bvv  = (const float*)d_in[10];
  const float* Wo   = (const float*)d_in[11];
  const float* bo   = (const float*)d_in[12];
  const float* ln2g = (const float*)d_in[13];
  const float* ln2b = (const float*)d_in[14];
  const float* W1   = (const float*)d_in[15];
  const float* b1   = (const float*)d_in[16];
  const float* W2   = (const float*)d_in[17];
  const float* b2   = (const float*)d_in[18];
  const float* lnbg = (const float*)d_in[19];
  const float* lnbb = (const float*)d_in[20];

  float* out_x = (float*)d_out;        // B*T*D fp32
  float* attn  = out_x + BTD;          // B*H*T*T fp32 (output #2)
  float* tt    = out_x;                // post-Wo+residual scratch in out x region

  const size_t MB = 1 << 20;
  char* wsb = (char*)d_ws;
  float*          xn    = (float*)(wsb);                    // [0,16) fp32; reused as y
  unsigned short* xn_b  = (unsigned short*)(wsb + 16 * MB); // [16,24)
  unsigned short* WqT   = (unsigned short*)(wsb + 24 * MB); // [24,30) contiguous Wq|Wk|Wv
  unsigned short* WkT   = (unsigned short*)(wsb + 26 * MB);
  unsigned short* WvT   = (unsigned short*)(wsb + 28 * MB);
  unsigned short* WoT   = (unsigned short*)(wsb + 30 * MB);
  unsigned short* W1T   = (unsigned short*)(wsb + 32 * MB); // [32,40)
  unsigned short* W2T   = (unsigned short*)(wsb + 40 * MB); // [40,48)
  unsigned short* q_h   = (unsigned short*)(wsb + 48 * MB); // [48,56) f16
  unsigned short* kb_h  = (unsigned short*)(wsb + 56 * MB); // [56,64) f16
  unsigned short* vt    = (unsigned short*)(wsb + 80 * MB); // [80,88) f16 V^T
  unsigned short* ctx_b = xn_b;                             // [16,24)
  unsigned short* h1_b  = (unsigned short*)(wsb + 48 * MB); // [48,80)
  float*          h2    = (float*)(wsb + 80 * MB);          // [80,96)
  float*          y     = xn;
  unsigned short* y_b   = xn_b;

  dim3 blk(256);
  dim3 g_dd(8, 32);

  // 1. LN1 -> xn (fp32 residual) + xn_b (bf16 GEMM operand)
  ln_rows<<<BT_, blk, 0, stream>>>(x, nullptr, ln1g, ln1b, xn, xn_b);
  // 2. weight transpose+cast
  tcast4<<<dim3(32, 32, 4), blk, 0, stream>>>(Wq, Wk, Wv, Wo, WqT, WkT, WvT, WoT);
  tcast_t<<<dim3(128, 32), blk, 0, stream>>>(W1, W1T, 1024, 4096);
  tcast_t<<<dim3(32, 128), blk, 0, stream>>>(W2, W2T, 4096, 1024);
  // 3. fused QKV (768 blocks): Q->f16, K(+sp+ed)->f16, V->f16 transposed
  gemm_qkv<<<dim3(24, 32), blk, 0, stream>>>(
      xn_b, WqT, bq, bk, bvv, sp, ed, q_h, kb_h, vt);
  // 4. fused scores + softmax + ctx
  attn_fused<<<dim3(8, 64), blk, 0, stream>>>(q_h, kb_h, vt, attn, ctx_b);
  // 5. tt = ctx @ Wo + bo + xn (MFMA, dbuf)
  gemm_nt<128, 2, true, false, false, true><<<g_dd, blk, 0, stream>>>(
      ctx_b, D_, WoT, D_, tt, nullptr, D_, bo, xn, nullptr, 1.f, D_);
  // 6. y = LN2(tt)
  ln_rows<<<BT_, blk, 0, stream>>>(tt, nullptr, ln2g, ln2b, y, y_b);
  // 7. h1 = gelu(y @ W1 + b1) -> bf16 (MFMA, 1024 blocks, single-buffer)
  gemm_nt<128, 1, false, true><<<dim3(32, 32), blk, 0, stream>>>(
      y_b, D_, W1T, D_, nullptr, h1_b, F_, b1, nullptr, nullptr, 1.f, D_);
  // 8. h2 = y + (h1 @ W2 + b2)  (MFMA, dbuf, fp32 out)
  gemm_nt<128, 2, true, false, false, true><<<g_dd, blk, 0, stream>>>(
      h1_b, F_, W2T, F_, h2, nullptr, D_, b2, y, nullptr, 1.f, F_);
  // 9. out = LN(h2)
  ln_rows<<<BT_, blk, 0, stream>>>(h2, nullptr, lnbg, lnbb, out_x, nullptr);
}

// Round 11
// 394.182 us; speedup vs baseline: 4.7915x; 1.0512x over previous
//
#include <hip/hip_runtime.h>
#include <hip/hip_bf16.h>
#include <hip/hip_fp16.h>
#include <math.h>

#define B_ 4
#define T_ 1024
#define D_ 1024
#define H_ 16
#define DH_ 64
#define F_ 4096
#define BT_ (B_ * T_)
#define BTD ((size_t)B_ * T_ * D_)

typedef short bf16x8 __attribute__((ext_vector_type(8)));
typedef _Float16 f16x8 __attribute__((ext_vector_type(8)));
typedef float f32x4 __attribute__((ext_vector_type(4)));

__device__ __forceinline__ unsigned short f2b(float f) {
  __hip_bfloat16 h = __float2bfloat16(f);
  return *reinterpret_cast<unsigned short*>(&h);
}
__device__ __forceinline__ unsigned short f2h(float f) {
  __half h = __float2half(f);
  return *reinterpret_cast<unsigned short*>(&h);
}

__device__ __forceinline__ void gload16(const unsigned short* g, unsigned short* l) {
  __builtin_amdgcn_global_load_lds(
      (const __attribute__((address_space(1))) unsigned int*)(const void*)g,
      (__attribute__((address_space(3))) unsigned int*)(void*)l, 16, 0, 0);
}

// tanh-approx GELU via sigmoid identity: 0.5*(1+tanh(z)) = sigmoid(2z).
__device__ __forceinline__ float gelu_f(float x) {
  float z2 = 1.5957691216057308f * (x + 0.044715f * x * x * x);
  return x / (1.0f + __expf(-z2));
}

// ---------------- block reductions (256 threads, wave64) ----------------
__device__ __forceinline__ float blk_sum256(float v, float* s4) {
#pragma unroll
  for (int off = 32; off > 0; off >>= 1) v += __shfl_down(v, off);
  if ((threadIdx.x & 63) == 0) s4[threadIdx.x >> 6] = v;
  __syncthreads();
  float t = s4[0] + s4[1] + s4[2] + s4[3];
  __syncthreads();
  return t;
}

// ---------------- LayerNorm rows of D=1024, fp32 out + optional bf16 out ----
__global__ __launch_bounds__(256) void ln_rows(
    const float* __restrict__ in, const float* __restrict__ in2,
    const float* __restrict__ g, const float* __restrict__ bb,
    float* __restrict__ outf, unsigned short* __restrict__ outb) {
  __shared__ float s4[4];
  const size_t base = (size_t)blockIdx.x * D_;
  const int t = threadIdx.x;
  float4 v = ((const float4*)(in + base))[t];
  if (in2) {
    float4 w = ((const float4*)(in2 + base))[t];
    v.x += w.x; v.y += w.y; v.z += w.z; v.w += w.w;
  }
  float mean = blk_sum256(v.x + v.y + v.z + v.w, s4) * (1.0f / D_);
  float dx = v.x - mean, dy = v.y - mean, dz = v.z - mean, dw = v.w - mean;
  float var = blk_sum256(dx * dx + dy * dy + dz * dz + dw * dw, s4) * (1.0f / D_);
  float rstd = rsqrtf(var + 1e-5f);
  float4 gv = ((const float4*)g)[t];
  float4 bv = ((const float4*)bb)[t];
  float4 o;
  o.x = dx * rstd * gv.x + bv.x;
  o.y = dy * rstd * gv.y + bv.y;
  o.z = dz * rstd * gv.z + bv.z;
  o.w = dw * rstd * gv.w + bv.w;
  if (outf) ((float4*)(outf + base))[t] = o;
  if (outb) {
    unsigned short o4[4] = {f2b(o.x), f2b(o.y), f2b(o.z), f2b(o.w)};
    *(uint2*)(&outb[base + (size_t)t * 4]) = *(uint2*)o4;
  }
}

// ---------------- transpose+cast fp32 [R][C] -> bf16 [C][R] ----------------
__global__ __launch_bounds__(256) void tcast_t(
    const float* __restrict__ in, unsigned short* __restrict__ out, int R, int C) {
  __shared__ unsigned short tile[32][33];
  const int c0 = blockIdx.x * 32, r0 = blockIdx.y * 32;
  const int col = threadIdx.x & 31, rq = threadIdx.x >> 5;
#pragma unroll
  for (int i = 0; i < 4; ++i) {
    int r = rq + i * 8;
    tile[r][col] = f2b(in[(size_t)(r0 + r) * C + c0 + col]);
  }
  __syncthreads();
#pragma unroll
  for (int i = 0; i < 4; ++i) {
    int r = rq + i * 8;
    out[(size_t)(c0 + r) * R + r0 + col] = tile[col][r];
  }
}

// four 1024x1024 weights at once (z selects)
__global__ __launch_bounds__(256) void tcast4(
    const float* w0, const float* w1, const float* w2, const float* w3,
    unsigned short* o0, unsigned short* o1, unsigned short* o2, unsigned short* o3) {
  __shared__ unsigned short tile[32][33];
  const float* in = blockIdx.z == 0 ? w0 : blockIdx.z == 1 ? w1 : blockIdx.z == 2 ? w2 : w3;
  unsigned short* out = blockIdx.z == 0 ? o0 : blockIdx.z == 1 ? o1 : blockIdx.z == 2 ? o2 : o3;
  const int c0 = blockIdx.x * 32, r0 = blockIdx.y * 32;
  const int col = threadIdx.x & 31, rq = threadIdx.x >> 5;
#pragma unroll
  for (int i = 0; i < 4; ++i) {
    int r = rq + i * 8;
    tile[r][col] = f2b(in[(size_t)(r0 + r) * D_ + c0 + col]);
  }
  __syncthreads();
#pragma unroll
  for (int i = 0; i < 4; ++i) {
    int r = rq + i * 8;
    out[(size_t)(c0 + r) * D_ + r0 + col] = tile[col][r];
  }
}

// ---------------- fused attention: scores + softmax + ctx -------------------
// grid (64, 8): x = bh, y = t-tile. XCD = linear_id % 8 = bh % 8, so all 8
// t-tiles of one head share an XCD -> K/V L2-resident (2 MB/XCD working set).
__global__ __launch_bounds__(256) void attn_fused(
    const unsigned short* __restrict__ qh, const unsigned short* __restrict__ kh,
    const unsigned short* __restrict__ vt, float* __restrict__ attn,
    unsigned short* __restrict__ ctxb) {
  __shared__ __align__(16) unsigned short Qs[128 * 64];
  __shared__ __align__(16) unsigned short Ks[128 * 64];
  __shared__ __align__(16) unsigned short Vs[64 * 128];
  __shared__ __align__(16) unsigned short Ps[128 * 128];
  const int tid = threadIdx.x;
  const int l = tid & 63, w = tid >> 6;
  const int wm = w >> 1, wn = w & 1;
  const int lk = l >> 4, lr = l & 15;
  const int bh = blockIdx.x, b = bh >> 4, h = bh & 15;
  const int tt = blockIdx.y;  // t-tile
  const unsigned short* Qg = qh + (size_t)b * T_ * D_ + h * DH_ + (size_t)tt * 128 * D_;
  const unsigned short* Kg = kh + (size_t)b * T_ * D_ + h * DH_;
  const unsigned short* Vg = vt + (size_t)bh * 64 * T_;

  const int ar = tid >> 3, ac = tid & 7;
  const int aswz = ((ac ^ (ar & 7)) << 3);

#pragma unroll
  for (int i = 0; i < 4; ++i)
    gload16(Qg + (size_t)(ar + 32 * i) * D_ + aswz, &Qs[(size_t)(i * 256 + tid) * 8]);
  __syncthreads();
  f16x8 qf[4][2];
#pragma unroll
  for (int mi = 0; mi < 4; ++mi) {
    const int row = wm * 64 + mi * 16 + lr;
#pragma unroll
    for (int kk = 0; kk < 2; ++kk)
      qf[mi][kk] = *(const f16x8*)&Qs[row * 64 + (((kk * 4 + lk) ^ (row & 7)) << 3)];
  }

  float lsum[4][4] = {};

  // ---- phase A ----
  for (int st = 0; st < 8; ++st) {
    __syncthreads();
#pragma unroll
    for (int i = 0; i < 4; ++i)
      gload16(Kg + (size_t)(st * 128 + ar + 32 * i) * D_ + aswz, &Ks[(size_t)(i * 256 + tid) * 8]);
    __syncthreads();
    f16x8 kf[4][2];
#pragma unroll
    for (int ni = 0; ni < 4; ++ni) {
      const int row = wn * 64 + ni * 16 + lr;
#pragma unroll
      for (int kk = 0; kk < 2; ++kk)
        kf[ni][kk] = *(const f16x8*)&Ks[row * 64 + (((kk * 4 + lk) ^ (row & 7)) << 3)];
    }
    f32x4 acc[4][4] = {};
#pragma unroll
    for (int kk = 0; kk < 2; ++kk)
#pragma unroll
      for (int mi = 0; mi < 4; ++mi)
#pragma unroll
        for (int ni = 0; ni < 4; ++ni)
          acc[mi][ni] = __builtin_amdgcn_mfma_f32_16x16x32_f16(
              qf[mi][kk], kf[ni][kk], acc[mi][ni], 0, 0, 0);
#pragma unroll
    for (int mi = 0; mi < 4; ++mi)
#pragma unroll
      for (int r = 0; r < 4; ++r) {
        float v = __expf(acc[mi][0][r] * 0.125f) + __expf(acc[mi][1][r] * 0.125f) +
                  __expf(acc[mi][2][r] * 0.125f) + __expf(acc[mi][3][r] * 0.125f);
        v += __shfl_xor(v, 1); v += __shfl_xor(v, 2);
        v += __shfl_xor(v, 4); v += __shfl_xor(v, 8);
        lsum[mi][r] += v;
      }
  }

  float* sL = (float*)Ps;
  if (lr == 0) {
#pragma unroll
    for (int mi = 0; mi < 4; ++mi)
#pragma unroll
      for (int r = 0; r < 4; ++r)
        sL[wn * 128 + wm * 64 + mi * 16 + lk * 4 + r] = lsum[mi][r];
  }
  __syncthreads();
  float rl[4][4];
#pragma unroll
  for (int mi = 0; mi < 4; ++mi)
#pragma unroll
    for (int r = 0; r < 4; ++r) {
      const int row = wm * 64 + mi * 16 + lk * 4 + r;
      rl[mi][r] = 1.0f / (sL[row] + sL[128 + row]);
    }
  __syncthreads();

  // ---- phase B ----
  float* Cg = attn + (size_t)bh * T_ * T_;
  f32x4 cacc[4][2] = {};
  for (int st = 0; st < 8; ++st) {
    __syncthreads();
#pragma unroll
    for (int i = 0; i < 4; ++i)
      gload16(Kg + (size_t)(st * 128 + ar + 32 * i) * D_ + aswz, &Ks[(size_t)(i * 256 + tid) * 8]);
#pragma unroll
    for (int i = 0; i < 4; ++i) {
      const int c = i * 256 + tid;
      const int row = c >> 4, ch = c & 15;
      gload16(Vg + (size_t)row * T_ + st * 128 + ((ch ^ (row & 7)) << 3), &Vs[(size_t)c * 8]);
    }
    __syncthreads();
    f16x8 kf[4][2], vf[2][4];
#pragma unroll
    for (int ni = 0; ni < 4; ++ni) {
      const int row = wn * 64 + ni * 16 + lr;
#pragma unroll
      for (int kk = 0; kk < 2; ++kk)
        kf[ni][kk] = *(const f16x8*)&Ks[row * 64 + (((kk * 4 + lk) ^ (row & 7)) << 3)];
    }
#pragma unroll
    for (int ni = 0; ni < 2; ++ni) {
      const int row = wn * 32 + ni * 16 + lr;
#pragma unroll
      for (int kk = 0; kk < 4; ++kk)
        vf[ni][kk] = *(const f16x8*)&Vs[row * 128 + (((kk * 4 + lk) ^ (row & 7)) << 3)];
    }
    f32x4 acc[4][4] = {};
#pragma unroll
    for (int kk = 0; kk < 2; ++kk)
#pragma unroll
      for (int mi = 0; mi < 4; ++mi)
#pragma unroll
        for (int ni = 0; ni < 4; ++ni)
          acc[mi][ni] = __builtin_amdgcn_mfma_f32_16x16x32_f16(
              qf[mi][kk], kf[ni][kk], acc[mi][ni], 0, 0, 0);
    // normalize, write fp32 attn (nontemporal: never re-read, keep L2 for K/V)
#pragma unroll
    for (int mi = 0; mi < 4; ++mi) {
      const int trow = wm * 64 + mi * 16 + lk * 4;
#pragma unroll
      for (int ni = 0; ni < 4; ++ni) {
        const int scol = wn * 64 + ni * 16 + lr;
#pragma unroll
        for (int r = 0; r < 4; ++r) {
          const int t = trow + r;
          float p = __expf(acc[mi][ni][r] * 0.125f) * rl[mi][r];
          __builtin_nontemporal_store(
              p, &Cg[(size_t)(tt * 128 + t) * T_ + (st * 128 + scol)]);
          Ps[t * 128 + (scol ^ ((t & 7) << 3))] = f2h(p);
        }
      }
    }
    __syncthreads();
#pragma unroll
    for (int kk = 0; kk < 4; ++kk) {
      f16x8 af[4];
#pragma unroll
      for (int mi = 0; mi < 4; ++mi) {
        const int row = wm * 64 + mi * 16 + lr;
        af[mi] = *(const f16x8*)&Ps[row * 128 + (((kk * 4 + lk) ^ (row & 7)) << 3)];
      }
#pragma unroll
      for (int mi = 0; mi < 4; ++mi)
#pragma unroll
        for (int ni = 0; ni < 2; ++ni)
          cacc[mi][ni] = __builtin_amdgcn_mfma_f32_16x16x32_f16(
              af[mi], vf[ni][kk], cacc[mi][ni], 0, 0, 0);
    }
  }

  unsigned short* Cb = ctxb + (size_t)b * T_ * D_ + h * DH_;
  const int crow0 = tt * 128 + wm * 64 + lk * 4;
  const int ccol0 = wn * 32 + lr;
#pragma unroll
  for (int mi = 0; mi < 4; ++mi)
#pragma unroll
    for (int ni = 0; ni < 2; ++ni)
#pragma unroll
      for (int r = 0; r < 4; ++r)
        Cb[(size_t)(crow0 + mi * 16 + r) * D_ + ccol0 + ni * 16] = f2b(cacc[mi][ni][r]);
}

// ---------------- MFMA NT GEMM: C[M][N] = A[M][K] @ Bn[N][K]^T ----------------
// EPI: 0=bias, 1=bias+gelu, 2=bias+res1, 3=scale only, 4=bias+res1+res2,
//      5=bias + f16 write TRANSPOSED per head: vt[(b*16+h)*64 + j][t]
// DB: double-buffered LDS, one barrier per K-step (for 1-block/CU grids).
template <int BN, int EPI, bool WF32, bool W16, bool FP16 = false, bool DB = false>
__global__ __launch_bounds__(256) void gemm_nt(
    const unsigned short* __restrict__ A, int lda,
    const unsigned short* __restrict__ Bm, int ldb,
    float* __restrict__ Cf, unsigned short* __restrict__ Cb, int ldc,
    const float* __restrict__ bias, const float* __restrict__ r1,
    const float* __restrict__ r2, float scale, int K) {
  constexpr int BM = 128, BK = 64;
  constexpr int WN = BN / 2;
  constexpr int FN = WN / 16;
  constexpr int NB = DB ? 2 : 1;
  __shared__ __align__(16) unsigned short As[NB][BM * BK];
  __shared__ __align__(16) unsigned short Bs[NB][BN * BK];
  const int tid = threadIdx.x;
  const int l = tid & 63;
  const int w = tid >> 6;
  const int wm = w >> 1, wn = w & 1;
  const int lr = l & 15, lk = l >> 4;
  const unsigned short* Ab = A + (size_t)blockIdx.y * BM * lda;
  const unsigned short* Bb = Bm + (size_t)blockIdx.x * BN * ldb;

  const int ar = tid >> 3;
  const int ac = tid & 7;
  const int aswz = ((ac ^ (ar & 7)) << 3);

  f32x4 acc[4][FN] = {};

  auto stage = [&](int buf, int k0) {
#pragma unroll
    for (int i = 0; i < 4; ++i)
      gload16(Ab + (size_t)(ar + 32 * i) * lda + k0 + aswz, &As[buf][(size_t)(i * 256 + tid) * 8]);
#pragma unroll
    for (int i = 0; i < BN / 32; ++i)
      gload16(Bb + (size_t)(ar + 32 * i) * ldb + k0 + aswz, &Bs[buf][(size_t)(i * 256 + tid) * 8]);
  };
  auto compute = [&](int buf) {
    bf16x8 af[4][2], bfr[FN][2];
#pragma unroll
    for (int mi = 0; mi < 4; ++mi) {
      const int row = wm * 64 + mi * 16 + lr;
#pragma unroll
      for (int kk = 0; kk < 2; ++kk)
        af[mi][kk] = *(const bf16x8*)&As[buf][row * BK + (((kk * 4 + lk) ^ (row & 7)) << 3)];
    }
#pragma unroll
    for (int ni = 0; ni < FN; ++ni) {
      const int row = wn * WN + ni * 16 + lr;
#pragma unroll
      for (int kk = 0; kk < 2; ++kk)
        bfr[ni][kk] = *(const bf16x8*)&Bs[buf][row * BK + (((kk * 4 + lk) ^ (row & 7)) << 3)];
    }
#pragma unroll
    for (int kk = 0; kk < 2; ++kk)
#pragma unroll
      for (int mi = 0; mi < 4; ++mi)
#pragma unroll
        for (int ni = 0; ni < FN; ++ni)
          acc[mi][ni] = __builtin_amdgcn_mfma_f32_16x16x32_bf16(
              af[mi][kk], bfr[ni][kk], acc[mi][ni], 0, 0, 0);
  };

  if constexpr (DB) {
    const int nt = K / BK;
    stage(0, 0);
    int cur = 0;
    for (int t = 0; t < nt; ++t) {
      __syncthreads();
      if (t + 1 < nt) stage(cur ^ 1, (t + 1) * BK);
      compute(cur);
      cur ^= 1;
    }
  } else {
    for (int k0 = 0; k0 < K; k0 += BK) {
      stage(0, k0);
      __syncthreads();
      compute(0);
      __syncthreads();
    }
  }

  const int crow0 = blockIdx.y * BM + wm * 64 + lk * 4;
  const int ccol0 = blockIdx.x * BN + wn * WN + lr;
  if constexpr (EPI == 5) {
#pragma unroll
    for (int mi = 0; mi < 4; ++mi)
#pragma unroll
      for (int ni = 0; ni < FN; ++ni) {
        const int row0 = crow0 + mi * 16;
        const int col = ccol0 + ni * 16;
        unsigned short __attribute__((aligned(8))) p4[4];
#pragma unroll
        for (int r = 0; r < 4; ++r) p4[r] = f2h(acc[mi][ni][r] + bias[col]);
        const int bidx = row0 >> 10, t0 = row0 & 1023;
        const int hh = col >> 6, j = col & 63;
        *(uint2*)&Cb[(((size_t)bidx * 16 + hh) * 64 + j) * T_ + t0] = *(uint2*)p4;
      }
  } else {
#pragma unroll
    for (int mi = 0; mi < 4; ++mi)
#pragma unroll
      for (int ni = 0; ni < FN; ++ni)
#pragma unroll
        for (int r = 0; r < 4; ++r) {
          const int row = crow0 + mi * 16 + r;
          const int col = ccol0 + ni * 16;
          float v = acc[mi][ni][r] * scale;
          if (EPI != 3) v += bias[col];
          if (EPI == 1) v = gelu_f(v);
          const size_t off = (size_t)row * ldc + col;
          if (EPI == 2) v += r1[off];
          if (EPI == 4) v += r1[off] + r2[off];
          if (WF32) Cf[off] = v;
          if (W16) Cb[off] = FP16 ? f2h(v) : f2b(v);
        }
  }
}

// ---------------- fused QKV: one N=3072 GEMM over contiguous WqT|WkT|WvT ----
__global__ __launch_bounds__(256) void gemm_qkv(
    const unsigned short* __restrict__ A, const unsigned short* __restrict__ Wt,
    const float* __restrict__ bq, const float* __restrict__ bk,
    const float* __restrict__ bv, const float* __restrict__ sp,
    const float* __restrict__ ed, unsigned short* __restrict__ q_h,
    unsigned short* __restrict__ kb_h, unsigned short* __restrict__ vt) {
  constexpr int BM = 128, BN = 128, BK = 64, K = 1024;
  __shared__ __align__(16) unsigned short As[BM * BK];
  __shared__ __align__(16) unsigned short Bs[BN * BK];
  const int tid = threadIdx.x;
  const int l = tid & 63, w = tid >> 6;
  const int wm = w >> 1, wn = w & 1;
  const int lr = l & 15, lk = l >> 4;
  const unsigned short* Ab = A + (size_t)blockIdx.y * BM * D_;
  const unsigned short* Bb = Wt + (size_t)blockIdx.x * BN * D_;
  const int ar = tid >> 3, ac = tid & 7;
  const int aswz = ((ac ^ (ar & 7)) << 3);

  f32x4 acc[4][4] = {};
  for (int k0 = 0; k0 < K; k0 += BK) {
#pragma unroll
    for (int i = 0; i < 4; ++i) {
      gload16(Ab + (size_t)(ar + 32 * i) * D_ + k0 + aswz, &As[(size_t)(i * 256 + tid) * 8]);
      gload16(Bb + (size_t)(ar + 32 * i) * D_ + k0 + aswz, &Bs[(size_t)(i * 256 + tid) * 8]);
    }
    __syncthreads();
    bf16x8 af[4][2], bfr[4][2];
#pragma unroll
    for (int mi = 0; mi < 4; ++mi) {
      const int row = wm * 64 + mi * 16 + lr;
#pragma unroll
      for (int kk = 0; kk < 2; ++kk)
        af[mi][kk] = *(const bf16x8*)&As[row * BK + (((kk * 4 + lk) ^ (row & 7)) << 3)];
    }
#pragma unroll
    for (int ni = 0; ni < 4; ++ni) {
      const int row = wn * 64 + ni * 16 + lr;
#pragma unroll
      for (int kk = 0; kk < 2; ++kk)
        bfr[ni][kk] = *(const bf16x8*)&Bs[row * BK + (((kk * 4 + lk) ^ (row & 7)) << 3)];
    }
#pragma unroll
    for (int kk = 0; kk < 2; ++kk)
#pragma unroll
      for (int mi = 0; mi < 4; ++mi)
#pragma unroll
        for (int ni = 0; ni < 4; ++ni)
          acc[mi][ni] = __builtin_amdgcn_mfma_f32_16x16x32_bf16(
              af[mi][kk], bfr[ni][kk], acc[mi][ni], 0, 0, 0);
    __syncthreads();
  }

  const int seg = blockIdx.x >> 3;  // 0=Q, 1=K, 2=V
  const float* bias = seg == 0 ? bq : seg == 1 ? bk : bv;
  const int crow0 = blockIdx.y * BM + wm * 64 + lk * 4;
  const int ccol0 = blockIdx.x * BN + wn * 64 + lr;
  if (seg == 2) {
#pragma unroll
    for (int mi = 0; mi < 4; ++mi)
#pragma unroll
      for (int ni = 0; ni < 4; ++ni) {
        const int row0 = crow0 + mi * 16;
        const int col = (ccol0 + ni * 16) & 1023;
        unsigned short __attribute__((aligned(8))) p4[4];
#pragma unroll
        for (int r = 0; r < 4; ++r) p4[r] = f2h(acc[mi][ni][r] + bias[col]);
        const int bidx = row0 >> 10, t0 = row0 & 1023;
        const int hh = col >> 6, j = col & 63;
        *(uint2*)&vt[(((size_t)bidx * 16 + hh) * 64 + j) * T_ + t0] = *(uint2*)p4;
      }
  } else {
    unsigned short* out = seg == 0 ? q_h : kb_h;
#pragma unroll
    for (int mi = 0; mi < 4; ++mi)
#pragma unroll
      for (int ni = 0; ni < 4; ++ni)
#pragma unroll
        for (int r = 0; r < 4; ++r) {
          const int row = crow0 + mi * 16 + r;
          const int col = (ccol0 + ni * 16) & 1023;
          float v = acc[mi][ni][r] + bias[col];
          const size_t off = (size_t)row * D_ + col;
          if (seg == 1) v += sp[off] + ed[off];
          out[off] = f2h(v);
        }
  }
}

extern "C" void kernel_launch(void* const* d_in, const int* in_sizes, int n_in,
                              void* d_out, int out_size, void* d_ws, size_t ws_size,
                              hipStream_t stream) {
  const float* x    = (const float*)d_in[0];
  const float* sp   = (const float*)d_in[1];
  const float* ed   = (const float*)d_in[2];
  const float* ln1g = (const float*)d_in[3];
  const float* ln1b = (const float*)d_in[4];
  const float* Wq   = (const float*)d_in[5];
  const float* bq   = (const float*)d_in[6];
  const float* Wk   = (const float*)d_in[7];
  const float* bk   = (const float*)d_in[8];
  const float* Wv   = (const float*)d_in[9];
  const float* bvv  = (const float*)d_in[10];
  const float* Wo   = (const float*)d_in[11];
  const float* bo   = (const float*)d_in[12];
  const float* ln2g = (const float*)d_in[13];
  const float* ln2b = (const float*)d_in[14];
  const float* W1   = (const float*)d_in[15];
  const float* b1   = (const float*)d_in[16];
  const float* W2   = (const float*)d_in[17];
  const float* b2   = (const float*)d_in[18];
  const float* lnbg = (const float*)d_in[19];
  const float* lnbb = (const float*)d_in[20];

  float* out_x = (float*)d_out;
  float* attn  = out_x + BTD;
  float* tt    = out_x;

  const size_t MB = 1 << 20;
  char* wsb = (char*)d_ws;
  float*          xn    = (float*)(wsb);                    // [0,16)
  unsigned short* xn_b  = (unsigned short*)(wsb + 16 * MB); // [16,24)
  unsigned short* WqT   = (unsigned short*)(wsb + 24 * MB); // [24,30) Wq|Wk|Wv
  unsigned short* WkT   = (unsigned short*)(wsb + 26 * MB);
  unsigned short* WvT   = (unsigned short*)(wsb + 28 * MB);
  unsigned short* WoT   = (unsigned short*)(wsb + 30 * MB);
  unsigned short* W1T   = (unsigned short*)(wsb + 32 * MB); // [32,40)
  unsigned short* W2T   = (unsigned short*)(wsb + 40 * MB); // [40,48)
  unsigned short* q_h   = (unsigned short*)(wsb + 48 * MB); // [48,56)
  unsigned short* kb_h  = (unsigned short*)(wsb + 56 * MB); // [56,64)
  unsigned short* vt    = (unsigned short*)(wsb + 80 * MB); // [80,88)
  unsigned short* ctx_b = xn_b;                             // [16,24)
  unsigned short* h1_b  = (unsigned short*)(wsb + 48 * MB); // [48,80)
  float*          h2    = (float*)(wsb + 80 * MB);          // [80,96)
  float*          y     = xn;
  unsigned short* y_b   = xn_b;

  dim3 blk(256);
  dim3 g_dd(8, 32);

  // 1. LN1 -> xn (fp32 residual) + xn_b (bf16 GEMM operand)
  ln_rows<<<BT_, blk, 0, stream>>>(x, nullptr, ln1g, ln1b, xn, xn_b);
  // 2. weight transpose+cast
  tcast4<<<dim3(32, 32, 4), blk, 0, stream>>>(Wq, Wk, Wv, Wo, WqT, WkT, WvT, WoT);
  tcast_t<<<dim3(128, 32), blk, 0, stream>>>(W1, W1T, 1024, 4096);
  tcast_t<<<dim3(32, 128), blk, 0, stream>>>(W2, W2T, 4096, 1024);
  // 3. fused QKV (768 blocks): Q->f16, K(+sp+ed)->f16, V->f16 transposed
  gemm_qkv<<<dim3(24, 32), blk, 0, stream>>>(
      xn_b, WqT, bq, bk, bvv, sp, ed, q_h, kb_h, vt);
  // 4. fused scores + softmax + ctx (grid transposed: bh on x for XCD locality)
  attn_fused<<<dim3(64, 8), blk, 0, stream>>>(q_h, kb_h, vt, attn, ctx_b);
  // 5. tt = ctx @ Wo + bo + xn (MFMA, dbuf)
  gemm_nt<128, 2, true, false, false, true><<<g_dd, blk, 0, stream>>>(
      ctx_b, D_, WoT, D_, tt, nullptr, D_, bo, xn, nullptr, 1.f, D_);
  // 6. y = LN2(tt)
  ln_rows<<<BT_, blk, 0, stream>>>(tt, nullptr, ln2g, ln2b, y, y_b);
  // 7. h1 = gelu(y @ W1 + b1) -> bf16 (MFMA)
  gemm_nt<128, 1, false, true><<<dim3(32, 32), blk, 0, stream>>>(
      y_b, D_, W1T, D_, nullptr, h1_b, F_, b1, nullptr, nullptr, 1.f, D_);
  // 8. h2 = y + (h1 @ W2 + b2)  (MFMA, dbuf, fp32 out)
  gemm_nt<128, 2, true, false, false, true><<<g_dd, blk, 0, stream>>>(
      h1_b, F_, W2T, F_, h2, nullptr, D_, b2, y, nullptr, 1.f, F_);
  // 9. out = LN(h2)
  ln_rows<<<BT_, blk, 0, stream>>>(h2, nullptr, lnbg, lnbb, out_x, nullptr);
}

// Round 12
// 367.105 us; speedup vs baseline: 5.1450x; 1.0738x over previous
//
#include <hip/hip_runtime.h>
#include <hip/hip_bf16.h>
#include <hip/hip_fp16.h>
#include <math.h>

#define B_ 4
#define T_ 1024
#define D_ 1024
#define H_ 16
#define DH_ 64
#define F_ 4096
#define BT_ (B_ * T_)
#define BTD ((size_t)B_ * T_ * D_)

typedef short bf16x8 __attribute__((ext_vector_type(8)));
typedef _Float16 f16x8 __attribute__((ext_vector_type(8)));
typedef float f32x4 __attribute__((ext_vector_type(4)));

__device__ __forceinline__ unsigned short f2b(float f) {
  __hip_bfloat16 h = __float2bfloat16(f);
  return *reinterpret_cast<unsigned short*>(&h);
}
__device__ __forceinline__ unsigned short f2h(float f) {
  __half h = __float2half(f);
  return *reinterpret_cast<unsigned short*>(&h);
}

__device__ __forceinline__ void gload16(const unsigned short* g, unsigned short* l) {
  __builtin_amdgcn_global_load_lds(
      (const __attribute__((address_space(1))) unsigned int*)(const void*)g,
      (__attribute__((address_space(3))) unsigned int*)(void*)l, 16, 0, 0);
}

// tanh-approx GELU via sigmoid identity: 0.5*(1+tanh(z)) = sigmoid(2z).
__device__ __forceinline__ float gelu_f(float x) {
  float z2 = 1.5957691216057308f * (x + 0.044715f * x * x * x);
  return x / (1.0f + __expf(-z2));
}

// ---------------- block reductions (256 threads, wave64) ----------------
__device__ __forceinline__ float blk_sum256(float v, float* s4) {
#pragma unroll
  for (int off = 32; off > 0; off >>= 1) v += __shfl_down(v, off);
  if ((threadIdx.x & 63) == 0) s4[threadIdx.x >> 6] = v;
  __syncthreads();
  float t = s4[0] + s4[1] + s4[2] + s4[3];
  __syncthreads();
  return t;
}

// ---------------- LayerNorm rows of D=1024, fp32 out + optional bf16 out ----
__global__ __launch_bounds__(256) void ln_rows(
    const float* __restrict__ in, const float* __restrict__ in2,
    const float* __restrict__ g, const float* __restrict__ bb,
    float* __restrict__ outf, unsigned short* __restrict__ outb) {
  __shared__ float s4[4];
  const size_t base = (size_t)blockIdx.x * D_;
  const int t = threadIdx.x;
  float4 v = ((const float4*)(in + base))[t];
  if (in2) {
    float4 w = ((const float4*)(in2 + base))[t];
    v.x += w.x; v.y += w.y; v.z += w.z; v.w += w.w;
  }
  float mean = blk_sum256(v.x + v.y + v.z + v.w, s4) * (1.0f / D_);
  float dx = v.x - mean, dy = v.y - mean, dz = v.z - mean, dw = v.w - mean;
  float var = blk_sum256(dx * dx + dy * dy + dz * dz + dw * dw, s4) * (1.0f / D_);
  float rstd = rsqrtf(var + 1e-5f);
  float4 gv = ((const float4*)g)[t];
  float4 bv = ((const float4*)bb)[t];
  float4 o;
  o.x = dx * rstd * gv.x + bv.x;
  o.y = dy * rstd * gv.y + bv.y;
  o.z = dz * rstd * gv.z + bv.z;
  o.w = dw * rstd * gv.w + bv.w;
  if (outf) ((float4*)(outf + base))[t] = o;
  if (outb) {
    unsigned short o4[4] = {f2b(o.x), f2b(o.y), f2b(o.z), f2b(o.w)};
    *(uint2*)(&outb[base + (size_t)t * 4]) = *(uint2*)o4;
  }
}

// ---------------- transpose+cast fp32 [R][C] -> bf16 [C][R] ----------------
__global__ __launch_bounds__(256) void tcast_t(
    const float* __restrict__ in, unsigned short* __restrict__ out, int R, int C) {
  __shared__ unsigned short tile[32][33];
  const int c0 = blockIdx.x * 32, r0 = blockIdx.y * 32;
  const int col = threadIdx.x & 31, rq = threadIdx.x >> 5;
#pragma unroll
  for (int i = 0; i < 4; ++i) {
    int r = rq + i * 8;
    tile[r][col] = f2b(in[(size_t)(r0 + r) * C + c0 + col]);
  }
  __syncthreads();
#pragma unroll
  for (int i = 0; i < 4; ++i) {
    int r = rq + i * 8;
    out[(size_t)(c0 + r) * R + r0 + col] = tile[col][r];
  }
}

// four 1024x1024 weights at once (z selects)
__global__ __launch_bounds__(256) void tcast4(
    const float* w0, const float* w1, const float* w2, const float* w3,
    unsigned short* o0, unsigned short* o1, unsigned short* o2, unsigned short* o3) {
  __shared__ unsigned short tile[32][33];
  const float* in = blockIdx.z == 0 ? w0 : blockIdx.z == 1 ? w1 : blockIdx.z == 2 ? w2 : w3;
  unsigned short* out = blockIdx.z == 0 ? o0 : blockIdx.z == 1 ? o1 : blockIdx.z == 2 ? o2 : o3;
  const int c0 = blockIdx.x * 32, r0 = blockIdx.y * 32;
  const int col = threadIdx.x & 31, rq = threadIdx.x >> 5;
#pragma unroll
  for (int i = 0; i < 4; ++i) {
    int r = rq + i * 8;
    tile[r][col] = f2b(in[(size_t)(r0 + r) * D_ + c0 + col]);
  }
  __syncthreads();
#pragma unroll
  for (int i = 0; i < 4; ++i) {
    int r = rq + i * 8;
    out[(size_t)(c0 + r) * D_ + r0 + col] = tile[col][r];
  }
}

// ---------------- fused attention: scores + softmax + ctx -------------------
// grid (64, 16): x = bh (XCD = bh%8 -> K/V L2-resident), y = t-tile (64 rows).
// 32 KB LDS + <=128 VGPR -> 4 blocks/CU so store-drains overlap across blocks.
// 4 waves 2x2 over (M=64, N=64); s streamed in 16 tiles of 64.
__global__ __launch_bounds__(256, 4) void attn_fused(
    const unsigned short* __restrict__ qh, const unsigned short* __restrict__ kh,
    const unsigned short* __restrict__ vt, float* __restrict__ attn,
    unsigned short* __restrict__ ctxb) {
  __shared__ __align__(16) unsigned short Qs[64 * 64];  // 8 KB
  __shared__ __align__(16) unsigned short Ks[64 * 64];  // 8 KB
  __shared__ __align__(16) unsigned short Vs[64 * 64];  // 8 KB
  __shared__ __align__(16) unsigned short Ps[64 * 64];  // 8 KB
  const int tid = threadIdx.x;
  const int l = tid & 63, w = tid >> 6;
  const int wm = w >> 1, wn = w & 1;
  const int lk = l >> 4, lr = l & 15;
  const int bh = blockIdx.x, b = bh >> 4, h = bh & 15;
  const int tt = blockIdx.y;  // 64-row t-tile
  const unsigned short* Qg = qh + (size_t)b * T_ * D_ + h * DH_ + (size_t)tt * 64 * D_;
  const unsigned short* Kg = kh + (size_t)b * T_ * D_ + h * DH_;
  const unsigned short* Vg = vt + (size_t)bh * 64 * T_;

  // staging: 64 rows x 8 chunks of 16B; thread covers chunks c=i*256+tid.
  const int ar = tid >> 3, ac = tid & 7;           // row 0..31 (+32*i), chunk
  const int aswz = ((ac ^ (ar & 7)) << 3);         // T2 source swizzle

  // stage Q once; fragments held in registers for both phases
#pragma unroll
  for (int i = 0; i < 2; ++i)
    gload16(Qg + (size_t)(ar + 32 * i) * D_ + aswz, &Qs[(size_t)(i * 256 + tid) * 8]);
  __syncthreads();
  f16x8 qf[2][2];
#pragma unroll
  for (int mi = 0; mi < 2; ++mi) {
    const int row = wm * 32 + mi * 16 + lr;
#pragma unroll
    for (int kk = 0; kk < 2; ++kk)
      qf[mi][kk] = *(const f16x8*)&Qs[row * 64 + (((kk * 4 + lk) ^ (row & 7)) << 3)];
  }

  float lsum[2][4] = {};  // partial row exp-sums (this wave's wn-half of s)

  // ---- phase A: row sums ----
  for (int st = 0; st < 16; ++st) {
    __syncthreads();
#pragma unroll
    for (int i = 0; i < 2; ++i)
      gload16(Kg + (size_t)(st * 64 + ar + 32 * i) * D_ + aswz, &Ks[(size_t)(i * 256 + tid) * 8]);
    __syncthreads();
    f16x8 kf[2][2];
#pragma unroll
    for (int ni = 0; ni < 2; ++ni) {
      const int row = wn * 32 + ni * 16 + lr;
#pragma unroll
      for (int kk = 0; kk < 2; ++kk)
        kf[ni][kk] = *(const f16x8*)&Ks[row * 64 + (((kk * 4 + lk) ^ (row & 7)) << 3)];
    }
    f32x4 acc[2][2] = {};
#pragma unroll
    for (int kk = 0; kk < 2; ++kk)
#pragma unroll
      for (int mi = 0; mi < 2; ++mi)
#pragma unroll
        for (int ni = 0; ni < 2; ++ni)
          acc[mi][ni] = __builtin_amdgcn_mfma_f32_16x16x32_f16(
              qf[mi][kk], kf[ni][kk], acc[mi][ni], 0, 0, 0);
#pragma unroll
    for (int mi = 0; mi < 2; ++mi)
#pragma unroll
      for (int r = 0; r < 4; ++r) {
        float v = __expf(acc[mi][0][r] * 0.125f) + __expf(acc[mi][1][r] * 0.125f);
        v += __shfl_xor(v, 1); v += __shfl_xor(v, 2);
        v += __shfl_xor(v, 4); v += __shfl_xor(v, 8);
        lsum[mi][r] += v;
      }
  }

  // ---- cross-wave combine of the two wn-halves (sL aliases head of Ps) ----
  float* sL = (float*)Ps;  // sL[2][64]
  if (lr == 0) {
#pragma unroll
    for (int mi = 0; mi < 2; ++mi)
#pragma unroll
      for (int r = 0; r < 4; ++r)
        sL[wn * 64 + wm * 32 + mi * 16 + lk * 4 + r] = lsum[mi][r];
  }
  __syncthreads();
  float rl[2][4];
#pragma unroll
  for (int mi = 0; mi < 2; ++mi)
#pragma unroll
    for (int r = 0; r < 4; ++r) {
      const int row = wm * 32 + mi * 16 + lk * 4 + r;
      rl[mi][r] = 1.0f / (sL[row] + sL[64 + row]);
    }
  __syncthreads();  // sL reads retired before Ps writes begin

  // ---- phase B: recompute, normalize, write attn, PV ----
  float* Cg = attn + (size_t)bh * T_ * T_;
  f32x4 cacc[2][2] = {};
  for (int st = 0; st < 16; ++st) {
    __syncthreads();
#pragma unroll
    for (int i = 0; i < 2; ++i) {
      gload16(Kg + (size_t)(st * 64 + ar + 32 * i) * D_ + aswz, &Ks[(size_t)(i * 256 + tid) * 8]);
      gload16(Vg + (size_t)(ar + 32 * i) * T_ + st * 64 + aswz, &Vs[(size_t)(i * 256 + tid) * 8]);
    }
    __syncthreads();
    f16x8 kf[2][2], vf[2][2];
#pragma unroll
    for (int ni = 0; ni < 2; ++ni) {
      const int row = wn * 32 + ni * 16 + lr;
#pragma unroll
      for (int kk = 0; kk < 2; ++kk) {
        kf[ni][kk] = *(const f16x8*)&Ks[row * 64 + (((kk * 4 + lk) ^ (row & 7)) << 3)];
        vf[ni][kk] = *(const f16x8*)&Vs[row * 64 + (((kk * 4 + lk) ^ (row & 7)) << 3)];
      }
    }
    f32x4 acc[2][2] = {};
#pragma unroll
    for (int kk = 0; kk < 2; ++kk)
#pragma unroll
      for (int mi = 0; mi < 2; ++mi)
#pragma unroll
        for (int ni = 0; ni < 2; ++ni)
          acc[mi][ni] = __builtin_amdgcn_mfma_f32_16x16x32_f16(
              qf[mi][kk], kf[ni][kk], acc[mi][ni], 0, 0, 0);
    // normalize, write fp32 attn (nontemporal), stash f16 P in swizzled LDS
#pragma unroll
    for (int mi = 0; mi < 2; ++mi) {
      const int trow = wm * 32 + mi * 16 + lk * 4;
#pragma unroll
      for (int ni = 0; ni < 2; ++ni) {
        const int scol = wn * 32 + ni * 16 + lr;
#pragma unroll
        for (int r = 0; r < 4; ++r) {
          const int t = trow + r;
          float p = __expf(acc[mi][ni][r] * 0.125f) * rl[mi][r];
          __builtin_nontemporal_store(
              p, &Cg[(size_t)(tt * 64 + t) * T_ + (st * 64 + scol)]);
          Ps[t * 64 + (scol ^ ((t & 7) << 3))] = f2h(p);
        }
      }
    }
    __syncthreads();  // Ps visible
    // PV: ctx[t][j] += P[t][s] * vt[j][s]
#pragma unroll
    for (int kk = 0; kk < 2; ++kk) {
      f16x8 af[2];
#pragma unroll
      for (int mi = 0; mi < 2; ++mi) {
        const int row = wm * 32 + mi * 16 + lr;
        af[mi] = *(const f16x8*)&Ps[row * 64 + (((kk * 4 + lk) ^ (row & 7)) << 3)];
      }
#pragma unroll
      for (int mi = 0; mi < 2; ++mi)
#pragma unroll
        for (int ni = 0; ni < 2; ++ni)
          cacc[mi][ni] = __builtin_amdgcn_mfma_f32_16x16x32_f16(
              af[mi], vf[ni][kk], cacc[mi][ni], 0, 0, 0);
    }
  }

  unsigned short* Cb = ctxb + (size_t)b * T_ * D_ + h * DH_;
  const int crow0 = tt * 64 + wm * 32 + lk * 4;
  const int ccol0 = wn * 32 + lr;
#pragma unroll
  for (int mi = 0; mi < 2; ++mi)
#pragma unroll
    for (int ni = 0; ni < 2; ++ni)
#pragma unroll
      for (int r = 0; r < 4; ++r)
        Cb[(size_t)(crow0 + mi * 16 + r) * D_ + ccol0 + ni * 16] = f2b(cacc[mi][ni][r]);
}

// ---------------- MFMA NT GEMM: C[M][N] = A[M][K] @ Bn[N][K]^T ----------------
// EPI: 0=bias, 1=bias+gelu, 2=bias+res1, 3=scale only, 4=bias+res1+res2,
//      5=bias + f16 write TRANSPOSED per head: vt[(b*16+h)*64 + j][t]
// DB: double-buffered LDS, one barrier per K-step (for 1-block/CU grids).
template <int BN, int EPI, bool WF32, bool W16, bool FP16 = false, bool DB = false>
__global__ __launch_bounds__(256) void gemm_nt(
    const unsigned short* __restrict__ A, int lda,
    const unsigned short* __restrict__ Bm, int ldb,
    float* __restrict__ Cf, unsigned short* __restrict__ Cb, int ldc,
    const float* __restrict__ bias, const float* __restrict__ r1,
    const float* __restrict__ r2, float scale, int K) {
  constexpr int BM = 128, BK = 64;
  constexpr int WN = BN / 2;
  constexpr int FN = WN / 16;
  constexpr int NB = DB ? 2 : 1;
  __shared__ __align__(16) unsigned short As[NB][BM * BK];
  __shared__ __align__(16) unsigned short Bs[NB][BN * BK];
  const int tid = threadIdx.x;
  const int l = tid & 63;
  const int w = tid >> 6;
  const int wm = w >> 1, wn = w & 1;
  const int lr = l & 15, lk = l >> 4;
  const unsigned short* Ab = A + (size_t)blockIdx.y * BM * lda;
  const unsigned short* Bb = Bm + (size_t)blockIdx.x * BN * ldb;

  const int ar = tid >> 3;
  const int ac = tid & 7;
  const int aswz = ((ac ^ (ar & 7)) << 3);

  f32x4 acc[4][FN] = {};

  auto stage = [&](int buf, int k0) {
#pragma unroll
    for (int i = 0; i < 4; ++i)
      gload16(Ab + (size_t)(ar + 32 * i) * lda + k0 + aswz, &As[buf][(size_t)(i * 256 + tid) * 8]);
#pragma unroll
    for (int i = 0; i < BN / 32; ++i)
      gload16(Bb + (size_t)(ar + 32 * i) * ldb + k0 + aswz, &Bs[buf][(size_t)(i * 256 + tid) * 8]);
  };
  auto compute = [&](int buf) {
    bf16x8 af[4][2], bfr[FN][2];
#pragma unroll
    for (int mi = 0; mi < 4; ++mi) {
      const int row = wm * 64 + mi * 16 + lr;
#pragma unroll
      for (int kk = 0; kk < 2; ++kk)
        af[mi][kk] = *(const bf16x8*)&As[buf][row * BK + (((kk * 4 + lk) ^ (row & 7)) << 3)];
    }
#pragma unroll
    for (int ni = 0; ni < FN; ++ni) {
      const int row = wn * WN + ni * 16 + lr;
#pragma unroll
      for (int kk = 0; kk < 2; ++kk)
        bfr[ni][kk] = *(const bf16x8*)&Bs[buf][row * BK + (((kk * 4 + lk) ^ (row & 7)) << 3)];
    }
#pragma unroll
    for (int kk = 0; kk < 2; ++kk)
#pragma unroll
      for (int mi = 0; mi < 4; ++mi)
#pragma unroll
        for (int ni = 0; ni < FN; ++ni)
          acc[mi][ni] = __builtin_amdgcn_mfma_f32_16x16x32_bf16(
              af[mi][kk], bfr[ni][kk], acc[mi][ni], 0, 0, 0);
  };

  if constexpr (DB) {
    const int nt = K / BK;
    stage(0, 0);
    int cur = 0;
    for (int t = 0; t < nt; ++t) {
      __syncthreads();
      if (t + 1 < nt) stage(cur ^ 1, (t + 1) * BK);
      compute(cur);
      cur ^= 1;
    }
  } else {
    for (int k0 = 0; k0 < K; k0 += BK) {
      stage(0, k0);
      __syncthreads();
      compute(0);
      __syncthreads();
    }
  }

  const int crow0 = blockIdx.y * BM + wm * 64 + lk * 4;
  const int ccol0 = blockIdx.x * BN + wn * WN + lr;
  if constexpr (EPI == 5) {
#pragma unroll
    for (int mi = 0; mi < 4; ++mi)
#pragma unroll
      for (int ni = 0; ni < FN; ++ni) {
        const int row0 = crow0 + mi * 16;
        const int col = ccol0 + ni * 16;
        unsigned short __attribute__((aligned(8))) p4[4];
#pragma unroll
        for (int r = 0; r < 4; ++r) p4[r] = f2h(acc[mi][ni][r] + bias[col]);
        const int bidx = row0 >> 10, t0 = row0 & 1023;
        const int hh = col >> 6, j = col & 63;
        *(uint2*)&Cb[(((size_t)bidx * 16 + hh) * 64 + j) * T_ + t0] = *(uint2*)p4;
      }
  } else {
#pragma unroll
    for (int mi = 0; mi < 4; ++mi)
#pragma unroll
      for (int ni = 0; ni < FN; ++ni)
#pragma unroll
        for (int r = 0; r < 4; ++r) {
          const int row = crow0 + mi * 16 + r;
          const int col = ccol0 + ni * 16;
          float v = acc[mi][ni][r] * scale;
          if (EPI != 3) v += bias[col];
          if (EPI == 1) v = gelu_f(v);
          const size_t off = (size_t)row * ldc + col;
          if (EPI == 2) v += r1[off];
          if (EPI == 4) v += r1[off] + r2[off];
          if (WF32) Cf[off] = v;
          if (W16) Cb[off] = FP16 ? f2h(v) : f2b(v);
        }
  }
}

// ---------------- fused QKV: one N=3072 GEMM over contiguous WqT|WkT|WvT ----
__global__ __launch_bounds__(256) void gemm_qkv(
    const unsigned short* __restrict__ A, const unsigned short* __restrict__ Wt,
    const float* __restrict__ bq, const float* __restrict__ bk,
    const float* __restrict__ bv, const float* __restrict__ sp,
    const float* __restrict__ ed, unsigned short* __restrict__ q_h,
    unsigned short* __restrict__ kb_h, unsigned short* __restrict__ vt) {
  constexpr int BM = 128, BN = 128, BK = 64, K = 1024;
  __shared__ __align__(16) unsigned short As[BM * BK];
  __shared__ __align__(16) unsigned short Bs[BN * BK];
  const int tid = threadIdx.x;
  const int l = tid & 63, w = tid >> 6;
  const int wm = w >> 1, wn = w & 1;
  const int lr = l & 15, lk = l >> 4;
  const unsigned short* Ab = A + (size_t)blockIdx.y * BM * D_;
  const unsigned short* Bb = Wt + (size_t)blockIdx.x * BN * D_;
  const int ar = tid >> 3, ac = tid & 7;
  const int aswz = ((ac ^ (ar & 7)) << 3);

  f32x4 acc[4][4] = {};
  for (int k0 = 0; k0 < K; k0 += BK) {
#pragma unroll
    for (int i = 0; i < 4; ++i) {
      gload16(Ab + (size_t)(ar + 32 * i) * D_ + k0 + aswz, &As[(size_t)(i * 256 + tid) * 8]);
      gload16(Bb + (size_t)(ar + 32 * i) * D_ + k0 + aswz, &Bs[(size_t)(i * 256 + tid) * 8]);
    }
    __syncthreads();
    bf16x8 af[4][2], bfr[4][2];
#pragma unroll
    for (int mi = 0; mi < 4; ++mi) {
      const int row = wm * 64 + mi * 16 + lr;
#pragma unroll
      for (int kk = 0; kk < 2; ++kk)
        af[mi][kk] = *(const bf16x8*)&As[row * BK + (((kk * 4 + lk) ^ (row & 7)) << 3)];
    }
#pragma unroll
    for (int ni = 0; ni < 4; ++ni) {
      const int row = wn * 64 + ni * 16 + lr;
#pragma unroll
      for (int kk = 0; kk < 2; ++kk)
        bfr[ni][kk] = *(const bf16x8*)&Bs[row * BK + (((kk * 4 + lk) ^ (row & 7)) << 3)];
    }
#pragma unroll
    for (int kk = 0; kk < 2; ++kk)
#pragma unroll
      for (int mi = 0; mi < 4; ++mi)
#pragma unroll
        for (int ni = 0; ni < 4; ++ni)
          acc[mi][ni] = __builtin_amdgcn_mfma_f32_16x16x32_bf16(
              af[mi][kk], bfr[ni][kk], acc[mi][ni], 0, 0, 0);
    __syncthreads();
  }

  const int seg = blockIdx.x >> 3;  // 0=Q, 1=K, 2=V
  const float* bias = seg == 0 ? bq : seg == 1 ? bk : bv;
  const int crow0 = blockIdx.y * BM + wm * 64 + lk * 4;
  const int ccol0 = blockIdx.x * BN + wn * 64 + lr;
  if (seg == 2) {
#pragma unroll
    for (int mi = 0; mi < 4; ++mi)
#pragma unroll
      for (int ni = 0; ni < 4; ++ni) {
        const int row0 = crow0 + mi * 16;
        const int col = (ccol0 + ni * 16) & 1023;
        unsigned short __attribute__((aligned(8))) p4[4];
#pragma unroll
        for (int r = 0; r < 4; ++r) p4[r] = f2h(acc[mi][ni][r] + bias[col]);
        const int bidx = row0 >> 10, t0 = row0 & 1023;
        const int hh = col >> 6, j = col & 63;
        *(uint2*)&vt[(((size_t)bidx * 16 + hh) * 64 + j) * T_ + t0] = *(uint2*)p4;
      }
  } else {
    unsigned short* out = seg == 0 ? q_h : kb_h;
#pragma unroll
    for (int mi = 0; mi < 4; ++mi)
#pragma unroll
      for (int ni = 0; ni < 4; ++ni)
#pragma unroll
        for (int r = 0; r < 4; ++r) {
          const int row = crow0 + mi * 16 + r;
          const int col = (ccol0 + ni * 16) & 1023;
          float v = acc[mi][ni][r] + bias[col];
          const size_t off = (size_t)row * D_ + col;
          if (seg == 1) v += sp[off] + ed[off];
          out[off] = f2h(v);
        }
  }
}

extern "C" void kernel_launch(void* const* d_in, const int* in_sizes, int n_in,
                              void* d_out, int out_size, void* d_ws, size_t ws_size,
                              hipStream_t stream) {
  const float* x    = (const float*)d_in[0];
  const float* sp   = (const float*)d_in[1];
  const float* ed   = (const float*)d_in[2];
  const float* ln1g = (const float*)d_in[3];
  const float* ln1b = (const float*)d_in[4];
  const float* Wq   = (const float*)d_in[5];
  const float* bq   = (const float*)d_in[6];
  const float* Wk   = (const float*)d_in[7];
  const float* bk   = (const float*)d_in[8];
  const float* Wv   = (const float*)d_in[9];
  const float* bvv  = (const float*)d_in[10];
  const float* Wo   = (const float*)d_in[11];
  const float* bo   = (const float*)d_in[12];
  const float* ln2g = (const float*)d_in[13];
  const float* ln2b = (const float*)d_in[14];
  const float* W1   = (const float*)d_in[15];
  const float* b1   = (const float*)d_in[16];
  const float* W2   = (const float*)d_in[17];
  const float* b2   = (const float*)d_in[18];
  const float* lnbg = (const float*)d_in[19];
  const float* lnbb = (const float*)d_in[20];

  float* out_x = (float*)d_out;
  float* attn  = out_x + BTD;
  float* tt    = out_x;

  const size_t MB = 1 << 20;
  char* wsb = (char*)d_ws;
  float*          xn    = (float*)(wsb);                    // [0,16)
  unsigned short* xn_b  = (unsigned short*)(wsb + 16 * MB); // [16,24)
  unsigned short* WqT   = (unsigned short*)(wsb + 24 * MB); // [24,30) Wq|Wk|Wv
  unsigned short* WkT   = (unsigned short*)(wsb + 26 * MB);
  unsigned short* WvT   = (unsigned short*)(wsb + 28 * MB);
  unsigned short* WoT   = (unsigned short*)(wsb + 30 * MB);
  unsigned short* W1T   = (unsigned short*)(wsb + 32 * MB); // [32,40)
  unsigned short* W2T   = (unsigned short*)(wsb + 40 * MB); // [40,48)
  unsigned short* q_h   = (unsigned short*)(wsb + 48 * MB); // [48,56)
  unsigned short* kb_h  = (unsigned short*)(wsb + 56 * MB); // [56,64)
  unsigned short* vt    = (unsigned short*)(wsb + 80 * MB); // [80,88)
  unsigned short* ctx_b = xn_b;                             // [16,24)
  unsigned short* h1_b  = (unsigned short*)(wsb + 48 * MB); // [48,80)
  float*          h2    = (float*)(wsb + 80 * MB);          // [80,96)
  float*          y     = xn;
  unsigned short* y_b   = xn_b;

  dim3 blk(256);
  dim3 g_dd(8, 32);

  // 1. LN1 -> xn (fp32 residual) + xn_b (bf16 GEMM operand)
  ln_rows<<<BT_, blk, 0, stream>>>(x, nullptr, ln1g, ln1b, xn, xn_b);
  // 2. weight transpose+cast
  tcast4<<<dim3(32, 32, 4), blk, 0, stream>>>(Wq, Wk, Wv, Wo, WqT, WkT, WvT, WoT);
  tcast_t<<<dim3(128, 32), blk, 0, stream>>>(W1, W1T, 1024, 4096);
  tcast_t<<<dim3(32, 128), blk, 0, stream>>>(W2, W2T, 4096, 1024);
  // 3. fused QKV (768 blocks): Q->f16, K(+sp+ed)->f16, V->f16 transposed
  gemm_qkv<<<dim3(24, 32), blk, 0, stream>>>(
      xn_b, WqT, bq, bk, bvv, sp, ed, q_h, kb_h, vt);
  // 4. fused scores + softmax + ctx (1024 blocks, 4/CU)
  attn_fused<<<dim3(64, 16), blk, 0, stream>>>(q_h, kb_h, vt, attn, ctx_b);
  // 5. tt = ctx @ Wo + bo + xn (MFMA, dbuf)
  gemm_nt<128, 2, true, false, false, true><<<g_dd, blk, 0, stream>>>(
      ctx_b, D_, WoT, D_, tt, nullptr, D_, bo, xn, nullptr, 1.f, D_);
  // 6. y = LN2(tt)
  ln_rows<<<BT_, blk, 0, stream>>>(tt, nullptr, ln2g, ln2b, y, y_b);
  // 7. h1 = gelu(y @ W1 + b1) -> bf16 (MFMA)
  gemm_nt<128, 1, false, true><<<dim3(32, 32), blk, 0, stream>>>(
      y_b, D_, W1T, D_, nullptr, h1_b, F_, b1, nullptr, nullptr, 1.f, D_);
  // 8. h2 = y + (h1 @ W2 + b2)  (MFMA, dbuf, fp32 out)
  gemm_nt<128, 2, true, false, false, true><<<g_dd, blk, 0, stream>>>(
      h1_b, F_, W2T, F_, h2, nullptr, D_, b2, y, nullptr, 1.f, F_);
  // 9. out = LN(h2)
  ln_rows<<<BT_, blk, 0, stream>>>(h2, nullptr, lnbg, lnbb, out_x, nullptr);
}